// Round 3
// baseline (173.959 us; speedup 1.0000x reference)
//
#include <hip/hip_runtime.h>

#define NB 4
#define CD 256
#define HW 4096
#define KSG 16
#define CC (CD * CD)

typedef __attribute__((ext_vector_type(8))) short bf16x8;
typedef __attribute__((ext_vector_type(4))) float f32x4;

__device__ inline unsigned short f2bf(float x) {
  unsigned int u = __float_as_uint(x);
  unsigned int r = (u + 0x7FFFu + ((u >> 16) & 1u)) >> 16;
  return (unsigned short)r;
}
__device__ inline float bfhi(unsigned short h) {
  return __uint_as_float(((unsigned int)h) << 16);
}
__device__ __forceinline__ void gload16(const unsigned short* g, unsigned short* l) {
  __builtin_amdgcn_global_load_lds((const __attribute__((address_space(1))) void*)g,
                                   (__attribute__((address_space(3))) void*)l, 16, 0, 0);
}

// ---------- convert X fp32 -> bf16 hi/lo ([c][p] and transposed [p][c]) + chansum partials ----------
__global__ __launch_bounds__(256) void k_convert(const float* __restrict__ X,
                                                 unsigned short* __restrict__ Uhi,
                                                 unsigned short* __restrict__ Ulo,
                                                 unsigned short* __restrict__ Xthi,
                                                 unsigned short* __restrict__ Xtlo,
                                                 float* __restrict__ psum) {
  int pt = blockIdx.x, ct = blockIdx.y, n = blockIdx.z;
  __shared__ unsigned int W[64][65];
  int t = threadIdx.x;
  int cl = t >> 2, pb = (t & 3) * 16;
  const float* Xp = X + ((size_t)n * CD + ct * 64 + cl) * HW + pt * 64 + pb;
  float x[16];
#pragma unroll
  for (int j = 0; j < 4; ++j) {
    float4 v = *(const float4*)(Xp + 4 * j);
    x[4 * j + 0] = v.x; x[4 * j + 1] = v.y; x[4 * j + 2] = v.z; x[4 * j + 3] = v.w;
  }
  float xs = 0.f;
  unsigned short h[16], l[16];
#pragma unroll
  for (int j = 0; j < 16; ++j) {
    xs += x[j];
    h[j] = f2bf(x[j]);
    l[j] = f2bf(x[j] - bfhi(h[j]));
    W[cl][pb + j] = (((unsigned int)h[j]) << 16) | l[j];
  }
  xs += __shfl_xor(xs, 1);
  xs += __shfl_xor(xs, 2);
  if ((t & 3) == 0) psum[((size_t)n * 64 + pt) * CD + ct * 64 + cl] = xs;
  size_t rowOff = ((size_t)n * CD + ct * 64 + cl) * HW + pt * 64 + pb;
#pragma unroll
  for (int j = 0; j < 4; ++j) {
    ushort4 vh, vl;
    vh.x = h[4 * j]; vh.y = h[4 * j + 1]; vh.z = h[4 * j + 2]; vh.w = h[4 * j + 3];
    vl.x = l[4 * j]; vl.y = l[4 * j + 1]; vl.z = l[4 * j + 2]; vl.w = l[4 * j + 3];
    *(ushort4*)(Uhi + rowOff + 4 * j) = vh;
    *(ushort4*)(Ulo + rowOff + 4 * j) = vl;
  }
  __syncthreads();
  int pl = t >> 2, cb = (t & 3) * 16;
  size_t rowT = ((size_t)n * HW + pt * 64 + pl) * CD + ct * 64 + cb;
#pragma unroll
  for (int j = 0; j < 4; ++j) {
    ushort4 vh, vl;
    unsigned int w0v = W[cb + 4 * j + 0][pl];
    unsigned int w1v = W[cb + 4 * j + 1][pl];
    unsigned int w2v = W[cb + 4 * j + 2][pl];
    unsigned int w3v = W[cb + 4 * j + 3][pl];
    vh.x = (unsigned short)(w0v >> 16); vl.x = (unsigned short)(w0v & 0xffff);
    vh.y = (unsigned short)(w1v >> 16); vl.y = (unsigned short)(w1v & 0xffff);
    vh.z = (unsigned short)(w2v >> 16); vl.z = (unsigned short)(w2v & 0xffff);
    vh.w = (unsigned short)(w3v >> 16); vl.w = (unsigned short)(w3v & 0xffff);
    *(ushort4*)(Xthi + rowT + 4 * j) = vh;
    *(ushort4*)(Xtlo + rowT + 4 * j) = vl;
  }
}

// ---------- all small vectors in one launch ----------
__global__ __launch_bounds__(256) void k_vec1(
    const float* __restrict__ psum, const float* __restrict__ w0,
    const float* __restrict__ w1, const float* __restrict__ w2,
    const float* __restrict__ w3, const float* __restrict__ b0,
    const float* __restrict__ b1, const float* __restrict__ b2,
    float* __restrict__ tv, float* __restrict__ rv, float* __restrict__ alp,
    float* __restrict__ gam, float* __restrict__ bet, float* __restrict__ dlt,
    float* __restrict__ v1) {
  int n = blockIdx.x, c = threadIdx.x;
  __shared__ float ss[CD], st[CD], sr[CD];
  float a = 0.f;
  for (int pt = 0; pt < 64; ++pt) a += psum[((size_t)n * 64 + pt) * CD + c];
  ss[c] = a;
  __syncthreads();
  float t_ = 0.f, r_ = 0.f;
  for (int k = 0; k < CD; ++k) {
    float sk = ss[k];
    t_ += w1[(size_t)c * CD + k] * sk;
    r_ += w0[(size_t)c * CD + k] * sk;
  }
  st[c] = t_; sr[c] = r_;
  tv[n * CD + c] = t_; rv[n * CD + c] = r_;
  __syncthreads();
  float al_ = 0.f, ga_ = 0.f;
  for (int k = 0; k < CD; ++k) {
    al_ += w2[(size_t)k * CD + c] * st[k];
    ga_ += w3[(size_t)c * CD + k] * sr[k];
  }
  alp[n * CD + c] = al_;
  gam[n * CD + c] = ga_;
  if (n == 0) {
    float be_ = 0.f, dl_ = 0.f, v_ = 0.f;
    for (int k = 0; k < CD; ++k) {
      be_ += w2[(size_t)k * CD + c] * b1[k];
      dl_ += w3[(size_t)c * CD + k] * b0[k];
      v_ += w1[(size_t)k * CD + c] * b2[k];
    }
    bet[c] = be_; dlt[c] = dl_; v1[c] = v_;
  }
}

// ---------- cv[n] = W3 (W0 (G v1) + (t.b2) b0 + (b1.b2)(r + HW b0))/HW + b3 ----------
__global__ void k_mv2(const float* __restrict__ G, const float* __restrict__ w0,
                      const float* __restrict__ w3, const float* __restrict__ b0,
                      const float* __restrict__ b1, const float* __restrict__ b2,
                      const float* __restrict__ b3, const float* __restrict__ t,
                      const float* __restrict__ r, const float* __restrict__ v1,
                      float* __restrict__ cv) {
  int n = blockIdx.x, i = threadIdx.x;
  __shared__ float red[CD], vsh[CD], g1[CD], u[CD];
  __shared__ float scal[2];
  red[i] = t[n * CD + i] * b2[i];
  __syncthreads();
  for (int off = 128; off > 0; off >>= 1) {
    if (i < off) red[i] += red[i + off];
    __syncthreads();
  }
  if (i == 0) scal[0] = red[0];
  __syncthreads();
  red[i] = b1[i] * b2[i];
  __syncthreads();
  for (int off = 128; off > 0; off >>= 1) {
    if (i < off) red[i] += red[i + off];
    __syncthreads();
  }
  if (i == 0) scal[1] = red[0];
  vsh[i] = v1[i];
  __syncthreads();
  const float* Gn = G + (size_t)n * CC;
  float a = 0.f;
  for (int k = 0; k < CD; ++k) a += Gn[(size_t)i * CD + k] * vsh[k];
  g1[i] = a;
  __syncthreads();
  float bacc = 0.f;
  for (int k = 0; k < CD; ++k) bacc += w0[(size_t)i * CD + k] * g1[k];
  u[i] = bacc + scal[0] * b0[i] + scal[1] * (r[n * CD + i] + (float)HW * b0[i]);
  __syncthreads();
  float cacc = 0.f;
  for (int k = 0; k < CD; ++k) cacc += w3[(size_t)i * CD + k] * u[k];
  cv[n * CD + i] = cacc * (1.0f / HW) + b3[i];
}

// ---------- fp32 64x64-tile GEMM (small 256^3), K=256 in 2 stages; TA: A col-major ----------
template <int TA, int EPI>
__global__ __launch_bounds__(256) void k_gemm64(
    const float* __restrict__ A, const float* __restrict__ B, size_t aStride,
    size_t bStride, float* __restrict__ C0, size_t cStride,
    unsigned short* __restrict__ Ohi, unsigned short* __restrict__ Olo,
    const float* __restrict__ dlt, const float* __restrict__ alp,
    const float* __restrict__ gam, const float* __restrict__ bet) {
  int i0 = blockIdx.x * 64, j0 = blockIdx.y * 64, n = blockIdx.z;
  const float* An = A + (size_t)n * aStride;
  const float* Bn = B + (size_t)n * bStride;
  __shared__ __align__(16) float As[TA ? 128 * 68 : 64 * 132];
  __shared__ __align__(16) float Bs[128 * 68];
  int t = threadIdx.x, tx = t & 15, ty = t >> 4;
  float acc[4][4] = {};
  for (int s = 0; s < 2; ++s) {
    int kb = s * 128;
    if (TA == 0) {
#pragma unroll
      for (int j = 0; j < 8; ++j) {
        int flat = t + j * 256;
        int i = flat >> 5, c4 = (flat & 31) * 4;
        *(float4*)&As[i * 132 + c4] = *(const float4*)(An + (size_t)(i0 + i) * CD + kb + c4);
      }
    } else {
#pragma unroll
      for (int j = 0; j < 8; ++j) {
        int flat = t + j * 256;
        int k = flat >> 4, c4 = (flat & 15) * 4;
        *(float4*)&As[k * 68 + c4] = *(const float4*)(An + (size_t)(kb + k) * CD + i0 + c4);
      }
    }
#pragma unroll
    for (int j = 0; j < 8; ++j) {
      int flat = t + j * 256;
      int k = flat >> 4, c4 = (flat & 15) * 4;
      *(float4*)&Bs[k * 68 + c4] = *(const float4*)(Bn + (size_t)(kb + k) * CD + j0 + c4);
    }
    __syncthreads();
    for (int k = 0; k < 128; ++k) {
      float a0, a1, a2, a3;
      if (TA == 0) {
        a0 = As[(ty * 4 + 0) * 132 + k];
        a1 = As[(ty * 4 + 1) * 132 + k];
        a2 = As[(ty * 4 + 2) * 132 + k];
        a3 = As[(ty * 4 + 3) * 132 + k];
      } else {
        float4 av = *(const float4*)&As[k * 68 + ty * 4];
        a0 = av.x; a1 = av.y; a2 = av.z; a3 = av.w;
      }
      float4 bv = *(const float4*)&Bs[k * 68 + tx * 4];
      float b[4] = {bv.x, bv.y, bv.z, bv.w};
      float a[4] = {a0, a1, a2, a3};
#pragma unroll
      for (int m = 0; m < 4; ++m)
#pragma unroll
        for (int q = 0; q < 4; ++q) acc[m][q] = fmaf(a[m], b[q], acc[m][q]);
    }
    __syncthreads();
  }
  if (EPI == 0) {
    float* Cn = C0 + (size_t)n * cStride;
#pragma unroll
    for (int m = 0; m < 4; ++m)
#pragma unroll
      for (int q = 0; q < 4; ++q)
        Cn[(size_t)(i0 + ty * 4 + m) * CD + j0 + tx * 4 + q] = acc[m][q];
  } else {
#pragma unroll
    for (int m = 0; m < 4; ++m) {
      int i = i0 + ty * 4 + m;
      float di = dlt[i];
      float gi = gam[n * CD + i];
#pragma unroll
      for (int q = 0; q < 4; ++q) {
        int j = j0 + tx * 4 + q;
        float bj = bet[j];
        float aj = alp[n * CD + j];
        float v = (acc[m][q] + di * aj + gi * bj) * (1.0f / HW) + di * bj;
        unsigned short hh = f2bf(v);
        unsigned short ll = f2bf(v - bfhi(hh));
        Ohi[(size_t)n * CC + (size_t)i * CD + j] = hh;
        Olo[(size_t)n * CC + (size_t)i * CD + j] = ll;
      }
    }
  }
}

// ---------- NT MFMA GEMM, m97-style: 512 thr, 128x128 tile, BK=64, global_load_lds ----------
// C[i][j] = sum_k P[i][k]*Q[j][k], 3-term bf16 split. kLen fixed = 256, kBegin = ks*256.
template <int EPI>
__global__ __launch_bounds__(512) void k_mfma_nt(
    const unsigned short* __restrict__ Phi, const unsigned short* __restrict__ Plo,
    size_t pStride, int ldP, const unsigned short* __restrict__ Qhi,
    const unsigned short* __restrict__ Qlo, size_t qStride, int ldQ,
    float* __restrict__ Cout, size_t cStride, int ldC, int KS,
    const float* __restrict__ cv) {
  int z = blockIdx.z, n = z / KS, ks = z % KS;
  int i0 = blockIdx.x * 128, j0 = blockIdx.y * 128;
  int kBegin = ks * 256;
  const unsigned short* pH = Phi + (size_t)n * pStride;
  const unsigned short* pL = Plo + (size_t)n * pStride;
  const unsigned short* qH = Qhi + (size_t)n * qStride;
  const unsigned short* qL = Qlo + (size_t)n * qStride;
  float* cPtr = Cout + ((size_t)ks * NB + n) * cStride;

  __shared__ __align__(16) unsigned short sm[4 * 128 * 64];

  int t = threadIdx.x;
  int lane = t & 63, wid = t >> 6;
  int wr = wid >> 2, wc = wid & 3;      // wave tile 64x32 in 2x4 wave grid
  int lrow = lane & 15, lkb = lane >> 4;

  // staging roles: waves 0-1 -> Ah, 2-3 -> Al, 4-5 -> Bh, 6-7 -> Bl
  int tsel = wid >> 1;
  int gbase = (wid & 1) * 8;
  const unsigned short* bp = (tsel == 0) ? pH : (tsel == 1) ? pL : (tsel == 2) ? qH : qL;
  int tb = (tsel < 2) ? i0 : j0;
  int ldT = (tsel < 2) ? ldP : ldQ;
  int rsub = lane >> 3;                       // row within 8-row group
  int gc = (lane & 7) ^ rsub;                 // inverse-swizzled global chunk
  unsigned short* ldsT = sm + (size_t)tsel * 128 * 64;

  f32x4 acc[4][2];
#pragma unroll
  for (int m = 0; m < 4; ++m)
#pragma unroll
    for (int q = 0; q < 2; ++q) acc[m][q] = (f32x4){0.f, 0.f, 0.f, 0.f};

  for (int k0 = 0; k0 < 256; k0 += 64) {
    int kb = kBegin + k0;
#pragma unroll
    for (int s = 0; s < 8; ++s) {
      int g = gbase + s;
      gload16(bp + (size_t)(tb + g * 8 + rsub) * ldT + kb + gc * 8, ldsT + g * 8 * 64);
    }
    __syncthreads();  // drains vmcnt(0): LDS tiles ready
#pragma unroll
    for (int ks2 = 0; ks2 < 2; ++ks2) {
      bf16x8 ah[4], al[4], bh[2], bl[2];
#pragma unroll
      for (int m = 0; m < 4; ++m) {
        int r = wr * 64 + m * 16 + lrow;
        int sw = ((ks2 * 4 + lkb) ^ (r & 7)) * 8;
        ah[m] = *(const bf16x8*)(sm + 0 * 8192 + r * 64 + sw);
        al[m] = *(const bf16x8*)(sm + 1 * 8192 + r * 64 + sw);
      }
#pragma unroll
      for (int q = 0; q < 2; ++q) {
        int r = wc * 32 + q * 16 + lrow;
        int sw = ((ks2 * 4 + lkb) ^ (r & 7)) * 8;
        bh[q] = *(const bf16x8*)(sm + 2 * 8192 + r * 64 + sw);
        bl[q] = *(const bf16x8*)(sm + 3 * 8192 + r * 64 + sw);
      }
#pragma unroll
      for (int m = 0; m < 4; ++m)
#pragma unroll
        for (int q = 0; q < 2; ++q) {
          acc[m][q] = __builtin_amdgcn_mfma_f32_16x16x32_bf16(ah[m], bh[q], acc[m][q], 0, 0, 0);
          acc[m][q] = __builtin_amdgcn_mfma_f32_16x16x32_bf16(ah[m], bl[q], acc[m][q], 0, 0, 0);
          acc[m][q] = __builtin_amdgcn_mfma_f32_16x16x32_bf16(al[m], bh[q], acc[m][q], 0, 0, 0);
        }
    }
    __syncthreads();  // all reads done before next stage overwrites
  }
#pragma unroll
  for (int m = 0; m < 4; ++m) {
    int row = i0 + wr * 64 + m * 16 + (lane >> 4) * 4;
#pragma unroll
    for (int q = 0; q < 2; ++q) {
      int col = j0 + wc * 32 + q * 16 + (lane & 15);
#pragma unroll
      for (int e = 0; e < 4; ++e) {
        float v = acc[m][q][e];
        if (EPI == 1) v += cv[n * CD + row + e];
        cPtr[(size_t)(row + e) * ldC + col] = v;
      }
    }
  }
}

// ---------- reduce gram K-split partials ----------
__global__ void k_gram_reduce(const float* __restrict__ Gp, float* __restrict__ G) {
  size_t idx = (size_t)blockIdx.x * 256 + threadIdx.x;
  float a = 0.f;
#pragma unroll
  for (int ks = 0; ks < KSG; ++ks) a += Gp[(size_t)ks * NB * CC + idx];
  G[idx] = a;
}

extern "C" void kernel_launch(void* const* d_in, const int* in_sizes, int n_in,
                              void* d_out, int out_size, void* d_ws, size_t ws_size,
                              hipStream_t stream) {
  const float* X = (const float*)d_in[0];
  const float* w0 = (const float*)d_in[1];
  const float* b0 = (const float*)d_in[2];
  const float* w1 = (const float*)d_in[3];
  const float* b1 = (const float*)d_in[4];
  const float* w2 = (const float*)d_in[5];
  const float* b2 = (const float*)d_in[6];
  const float* w3 = (const float*)d_in[7];
  const float* b3 = (const float*)d_in[8];
  float* out = (float*)d_out;
  float* ws = (float*)d_ws;

  float* tv = ws;
  float* rv = ws + 1024;
  float* cv = ws + 2048;
  float* alp = ws + 3072;
  float* gam = ws + 4096;
  float* bet = ws + 5120;
  float* dlt = ws + 6144;
  float* v1 = ws + 7168;
  float* psum = ws + 8192;                 // NB*64*CD = 65536
  float* E = psum + 65536;
  float* F = E + CC;
  float* G = F + CC;                       // NB*CC
  float* R = G + (size_t)NB * CC;
  unsigned short* Athi = (unsigned short*)(R + (size_t)NB * CC);
  unsigned short* Atlo = Athi + (size_t)NB * CC;
  unsigned short* Uhi = Atlo + (size_t)NB * CC;
  unsigned short* Ulo = Uhi + (size_t)NB * CD * HW;
  unsigned short* Xthi = Ulo + (size_t)NB * CD * HW;
  unsigned short* Xtlo = Xthi + (size_t)NB * CD * HW;
  float* Gp = (float*)(Xtlo + (size_t)NB * CD * HW);  // KSG*NB*CC floats

  k_convert<<<dim3(HW / 64, CD / 64, NB), 256, 0, stream>>>(X, Uhi, Ulo, Xthi, Xtlo, psum);
  // Gram partials via MFMA (start the long pole early)
  k_mfma_nt<0><<<dim3(2, 2, NB * KSG), 512, 0, stream>>>(
      Uhi, Ulo, (size_t)CD * HW, HW, Uhi, Ulo, (size_t)CD * HW, HW, Gp, CC, CD, KSG,
      nullptr);
  k_vec1<<<dim3(NB), 256, 0, stream>>>(psum, w0, w1, w2, w3, b0, b1, b2, tv, rv, alp,
                                       gam, bet, dlt, v1);
  // E = W3*W0 (NN), F = W1^T*W2 (TN)
  k_gemm64<0, 0><<<dim3(4, 4, 1), 256, 0, stream>>>(w3, w0, 0, 0, E, 0, nullptr, nullptr,
                                                    nullptr, nullptr, nullptr, nullptr);
  k_gemm64<1, 0><<<dim3(4, 4, 1), 256, 0, stream>>>(w1, w2, 0, 0, F, 0, nullptr, nullptr,
                                                    nullptr, nullptr, nullptr, nullptr);
  k_gram_reduce<<<dim3(NB * CC / 256), 256, 0, stream>>>(Gp, G);
  // R = E*G[n]
  k_gemm64<0, 0><<<dim3(4, 4, NB), 256, 0, stream>>>(E, G, 0, CC, R, CC, nullptr, nullptr,
                                                     nullptr, nullptr, nullptr, nullptr);
  // At = (R*F + dlt*alp^T + gam*bet^T)/HW + dlt*bet^T  -> bf16 hi/lo
  k_gemm64<0, 1><<<dim3(4, 4, NB), 256, 0, stream>>>(R, F, CC, 0, nullptr, 0, Athi, Atlo,
                                                     dlt, alp, gam, bet);
  k_mv2<<<dim3(NB), 256, 0, stream>>>(G, w0, w3, b0, b1, b2, b3, tv, rv, v1, cv);
  // out = At * Xt^T + cv
  k_mfma_nt<1><<<dim3(2, 32, NB), 512, 0, stream>>>(
      Athi, Atlo, CC, CD, Xthi, Xtlo, (size_t)HW * CD, CD, out, (size_t)CD * HW, HW, 1,
      cv);
}

// Round 4
// 156.603 us; speedup vs baseline: 1.1108x; 1.1108x over previous
//
#include <hip/hip_runtime.h>

#define NB 4
#define CD 256
#define HW 4096
#define KSG 16
#define CC (CD * CD)

typedef __attribute__((ext_vector_type(8))) short bf16x8;
typedef __attribute__((ext_vector_type(4))) float f32x4;

__device__ inline unsigned short f2bf(float x) {
  unsigned int u = __float_as_uint(x);
  unsigned int r = (u + 0x7FFFu + ((u >> 16) & 1u)) >> 16;
  return (unsigned short)r;
}
__device__ inline float bfhi(unsigned short h) {
  return __uint_as_float(((unsigned int)h) << 16);
}
__device__ __forceinline__ void gload16(const unsigned short* g, unsigned short* l) {
  __builtin_amdgcn_global_load_lds((const __attribute__((address_space(1))) void*)g,
                                   (__attribute__((address_space(3))) void*)l, 16, 0, 0);
}

// ---------- convert X fp32 -> bf16 hi/lo ([c][p] and transposed [p][c]) + chansum partials ----------
__global__ __launch_bounds__(256) void k_convert(const float* __restrict__ X,
                                                 unsigned short* __restrict__ Uhi,
                                                 unsigned short* __restrict__ Ulo,
                                                 unsigned short* __restrict__ Xthi,
                                                 unsigned short* __restrict__ Xtlo,
                                                 float* __restrict__ psum) {
  int pt = blockIdx.x, ct = blockIdx.y, n = blockIdx.z;
  __shared__ unsigned int W[64][65];
  int t = threadIdx.x;
  int cl = t >> 2, pb = (t & 3) * 16;
  const float* Xp = X + ((size_t)n * CD + ct * 64 + cl) * HW + pt * 64 + pb;
  float x[16];
#pragma unroll
  for (int j = 0; j < 4; ++j) {
    float4 v = *(const float4*)(Xp + 4 * j);
    x[4 * j + 0] = v.x; x[4 * j + 1] = v.y; x[4 * j + 2] = v.z; x[4 * j + 3] = v.w;
  }
  float xs = 0.f;
  unsigned short h[16], l[16];
#pragma unroll
  for (int j = 0; j < 16; ++j) {
    xs += x[j];
    h[j] = f2bf(x[j]);
    l[j] = f2bf(x[j] - bfhi(h[j]));
    W[cl][pb + j] = (((unsigned int)h[j]) << 16) | l[j];
  }
  xs += __shfl_xor(xs, 1);
  xs += __shfl_xor(xs, 2);
  if ((t & 3) == 0) psum[((size_t)n * 64 + pt) * CD + ct * 64 + cl] = xs;
  size_t rowOff = ((size_t)n * CD + ct * 64 + cl) * HW + pt * 64 + pb;
#pragma unroll
  for (int j = 0; j < 4; ++j) {
    ushort4 vh, vl;
    vh.x = h[4 * j]; vh.y = h[4 * j + 1]; vh.z = h[4 * j + 2]; vh.w = h[4 * j + 3];
    vl.x = l[4 * j]; vl.y = l[4 * j + 1]; vl.z = l[4 * j + 2]; vl.w = l[4 * j + 3];
    *(ushort4*)(Uhi + rowOff + 4 * j) = vh;
    *(ushort4*)(Ulo + rowOff + 4 * j) = vl;
  }
  __syncthreads();
  int pl = t >> 2, cb = (t & 3) * 16;
  size_t rowT = ((size_t)n * HW + pt * 64 + pl) * CD + ct * 64 + cb;
#pragma unroll
  for (int j = 0; j < 4; ++j) {
    ushort4 vh, vl;
    unsigned int w0v = W[cb + 4 * j + 0][pl];
    unsigned int w1v = W[cb + 4 * j + 1][pl];
    unsigned int w2v = W[cb + 4 * j + 2][pl];
    unsigned int w3v = W[cb + 4 * j + 3][pl];
    vh.x = (unsigned short)(w0v >> 16); vl.x = (unsigned short)(w0v & 0xffff);
    vh.y = (unsigned short)(w1v >> 16); vl.y = (unsigned short)(w1v & 0xffff);
    vh.z = (unsigned short)(w2v >> 16); vl.z = (unsigned short)(w2v & 0xffff);
    vh.w = (unsigned short)(w3v >> 16); vl.w = (unsigned short)(w3v & 0xffff);
    *(ushort4*)(Xthi + rowT + 4 * j) = vh;
    *(ushort4*)(Xtlo + rowT + 4 * j) = vl;
  }
}

// ---------- weights-only vectors: v1 = W1^T b2, bet = W2^T b1, dlt = W3 b0, scal1 = b1.b2 ----------
__global__ __launch_bounds__(256) void k_w(const float* __restrict__ w1,
                                           const float* __restrict__ w2,
                                           const float* __restrict__ w3,
                                           const float* __restrict__ b0,
                                           const float* __restrict__ b1,
                                           const float* __restrict__ b2,
                                           float* __restrict__ v1, float* __restrict__ bet,
                                           float* __restrict__ dlt,
                                           float* __restrict__ scal1) {
  int task = blockIdx.x, t = threadIdx.x;
  __shared__ float vin[CD];
  if (task == 0) {
    vin[t] = b2[t];
    __syncthreads();
    float a = 0.f;
    for (int k = 0; k < CD; ++k) a += w1[(size_t)k * CD + t] * vin[k];
    v1[t] = a;
  } else if (task == 1) {
    vin[t] = b1[t];
    __syncthreads();
    float a = 0.f;
    for (int k = 0; k < CD; ++k) a += w2[(size_t)k * CD + t] * vin[k];
    bet[t] = a;
  } else {
    __shared__ float red[256];
    red[t] = b1[t] * b2[t];
    __syncthreads();
    for (int off = 128; off > 0; off >>= 1) {
      if (t < off) red[t] += red[t + off];
      __syncthreads();
    }
    if (t == 0) scal1[0] = red[0];
    int lane = t & 63, wv = t >> 6;
    float4 bv = *(const float4*)(b0 + lane * 4);
    for (int i = 0; i < 64; ++i) {
      int o = wv * 64 + i;
      float4 v = *(const float4*)(w3 + (size_t)o * CD + lane * 4);
      float a = v.x * bv.x + v.y * bv.y + v.z * bv.z + v.w * bv.w;
      a += __shfl_xor(a, 1);  a += __shfl_xor(a, 2);  a += __shfl_xor(a, 4);
      a += __shfl_xor(a, 8);  a += __shfl_xor(a, 16); a += __shfl_xor(a, 32);
      if (lane == 0) dlt[o] = a;
    }
  }
}

// ---------- s[n] from psum; scal0[n] = s.v1 ----------
__global__ __launch_bounds__(256) void k_s(const float* __restrict__ psum,
                                           const float* __restrict__ v1,
                                           float* __restrict__ sx,
                                           float* __restrict__ scal0) {
  int n = blockIdx.x, c = threadIdx.x;
  float a = 0.f;
  for (int pt = 0; pt < 64; ++pt) a += psum[((size_t)n * 64 + pt) * CD + c];
  sx[n * CD + c] = a;
  __shared__ float red[256];
  red[c] = a * v1[c];
  __syncthreads();
  for (int off = 128; off > 0; off >>= 1) {
    if (c < off) red[c] += red[c + off];
    __syncthreads();
  }
  if (c == 0) scal0[n] = red[0];
}

// ---------- alp[n] = F^T s, gam[n] = E s (via Et colmode) ----------
__global__ __launch_bounds__(256) void k_ag(const float* __restrict__ F,
                                            const float* __restrict__ Et,
                                            const float* __restrict__ sx,
                                            float* __restrict__ alp,
                                            float* __restrict__ gam) {
  int n = blockIdx.x, o = threadIdx.x;
  __shared__ float sh[CD];
  sh[o] = sx[n * CD + o];
  __syncthreads();
  float a = 0.f, g = 0.f;
  for (int k = 0; k < CD; ++k) {
    float sk = sh[k];
    a += F[(size_t)k * CD + o] * sk;
    g += Et[(size_t)k * CD + o] * sk;
  }
  alp[n * CD + o] = a;
  gam[n * CD + o] = g;
}

// ---------- cv[n] = (E (G v1) + scal0 dlt + scal1 (gam + HW dlt))/HW + b3 ----------
__global__ __launch_bounds__(256) void k_cv(const float* __restrict__ G,
                                            const float* __restrict__ Et,
                                            const float* __restrict__ v1,
                                            const float* __restrict__ dlt,
                                            const float* __restrict__ gam,
                                            const float* __restrict__ scal0,
                                            const float* __restrict__ scal1,
                                            const float* __restrict__ b3,
                                            float* __restrict__ cv) {
  int n = blockIdx.x, o = threadIdx.x;
  __shared__ float vsh[CD], g1[CD];
  vsh[o] = v1[o];
  __syncthreads();
  const float* Gn = G + (size_t)n * CC;
  float a = 0.f;
  for (int k = 0; k < CD; ++k) a += Gn[(size_t)k * CD + o] * vsh[k];  // G symmetric
  g1[o] = a;
  __syncthreads();
  float c2 = 0.f;
  for (int k = 0; k < CD; ++k) c2 += Et[(size_t)k * CD + o] * g1[k];
  float s0 = scal0[n], s1 = scal1[0];
  cv[n * CD + o] =
      (c2 + s0 * dlt[o] + s1 * (gam[n * CD + o] + (float)HW * dlt[o])) * (1.0f / HW) +
      b3[o];
}

// ---------- fp32 64x64-tile GEMM (small 256^3), K=256 in 2 stages; TA: A col-major ----------
// EPI=0: write C0 (+ Ct transposed copy if non-null). EPI=1: bf16 hi/lo At epilogue.
template <int TA, int EPI>
__global__ __launch_bounds__(256) void k_gemm64(
    const float* __restrict__ A, const float* __restrict__ B, size_t aStride,
    size_t bStride, float* __restrict__ C0, float* __restrict__ Ct, size_t cStride,
    unsigned short* __restrict__ Ohi, unsigned short* __restrict__ Olo,
    const float* __restrict__ dlt, const float* __restrict__ alp,
    const float* __restrict__ gam, const float* __restrict__ bet) {
  int i0 = blockIdx.x * 64, j0 = blockIdx.y * 64, n = blockIdx.z;
  const float* An = A + (size_t)n * aStride;
  const float* Bn = B + (size_t)n * bStride;
  __shared__ __align__(16) float As[TA ? 128 * 68 : 64 * 132];
  __shared__ __align__(16) float Bs[128 * 68];
  int t = threadIdx.x, tx = t & 15, ty = t >> 4;
  float acc[4][4] = {};
  for (int s = 0; s < 2; ++s) {
    int kb = s * 128;
    if (TA == 0) {
#pragma unroll
      for (int j = 0; j < 8; ++j) {
        int flat = t + j * 256;
        int i = flat >> 5, c4 = (flat & 31) * 4;
        *(float4*)&As[i * 132 + c4] = *(const float4*)(An + (size_t)(i0 + i) * CD + kb + c4);
      }
    } else {
#pragma unroll
      for (int j = 0; j < 8; ++j) {
        int flat = t + j * 256;
        int k = flat >> 4, c4 = (flat & 15) * 4;
        *(float4*)&As[k * 68 + c4] = *(const float4*)(An + (size_t)(kb + k) * CD + i0 + c4);
      }
    }
#pragma unroll
    for (int j = 0; j < 8; ++j) {
      int flat = t + j * 256;
      int k = flat >> 4, c4 = (flat & 15) * 4;
      *(float4*)&Bs[k * 68 + c4] = *(const float4*)(Bn + (size_t)(kb + k) * CD + j0 + c4);
    }
    __syncthreads();
    for (int k = 0; k < 128; ++k) {
      float a0, a1, a2, a3;
      if (TA == 0) {
        a0 = As[(ty * 4 + 0) * 132 + k];
        a1 = As[(ty * 4 + 1) * 132 + k];
        a2 = As[(ty * 4 + 2) * 132 + k];
        a3 = As[(ty * 4 + 3) * 132 + k];
      } else {
        float4 av = *(const float4*)&As[k * 68 + ty * 4];
        a0 = av.x; a1 = av.y; a2 = av.z; a3 = av.w;
      }
      float4 bv = *(const float4*)&Bs[k * 68 + tx * 4];
      float b[4] = {bv.x, bv.y, bv.z, bv.w};
      float a[4] = {a0, a1, a2, a3};
#pragma unroll
      for (int m = 0; m < 4; ++m)
#pragma unroll
        for (int q = 0; q < 4; ++q) acc[m][q] = fmaf(a[m], b[q], acc[m][q]);
    }
    __syncthreads();
  }
  if (EPI == 0) {
    float* Cn = C0 + (size_t)n * cStride;
#pragma unroll
    for (int m = 0; m < 4; ++m)
#pragma unroll
      for (int q = 0; q < 4; ++q)
        Cn[(size_t)(i0 + ty * 4 + m) * CD + j0 + tx * 4 + q] = acc[m][q];
    if (Ct) {
#pragma unroll
      for (int m = 0; m < 4; ++m)
#pragma unroll
        for (int q = 0; q < 4; ++q)
          Ct[(size_t)(j0 + tx * 4 + q) * CD + i0 + ty * 4 + m] = acc[m][q];
    }
  } else {
#pragma unroll
    for (int m = 0; m < 4; ++m) {
      int i = i0 + ty * 4 + m;
      float di = dlt[i];
      float gi = gam[n * CD + i];
#pragma unroll
      for (int q = 0; q < 4; ++q) {
        int j = j0 + tx * 4 + q;
        float bj = bet[j];
        float aj = alp[n * CD + j];
        float v = (acc[m][q] + di * aj + gi * bj) * (1.0f / HW) + di * bj;
        unsigned short hh = f2bf(v);
        unsigned short ll = f2bf(v - bfhi(hh));
        Ohi[(size_t)n * CC + (size_t)i * CD + j] = hh;
        Olo[(size_t)n * CC + (size_t)i * CD + j] = ll;
      }
    }
  }
}

// ---------- NT MFMA GEMM, m97-style: 512 thr, 128x128 tile, BK=64, global_load_lds ----------
template <int EPI>
__global__ __launch_bounds__(512) void k_mfma_nt(
    const unsigned short* __restrict__ Phi, const unsigned short* __restrict__ Plo,
    size_t pStride, int ldP, const unsigned short* __restrict__ Qhi,
    const unsigned short* __restrict__ Qlo, size_t qStride, int ldQ,
    float* __restrict__ Cout, size_t cStride, int ldC, int KS,
    const float* __restrict__ cv) {
  int z = blockIdx.z, n = z / KS, ks = z % KS;
  int i0 = blockIdx.x * 128, j0 = blockIdx.y * 128;
  int kBegin = ks * 256;
  const unsigned short* pH = Phi + (size_t)n * pStride;
  const unsigned short* pL = Plo + (size_t)n * pStride;
  const unsigned short* qH = Qhi + (size_t)n * qStride;
  const unsigned short* qL = Qlo + (size_t)n * qStride;
  float* cPtr = Cout + ((size_t)ks * NB + n) * cStride;

  __shared__ __align__(16) unsigned short sm[4 * 128 * 64];

  int t = threadIdx.x;
  int lane = t & 63, wid = t >> 6;
  int wr = wid >> 2, wc = wid & 3;
  int lrow = lane & 15, lkb = lane >> 4;

  int tsel = wid >> 1;
  int gbase = (wid & 1) * 8;
  const unsigned short* bp = (tsel == 0) ? pH : (tsel == 1) ? pL : (tsel == 2) ? qH : qL;
  int tb = (tsel < 2) ? i0 : j0;
  int ldT = (tsel < 2) ? ldP : ldQ;
  int rsub = lane >> 3;
  int gc = (lane & 7) ^ rsub;
  unsigned short* ldsT = sm + (size_t)tsel * 128 * 64;

  f32x4 acc[4][2];
#pragma unroll
  for (int m = 0; m < 4; ++m)
#pragma unroll
    for (int q = 0; q < 2; ++q) acc[m][q] = (f32x4){0.f, 0.f, 0.f, 0.f};

  for (int k0 = 0; k0 < 256; k0 += 64) {
    int kb = kBegin + k0;
#pragma unroll
    for (int s = 0; s < 8; ++s) {
      int g = gbase + s;
      gload16(bp + (size_t)(tb + g * 8 + rsub) * ldT + kb + gc * 8, ldsT + g * 8 * 64);
    }
    __syncthreads();
#pragma unroll
    for (int ks2 = 0; ks2 < 2; ++ks2) {
      bf16x8 ah[4], al[4], bh[2], bl[2];
#pragma unroll
      for (int m = 0; m < 4; ++m) {
        int r = wr * 64 + m * 16 + lrow;
        int sw = ((ks2 * 4 + lkb) ^ (r & 7)) * 8;
        ah[m] = *(const bf16x8*)(sm + 0 * 8192 + r * 64 + sw);
        al[m] = *(const bf16x8*)(sm + 1 * 8192 + r * 64 + sw);
      }
#pragma unroll
      for (int q = 0; q < 2; ++q) {
        int r = wc * 32 + q * 16 + lrow;
        int sw = ((ks2 * 4 + lkb) ^ (r & 7)) * 8;
        bh[q] = *(const bf16x8*)(sm + 2 * 8192 + r * 64 + sw);
        bl[q] = *(const bf16x8*)(sm + 3 * 8192 + r * 64 + sw);
      }
#pragma unroll
      for (int m = 0; m < 4; ++m)
#pragma unroll
        for (int q = 0; q < 2; ++q) {
          acc[m][q] = __builtin_amdgcn_mfma_f32_16x16x32_bf16(ah[m], bh[q], acc[m][q], 0, 0, 0);
          acc[m][q] = __builtin_amdgcn_mfma_f32_16x16x32_bf16(ah[m], bl[q], acc[m][q], 0, 0, 0);
          acc[m][q] = __builtin_amdgcn_mfma_f32_16x16x32_bf16(al[m], bh[q], acc[m][q], 0, 0, 0);
        }
    }
    __syncthreads();
  }
#pragma unroll
  for (int m = 0; m < 4; ++m) {
    int row = i0 + wr * 64 + m * 16 + (lane >> 4) * 4;
#pragma unroll
    for (int q = 0; q < 2; ++q) {
      int col = j0 + wc * 32 + q * 16 + (lane & 15);
#pragma unroll
      for (int e = 0; e < 4; ++e) {
        float v = acc[m][q][e];
        if (EPI == 1) v += cv[n * CD + row + e];
        cPtr[(size_t)(row + e) * ldC + col] = v;
      }
    }
  }
}

// ---------- reduce gram K-split partials ----------
__global__ void k_gram_reduce(const float* __restrict__ Gp, float* __restrict__ G) {
  size_t idx = (size_t)blockIdx.x * 256 + threadIdx.x;
  float a = 0.f;
#pragma unroll
  for (int ks = 0; ks < KSG; ++ks) a += Gp[(size_t)ks * NB * CC + idx];
  G[idx] = a;
}

extern "C" void kernel_launch(void* const* d_in, const int* in_sizes, int n_in,
                              void* d_out, int out_size, void* d_ws, size_t ws_size,
                              hipStream_t stream) {
  const float* X = (const float*)d_in[0];
  const float* w0 = (const float*)d_in[1];
  const float* b0 = (const float*)d_in[2];
  const float* w1 = (const float*)d_in[3];
  const float* b1 = (const float*)d_in[4];
  const float* w2 = (const float*)d_in[5];
  const float* b2 = (const float*)d_in[6];
  const float* w3 = (const float*)d_in[7];
  const float* b3 = (const float*)d_in[8];
  float* out = (float*)d_out;
  float* ws = (float*)d_ws;

  float* sx = ws;                      // NB*CD
  float* cv = ws + 1024;
  float* alp = ws + 2048;
  float* gam = ws + 3072;
  float* bet = ws + 4096;
  float* dlt = ws + 5120;
  float* v1 = ws + 6144;
  float* scal0 = ws + 7168;            // NB
  float* scal1 = ws + 7200;            // 1
  float* psum = ws + 8192;             // NB*64*CD = 65536
  float* E = psum + 65536;
  float* Et = E + CC;
  float* F = Et + CC;
  float* G = F + CC;                   // NB*CC
  float* R = G + (size_t)NB * CC;
  unsigned short* Athi = (unsigned short*)(R + (size_t)NB * CC);
  unsigned short* Atlo = Athi + (size_t)NB * CC;
  unsigned short* Uhi = Atlo + (size_t)NB * CC;
  unsigned short* Ulo = Uhi + (size_t)NB * CD * HW;
  unsigned short* Xthi = Ulo + (size_t)NB * CD * HW;
  unsigned short* Xtlo = Xthi + (size_t)NB * CD * HW;
  float* Gp = (float*)(Xtlo + (size_t)NB * CD * HW);  // KSG*NB*CC floats

  k_convert<<<dim3(HW / 64, CD / 64, NB), 256, 0, stream>>>(X, Uhi, Ulo, Xthi, Xtlo, psum);
  // Gram partials via MFMA (the long pole)
  k_mfma_nt<0><<<dim3(2, 2, NB * KSG), 512, 0, stream>>>(
      Uhi, Ulo, (size_t)CD * HW, HW, Uhi, Ulo, (size_t)CD * HW, HW, Gp, CC, CD, KSG,
      nullptr);
  k_w<<<dim3(3), 256, 0, stream>>>(w1, w2, w3, b0, b1, b2, v1, bet, dlt, scal1);
  k_s<<<dim3(NB), 256, 0, stream>>>(psum, v1, sx, scal0);
  // E = W3*W0 (NN, + transposed copy Et), F = W1^T*W2 (TN)
  k_gemm64<0, 0><<<dim3(4, 4, 1), 256, 0, stream>>>(w3, w0, 0, 0, E, Et, 0, nullptr,
                                                    nullptr, nullptr, nullptr, nullptr,
                                                    nullptr);
  k_gemm64<1, 0><<<dim3(4, 4, 1), 256, 0, stream>>>(w1, w2, 0, 0, F, nullptr, 0, nullptr,
                                                    nullptr, nullptr, nullptr, nullptr,
                                                    nullptr);
  k_ag<<<dim3(NB), 256, 0, stream>>>(F, Et, sx, alp, gam);
  k_gram_reduce<<<dim3(NB * CC / 256), 256, 0, stream>>>(Gp, G);
  // R = E*G[n]
  k_gemm64<0, 0><<<dim3(4, 4, NB), 256, 0, stream>>>(E, G, 0, CC, R, nullptr, CC, nullptr,
                                                     nullptr, nullptr, nullptr, nullptr,
                                                     nullptr);
  // At = (R*F + dlt*alp^T + gam*bet^T)/HW + dlt*bet^T  -> bf16 hi/lo
  k_gemm64<0, 1><<<dim3(4, 4, NB), 256, 0, stream>>>(R, F, CC, 0, nullptr, nullptr, 0,
                                                     Athi, Atlo, dlt, alp, gam, bet);
  k_cv<<<dim3(NB), 256, 0, stream>>>(G, Et, v1, dlt, gam, scal0, scal1, b3, cv);
  // out = At * Xt^T + cv
  k_mfma_nt<1><<<dim3(2, 32, NB), 512, 0, stream>>>(
      Athi, Atlo, CC, CD, Xthi, Xtlo, (size_t)HW * CD, CD, out, (size_t)CD * HW, HW, 1,
      cv);
}

// Round 5
// 118.810 us; speedup vs baseline: 1.4642x; 1.3181x over previous
//
#include <hip/hip_runtime.h>

#define NB 4
#define CD 256
#define HW 4096
#define KSG 16
#define CC (CD * CD)

typedef __attribute__((ext_vector_type(8))) short bf16x8;
typedef __attribute__((ext_vector_type(4))) float f32x4;

__device__ inline unsigned short f2bf(float x) {
  unsigned int u = __float_as_uint(x);
  unsigned int r = (u + 0x7FFFu + ((u >> 16) & 1u)) >> 16;
  return (unsigned short)r;
}
__device__ inline float bfhi(unsigned short h) {
  return __uint_as_float(((unsigned int)h) << 16);
}
__device__ __forceinline__ void gload16(const unsigned short* g, unsigned short* l) {
  __builtin_amdgcn_global_load_lds((const __attribute__((address_space(1))) void*)g,
                                   (__attribute__((address_space(3))) void*)l, 16, 0, 0);
}

// ---------- convert X fp32 -> bf16 hi/lo ([c][p] and transposed [p][c]) + chansum partials ----------
__global__ __launch_bounds__(256) void k_convert(const float* __restrict__ X,
                                                 unsigned short* __restrict__ Uhi,
                                                 unsigned short* __restrict__ Ulo,
                                                 unsigned short* __restrict__ Xthi,
                                                 unsigned short* __restrict__ Xtlo,
                                                 float* __restrict__ psum) {
  int pt = blockIdx.x, ct = blockIdx.y, n = blockIdx.z;
  __shared__ unsigned int W[64][65];
  int t = threadIdx.x;
  int cl = t >> 2, pb = (t & 3) * 16;
  const float* Xp = X + ((size_t)n * CD + ct * 64 + cl) * HW + pt * 64 + pb;
  float x[16];
#pragma unroll
  for (int j = 0; j < 4; ++j) {
    float4 v = *(const float4*)(Xp + 4 * j);
    x[4 * j + 0] = v.x; x[4 * j + 1] = v.y; x[4 * j + 2] = v.z; x[4 * j + 3] = v.w;
  }
  float xs = 0.f;
  unsigned short h[16], l[16];
#pragma unroll
  for (int j = 0; j < 16; ++j) {
    xs += x[j];
    h[j] = f2bf(x[j]);
    l[j] = f2bf(x[j] - bfhi(h[j]));
    W[cl][pb + j] = (((unsigned int)h[j]) << 16) | l[j];
  }
  xs += __shfl_xor(xs, 1);
  xs += __shfl_xor(xs, 2);
  if ((t & 3) == 0) psum[((size_t)n * 64 + pt) * CD + ct * 64 + cl] = xs;
  size_t rowOff = ((size_t)n * CD + ct * 64 + cl) * HW + pt * 64 + pb;
#pragma unroll
  for (int j = 0; j < 4; ++j) {
    ushort4 vh, vl;
    vh.x = h[4 * j]; vh.y = h[4 * j + 1]; vh.z = h[4 * j + 2]; vh.w = h[4 * j + 3];
    vl.x = l[4 * j]; vl.y = l[4 * j + 1]; vl.z = l[4 * j + 2]; vl.w = l[4 * j + 3];
    *(ushort4*)(Uhi + rowOff + 4 * j) = vh;
    *(ushort4*)(Ulo + rowOff + 4 * j) = vl;
  }
  __syncthreads();
  int pl = t >> 2, cb = (t & 3) * 16;
  size_t rowT = ((size_t)n * HW + pt * 64 + pl) * CD + ct * 64 + cb;
#pragma unroll
  for (int j = 0; j < 4; ++j) {
    ushort4 vh, vl;
    unsigned int w0v = W[cb + 4 * j + 0][pl];
    unsigned int w1v = W[cb + 4 * j + 1][pl];
    unsigned int w2v = W[cb + 4 * j + 2][pl];
    unsigned int w3v = W[cb + 4 * j + 3][pl];
    vh.x = (unsigned short)(w0v >> 16); vl.x = (unsigned short)(w0v & 0xffff);
    vh.y = (unsigned short)(w1v >> 16); vl.y = (unsigned short)(w1v & 0xffff);
    vh.z = (unsigned short)(w2v >> 16); vl.z = (unsigned short)(w2v & 0xffff);
    vh.w = (unsigned short)(w3v >> 16); vl.w = (unsigned short)(w3v & 0xffff);
    *(ushort4*)(Xthi + rowT + 4 * j) = vh;
    *(ushort4*)(Xtlo + rowT + 4 * j) = vl;
  }
}

// ---------- weight-vector products, latency-parallel ----------
// blocks 0-3: vp[b][o]  partial of v1 = W1^T b2 over k in [b*64,b*64+64)
// blocks 4-7: bp[b-4][o] partial of bet = W2^T b1
// blocks 8-11: dlt = W3 b0 (wave-per-output, float4 rows)
// block 12: scal1 = b1.b2
__global__ __launch_bounds__(256) void k_wv(const float* __restrict__ w1,
                                            const float* __restrict__ w2,
                                            const float* __restrict__ w3,
                                            const float* __restrict__ b0,
                                            const float* __restrict__ b1,
                                            const float* __restrict__ b2,
                                            float* __restrict__ vp, float* __restrict__ bp,
                                            float* __restrict__ dlt,
                                            float* __restrict__ scal1) {
  int b = blockIdx.x, t = threadIdx.x;
  if (b < 8) {
    __shared__ float vin[64];
    int seg = b & 3;
    const float* W = (b < 4) ? w1 : w2;
    const float* v = (b < 4) ? b2 : b1;
    float* dst = (b < 4) ? (vp + seg * CD) : (bp + seg * CD);
    if (t < 64) vin[t] = v[seg * 64 + t];
    __syncthreads();
    float a = 0.f;
#pragma unroll 16
    for (int kk = 0; kk < 64; ++kk)
      a += W[(size_t)(seg * 64 + kk) * CD + t] * vin[kk];
    dst[t] = a;
  } else if (b < 12) {
    int lane = t & 63, wv = t >> 6;
    float4 bv = *(const float4*)(b0 + lane * 4);
#pragma unroll 4
    for (int i = 0; i < 16; ++i) {
      int o = (b - 8) * 64 + wv * 16 + i;
      float4 v = *(const float4*)(w3 + (size_t)o * CD + lane * 4);
      float a = v.x * bv.x + v.y * bv.y + v.z * bv.z + v.w * bv.w;
      a += __shfl_xor(a, 1);  a += __shfl_xor(a, 2);  a += __shfl_xor(a, 4);
      a += __shfl_xor(a, 8);  a += __shfl_xor(a, 16); a += __shfl_xor(a, 32);
      if (lane == 0) dlt[o] = a;
    }
  } else {
    __shared__ float red[256];
    red[t] = b1[t] * b2[t];
    __syncthreads();
    for (int off = 128; off > 0; off >>= 1) {
      if (t < off) red[t] += red[t + off];
      __syncthreads();
    }
    if (t == 0) scal1[0] = red[0];
  }
}

// ---------- combined E = W3*W0 (NN, +Et) and F = W1^T*W2 (TN) ----------
__global__ __launch_bounds__(256) void k_EF(const float* __restrict__ w3,
                                            const float* __restrict__ w0,
                                            const float* __restrict__ w1,
                                            const float* __restrict__ w2,
                                            float* __restrict__ E, float* __restrict__ Et,
                                            float* __restrict__ F) {
  int i0 = blockIdx.x * 64, j0 = blockIdx.y * 64, z = blockIdx.z;
  __shared__ __align__(16) float As[8704];
  __shared__ __align__(16) float Bs[128 * 68];
  int t = threadIdx.x, tx = t & 15, ty = t >> 4;
  float acc[4][4] = {};
  const float* A = z ? w1 : w3;
  const float* B = z ? w2 : w0;
  for (int s = 0; s < 2; ++s) {
    int kb = s * 128;
    if (z == 0) {
#pragma unroll
      for (int j = 0; j < 8; ++j) {
        int flat = t + j * 256;
        int i = flat >> 5, c4 = (flat & 31) * 4;
        *(float4*)&As[i * 132 + c4] = *(const float4*)(A + (size_t)(i0 + i) * CD + kb + c4);
      }
    } else {
#pragma unroll
      for (int j = 0; j < 8; ++j) {
        int flat = t + j * 256;
        int k = flat >> 4, c4 = (flat & 15) * 4;
        *(float4*)&As[k * 68 + c4] = *(const float4*)(A + (size_t)(kb + k) * CD + i0 + c4);
      }
    }
#pragma unroll
    for (int j = 0; j < 8; ++j) {
      int flat = t + j * 256;
      int k = flat >> 4, c4 = (flat & 15) * 4;
      *(float4*)&Bs[k * 68 + c4] = *(const float4*)(B + (size_t)(kb + k) * CD + j0 + c4);
    }
    __syncthreads();
    if (z == 0) {
      for (int k = 0; k < 128; ++k) {
        float a[4] = {As[(ty * 4 + 0) * 132 + k], As[(ty * 4 + 1) * 132 + k],
                      As[(ty * 4 + 2) * 132 + k], As[(ty * 4 + 3) * 132 + k]};
        float4 bv = *(const float4*)&Bs[k * 68 + tx * 4];
        float bb[4] = {bv.x, bv.y, bv.z, bv.w};
#pragma unroll
        for (int m = 0; m < 4; ++m)
#pragma unroll
          for (int q = 0; q < 4; ++q) acc[m][q] = fmaf(a[m], bb[q], acc[m][q]);
      }
    } else {
      for (int k = 0; k < 128; ++k) {
        float4 av = *(const float4*)&As[k * 68 + ty * 4];
        float a[4] = {av.x, av.y, av.z, av.w};
        float4 bv = *(const float4*)&Bs[k * 68 + tx * 4];
        float bb[4] = {bv.x, bv.y, bv.z, bv.w};
#pragma unroll
        for (int m = 0; m < 4; ++m)
#pragma unroll
          for (int q = 0; q < 4; ++q) acc[m][q] = fmaf(a[m], bb[q], acc[m][q]);
      }
    }
    __syncthreads();
  }
  if (z == 0) {
#pragma unroll
    for (int m = 0; m < 4; ++m)
#pragma unroll
      for (int q = 0; q < 4; ++q) {
        E[(size_t)(i0 + ty * 4 + m) * CD + j0 + tx * 4 + q] = acc[m][q];
        Et[(size_t)(j0 + tx * 4 + q) * CD + i0 + ty * 4 + m] = acc[m][q];
      }
  } else {
#pragma unroll
    for (int m = 0; m < 4; ++m)
#pragma unroll
      for (int q = 0; q < 4; ++q)
        F[(size_t)(i0 + ty * 4 + m) * CD + j0 + tx * 4 + q] = acc[m][q];
  }
}

// ---------- s from psum; scal0 = s.v1; alp = F^T s; gam = E s ----------
__global__ __launch_bounds__(256) void k_sag(const float* __restrict__ psum,
                                             const float* __restrict__ vp,
                                             const float* __restrict__ F,
                                             const float* __restrict__ Et,
                                             float* __restrict__ alp,
                                             float* __restrict__ gam,
                                             float* __restrict__ scal0) {
  int n = blockIdx.x, c = threadIdx.x;
  __shared__ float ss[CD];
  __shared__ float red[256];
  float a = 0.f;
#pragma unroll 16
  for (int pt = 0; pt < 64; ++pt) a += psum[((size_t)n * 64 + pt) * CD + c];
  ss[c] = a;
  float v1c = vp[c] + vp[CD + c] + vp[2 * CD + c] + vp[3 * CD + c];
  red[c] = a * v1c;
  __syncthreads();
  for (int off = 128; off > 0; off >>= 1) {
    if (c < off) red[c] += red[c + off];
    __syncthreads();
  }
  if (c == 0) scal0[n] = red[0];
  float al = 0.f, ga = 0.f;
#pragma unroll 16
  for (int k = 0; k < CD; ++k) {
    float sk = ss[k];
    al += F[(size_t)k * CD + c] * sk;
    ga += Et[(size_t)k * CD + c] * sk;
  }
  alp[n * CD + c] = al;
  gam[n * CD + c] = ga;
}

// ---------- cv[n] = (E (G v1) + scal0 dlt + scal1 (gam + HW dlt))/HW + b3 ----------
__global__ __launch_bounds__(256) void k_cv(const float* __restrict__ G,
                                            const float* __restrict__ Et,
                                            const float* __restrict__ vp,
                                            const float* __restrict__ dlt,
                                            const float* __restrict__ gam,
                                            const float* __restrict__ scal0,
                                            const float* __restrict__ scal1,
                                            const float* __restrict__ b3,
                                            float* __restrict__ cv) {
  int n = blockIdx.x, o = threadIdx.x;
  __shared__ float vsh[CD], g1[CD];
  vsh[o] = vp[o] + vp[CD + o] + vp[2 * CD + o] + vp[3 * CD + o];
  __syncthreads();
  const float* Gn = G + (size_t)n * CC;
  float a = 0.f;
#pragma unroll 16
  for (int k = 0; k < CD; ++k) a += Gn[(size_t)k * CD + o] * vsh[k];  // G symmetric
  g1[o] = a;
  __syncthreads();
  float c2 = 0.f;
#pragma unroll 16
  for (int k = 0; k < CD; ++k) c2 += Et[(size_t)k * CD + o] * g1[k];
  float s0 = scal0[n], s1 = scal1[0];
  cv[n * CD + o] =
      (c2 + s0 * dlt[o] + s1 * (gam[n * CD + o] + (float)HW * dlt[o])) * (1.0f / HW) +
      b3[o];
}

// ---------- fp32 64x64-tile GEMM, K=256 in 2 stages (NN only) ----------
// EPI=0: write C0. EPI=1: bf16 hi/lo At epilogue (bet from 4 partials bp).
template <int EPI>
__global__ __launch_bounds__(256) void k_gemm64(
    const float* __restrict__ A, const float* __restrict__ B, size_t aStride,
    size_t bStride, float* __restrict__ C0, size_t cStride,
    unsigned short* __restrict__ Ohi, unsigned short* __restrict__ Olo,
    const float* __restrict__ dlt, const float* __restrict__ alp,
    const float* __restrict__ gam, const float* __restrict__ bp) {
  int i0 = blockIdx.x * 64, j0 = blockIdx.y * 64, n = blockIdx.z;
  const float* An = A + (size_t)n * aStride;
  const float* Bn = B + (size_t)n * bStride;
  __shared__ __align__(16) float As[64 * 132];
  __shared__ __align__(16) float Bs[128 * 68];
  int t = threadIdx.x, tx = t & 15, ty = t >> 4;
  float acc[4][4] = {};
  for (int s = 0; s < 2; ++s) {
    int kb = s * 128;
#pragma unroll
    for (int j = 0; j < 8; ++j) {
      int flat = t + j * 256;
      int i = flat >> 5, c4 = (flat & 31) * 4;
      *(float4*)&As[i * 132 + c4] = *(const float4*)(An + (size_t)(i0 + i) * CD + kb + c4);
    }
#pragma unroll
    for (int j = 0; j < 8; ++j) {
      int flat = t + j * 256;
      int k = flat >> 4, c4 = (flat & 15) * 4;
      *(float4*)&Bs[k * 68 + c4] = *(const float4*)(Bn + (size_t)(kb + k) * CD + j0 + c4);
    }
    __syncthreads();
    for (int k = 0; k < 128; ++k) {
      float a[4] = {As[(ty * 4 + 0) * 132 + k], As[(ty * 4 + 1) * 132 + k],
                    As[(ty * 4 + 2) * 132 + k], As[(ty * 4 + 3) * 132 + k]};
      float4 bv = *(const float4*)&Bs[k * 68 + tx * 4];
      float bb[4] = {bv.x, bv.y, bv.z, bv.w};
#pragma unroll
      for (int m = 0; m < 4; ++m)
#pragma unroll
        for (int q = 0; q < 4; ++q) acc[m][q] = fmaf(a[m], bb[q], acc[m][q]);
    }
    __syncthreads();
  }
  if (EPI == 0) {
    float* Cn = C0 + (size_t)n * cStride;
#pragma unroll
    for (int m = 0; m < 4; ++m)
#pragma unroll
      for (int q = 0; q < 4; ++q)
        Cn[(size_t)(i0 + ty * 4 + m) * CD + j0 + tx * 4 + q] = acc[m][q];
  } else {
#pragma unroll
    for (int m = 0; m < 4; ++m) {
      int i = i0 + ty * 4 + m;
      float di = dlt[i];
      float gi = gam[n * CD + i];
#pragma unroll
      for (int q = 0; q < 4; ++q) {
        int j = j0 + tx * 4 + q;
        float bj = bp[j] + bp[CD + j] + bp[2 * CD + j] + bp[3 * CD + j];
        float aj = alp[n * CD + j];
        float v = (acc[m][q] + di * aj + gi * bj) * (1.0f / HW) + di * bj;
        unsigned short hh = f2bf(v);
        unsigned short ll = f2bf(v - bfhi(hh));
        Ohi[(size_t)n * CC + (size_t)i * CD + j] = hh;
        Olo[(size_t)n * CC + (size_t)i * CD + j] = ll;
      }
    }
  }
}

// ---------- NT MFMA GEMM, m97-style: 512 thr, 128x128 tile, BK=64, global_load_lds ----------
template <int EPI>
__global__ __launch_bounds__(512) void k_mfma_nt(
    const unsigned short* __restrict__ Phi, const unsigned short* __restrict__ Plo,
    size_t pStride, int ldP, const unsigned short* __restrict__ Qhi,
    const unsigned short* __restrict__ Qlo, size_t qStride, int ldQ,
    float* __restrict__ Cout, size_t cStride, int ldC, int KS,
    const float* __restrict__ cv) {
  int z = blockIdx.z, n = z / KS, ks = z % KS;
  int i0 = blockIdx.x * 128, j0 = blockIdx.y * 128;
  int kBegin = ks * 256;
  const unsigned short* pH = Phi + (size_t)n * pStride;
  const unsigned short* pL = Plo + (size_t)n * pStride;
  const unsigned short* qH = Qhi + (size_t)n * qStride;
  const unsigned short* qL = Qlo + (size_t)n * qStride;
  float* cPtr = Cout + ((size_t)ks * NB + n) * cStride;

  __shared__ __align__(16) unsigned short sm[4 * 128 * 64];

  int t = threadIdx.x;
  int lane = t & 63, wid = t >> 6;
  int wr = wid >> 2, wc = wid & 3;
  int lrow = lane & 15, lkb = lane >> 4;

  int tsel = wid >> 1;
  int gbase = (wid & 1) * 8;
  const unsigned short* bp2 = (tsel == 0) ? pH : (tsel == 1) ? pL : (tsel == 2) ? qH : qL;
  int tb = (tsel < 2) ? i0 : j0;
  int ldT = (tsel < 2) ? ldP : ldQ;
  int rsub = lane >> 3;
  int gc = (lane & 7) ^ rsub;
  unsigned short* ldsT = sm + (size_t)tsel * 128 * 64;

  f32x4 acc[4][2];
#pragma unroll
  for (int m = 0; m < 4; ++m)
#pragma unroll
    for (int q = 0; q < 2; ++q) acc[m][q] = (f32x4){0.f, 0.f, 0.f, 0.f};

  for (int k0 = 0; k0 < 256; k0 += 64) {
    int kb = kBegin + k0;
#pragma unroll
    for (int s = 0; s < 8; ++s) {
      int g = gbase + s;
      gload16(bp2 + (size_t)(tb + g * 8 + rsub) * ldT + kb + gc * 8, ldsT + g * 8 * 64);
    }
    __syncthreads();
#pragma unroll
    for (int ks2 = 0; ks2 < 2; ++ks2) {
      bf16x8 ah[4], al[4], bh[2], bl[2];
#pragma unroll
      for (int m = 0; m < 4; ++m) {
        int r = wr * 64 + m * 16 + lrow;
        int sw = ((ks2 * 4 + lkb) ^ (r & 7)) * 8;
        ah[m] = *(const bf16x8*)(sm + 0 * 8192 + r * 64 + sw);
        al[m] = *(const bf16x8*)(sm + 1 * 8192 + r * 64 + sw);
      }
#pragma unroll
      for (int q = 0; q < 2; ++q) {
        int r = wc * 32 + q * 16 + lrow;
        int sw = ((ks2 * 4 + lkb) ^ (r & 7)) * 8;
        bh[q] = *(const bf16x8*)(sm + 2 * 8192 + r * 64 + sw);
        bl[q] = *(const bf16x8*)(sm + 3 * 8192 + r * 64 + sw);
      }
#pragma unroll
      for (int m = 0; m < 4; ++m)
#pragma unroll
        for (int q = 0; q < 2; ++q) {
          acc[m][q] = __builtin_amdgcn_mfma_f32_16x16x32_bf16(ah[m], bh[q], acc[m][q], 0, 0, 0);
          acc[m][q] = __builtin_amdgcn_mfma_f32_16x16x32_bf16(ah[m], bl[q], acc[m][q], 0, 0, 0);
          acc[m][q] = __builtin_amdgcn_mfma_f32_16x16x32_bf16(al[m], bh[q], acc[m][q], 0, 0, 0);
        }
    }
    __syncthreads();
  }
#pragma unroll
  for (int m = 0; m < 4; ++m) {
    int row = i0 + wr * 64 + m * 16 + (lane >> 4) * 4;
#pragma unroll
    for (int q = 0; q < 2; ++q) {
      int col = j0 + wc * 32 + q * 16 + (lane & 15);
#pragma unroll
      for (int e = 0; e < 4; ++e) {
        float v = acc[m][q][e];
        if (EPI == 1) v += cv[n * CD + row + e];
        cPtr[(size_t)(row + e) * ldC + col] = v;
      }
    }
  }
}

// ---------- reduce gram K-split partials ----------
__global__ void k_gram_reduce(const float* __restrict__ Gp, float* __restrict__ G) {
  size_t idx = (size_t)blockIdx.x * 256 + threadIdx.x;
  float a = 0.f;
#pragma unroll
  for (int ks = 0; ks < KSG; ++ks) a += Gp[(size_t)ks * NB * CC + idx];
  G[idx] = a;
}

extern "C" void kernel_launch(void* const* d_in, const int* in_sizes, int n_in,
                              void* d_out, int out_size, void* d_ws, size_t ws_size,
                              hipStream_t stream) {
  const float* X = (const float*)d_in[0];
  const float* w0 = (const float*)d_in[1];
  const float* b0 = (const float*)d_in[2];
  const float* w1 = (const float*)d_in[3];
  const float* b1 = (const float*)d_in[4];
  const float* w2 = (const float*)d_in[5];
  const float* b2 = (const float*)d_in[6];
  const float* w3 = (const float*)d_in[7];
  const float* b3 = (const float*)d_in[8];
  float* out = (float*)d_out;
  float* ws = (float*)d_ws;

  float* cv = ws;                      // CD*NB
  float* alp = ws + 1024;
  float* gam = ws + 2048;
  float* dlt = ws + 3072;              // CD
  float* vp = ws + 4096;               // 4*CD
  float* bp = ws + 5120;               // 4*CD
  float* scal0 = ws + 6144;            // NB
  float* scal1 = ws + 6176;            // 1
  float* psum = ws + 8192;             // NB*64*CD = 65536
  float* E = psum + 65536;
  float* Et = E + CC;
  float* F = Et + CC;
  float* G = F + CC;                   // NB*CC
  float* R = G + (size_t)NB * CC;
  unsigned short* Athi = (unsigned short*)(R + (size_t)NB * CC);
  unsigned short* Atlo = Athi + (size_t)NB * CC;
  unsigned short* Uhi = Atlo + (size_t)NB * CC;
  unsigned short* Ulo = Uhi + (size_t)NB * CD * HW;
  unsigned short* Xthi = Ulo + (size_t)NB * CD * HW;
  unsigned short* Xtlo = Xthi + (size_t)NB * CD * HW;
  float* Gp = (float*)(Xtlo + (size_t)NB * CD * HW);  // KSG*NB*CC floats

  k_convert<<<dim3(HW / 64, CD / 64, NB), 256, 0, stream>>>(X, Uhi, Ulo, Xthi, Xtlo, psum);
  // Gram partials via MFMA (the long pole)
  k_mfma_nt<0><<<dim3(2, 2, NB * KSG), 512, 0, stream>>>(
      Uhi, Ulo, (size_t)CD * HW, HW, Uhi, Ulo, (size_t)CD * HW, HW, Gp, CC, CD, KSG,
      nullptr);
  k_wv<<<dim3(13), 256, 0, stream>>>(w1, w2, w3, b0, b1, b2, vp, bp, dlt, scal1);
  k_EF<<<dim3(4, 4, 2), 256, 0, stream>>>(w3, w0, w1, w2, E, Et, F);
  k_sag<<<dim3(NB), 256, 0, stream>>>(psum, vp, F, Et, alp, gam, scal0);
  k_gram_reduce<<<dim3(NB * CC / 256), 256, 0, stream>>>(Gp, G);
  // R = E*G[n]
  k_gemm64<0><<<dim3(4, 4, NB), 256, 0, stream>>>(E, G, 0, CC, R, CC, nullptr, nullptr,
                                                  nullptr, nullptr, nullptr, nullptr);
  // At = (R*F + dlt*alp^T + gam*bet^T)/HW + dlt*bet^T  -> bf16 hi/lo
  k_gemm64<1><<<dim3(4, 4, NB), 256, 0, stream>>>(R, F, CC, 0, nullptr, 0, Athi, Atlo,
                                                  dlt, alp, gam, bp);
  k_cv<<<dim3(NB), 256, 0, stream>>>(G, Et, vp, dlt, gam, scal0, scal1, b3, cv);
  // out = At * Xt^T + cv
  k_mfma_nt<1><<<dim3(2, 32, NB), 512, 0, stream>>>(
      Athi, Atlo, CC, CD, Xthi, Xtlo, (size_t)HW * CD, CD, out, (size_t)CD * HW, HW, 1,
      cv);
}

// Round 6
// 107.003 us; speedup vs baseline: 1.6257x; 1.1103x over previous
//
#include <hip/hip_runtime.h>

#define NB 4
#define CD 256
#define HW 4096
#define KSG 16
#define CC (CD * CD)

typedef __attribute__((ext_vector_type(8))) short bf16x8;
typedef __attribute__((ext_vector_type(4))) float f32x4;

__device__ inline unsigned short f2bf(float x) {
  unsigned int u = __float_as_uint(x);
  unsigned int r = (u + 0x7FFFu + ((u >> 16) & 1u)) >> 16;
  return (unsigned short)r;
}
__device__ inline float bfhi(unsigned short h) {
  return __uint_as_float(((unsigned int)h) << 16);
}
__device__ __forceinline__ void gload16(const unsigned short* g, unsigned short* l) {
  __builtin_amdgcn_global_load_lds((const __attribute__((address_space(1))) void*)g,
                                   (__attribute__((address_space(3))) void*)l, 16, 0, 0);
}

// ---------- convert X fp32 -> bf16 hi/lo ([c][p] and transposed [p][c]) + chansum partials ----------
__global__ __launch_bounds__(256) void k_convert(const float* __restrict__ X,
                                                 unsigned short* __restrict__ Uhi,
                                                 unsigned short* __restrict__ Ulo,
                                                 unsigned short* __restrict__ Xthi,
                                                 unsigned short* __restrict__ Xtlo,
                                                 float* __restrict__ psum) {
  int pt = blockIdx.x, ct = blockIdx.y, n = blockIdx.z;
  __shared__ unsigned int W[64][65];
  int t = threadIdx.x;
  int cl = t >> 2, pb = (t & 3) * 16;
  const float* Xp = X + ((size_t)n * CD + ct * 64 + cl) * HW + pt * 64 + pb;
  float x[16];
#pragma unroll
  for (int j = 0; j < 4; ++j) {
    float4 v = *(const float4*)(Xp + 4 * j);
    x[4 * j + 0] = v.x; x[4 * j + 1] = v.y; x[4 * j + 2] = v.z; x[4 * j + 3] = v.w;
  }
  float xs = 0.f;
  unsigned short h[16], l[16];
#pragma unroll
  for (int j = 0; j < 16; ++j) {
    xs += x[j];
    h[j] = f2bf(x[j]);
    l[j] = f2bf(x[j] - bfhi(h[j]));
    W[cl][pb + j] = (((unsigned int)h[j]) << 16) | l[j];
  }
  xs += __shfl_xor(xs, 1);
  xs += __shfl_xor(xs, 2);
  if ((t & 3) == 0) psum[((size_t)n * 64 + pt) * CD + ct * 64 + cl] = xs;
  size_t rowOff = ((size_t)n * CD + ct * 64 + cl) * HW + pt * 64 + pb;
#pragma unroll
  for (int j = 0; j < 4; ++j) {
    ushort4 vh, vl;
    vh.x = h[4 * j]; vh.y = h[4 * j + 1]; vh.z = h[4 * j + 2]; vh.w = h[4 * j + 3];
    vl.x = l[4 * j]; vl.y = l[4 * j + 1]; vl.z = l[4 * j + 2]; vl.w = l[4 * j + 3];
    *(ushort4*)(Uhi + rowOff + 4 * j) = vh;
    *(ushort4*)(Ulo + rowOff + 4 * j) = vl;
  }
  __syncthreads();
  int pl = t >> 2, cb = (t & 3) * 16;
  size_t rowT = ((size_t)n * HW + pt * 64 + pl) * CD + ct * 64 + cb;
#pragma unroll
  for (int j = 0; j < 4; ++j) {
    ushort4 vh, vl;
    unsigned int a0 = W[cb + 4 * j + 0][pl];
    unsigned int a1 = W[cb + 4 * j + 1][pl];
    unsigned int a2 = W[cb + 4 * j + 2][pl];
    unsigned int a3 = W[cb + 4 * j + 3][pl];
    vh.x = (unsigned short)(a0 >> 16); vl.x = (unsigned short)(a0 & 0xffff);
    vh.y = (unsigned short)(a1 >> 16); vl.y = (unsigned short)(a1 & 0xffff);
    vh.z = (unsigned short)(a2 >> 16); vl.z = (unsigned short)(a2 & 0xffff);
    vh.w = (unsigned short)(a3 >> 16); vl.w = (unsigned short)(a3 & 0xffff);
    *(ushort4*)(Xthi + rowT + 4 * j) = vh;
    *(ushort4*)(Xtlo + rowT + 4 * j) = vl;
  }
}

// ---------- weights -> bf16 hi/lo (w3 direct; w0,w1,w2 transposed) + small vectors ----------
__global__ __launch_bounds__(256) void k_wconv_wv(
    const float* __restrict__ w0, const float* __restrict__ w1,
    const float* __restrict__ w2, const float* __restrict__ w3,
    const float* __restrict__ b0, const float* __restrict__ b1,
    const float* __restrict__ b2, unsigned short* __restrict__ w3h,
    unsigned short* __restrict__ w3l, unsigned short* __restrict__ w0th,
    unsigned short* __restrict__ w0tl, unsigned short* __restrict__ w1th,
    unsigned short* __restrict__ w1tl, unsigned short* __restrict__ w2th,
    unsigned short* __restrict__ w2tl, float* __restrict__ vp,
    float* __restrict__ bpv, float* __restrict__ dlt, float* __restrict__ scal1) {
  int z = blockIdx.z, t = threadIdx.x;
  if (z == 0) {
    int i0 = blockIdx.x * 64, k0 = blockIdx.y * 64;
    int r = t >> 2, cb = (t & 3) * 16;
    const float* src = w3 + (size_t)(i0 + r) * CD + k0 + cb;
    size_t o = (size_t)(i0 + r) * CD + k0 + cb;
#pragma unroll
    for (int j = 0; j < 4; ++j) {
      float4 v = *(const float4*)(src + 4 * j);
      ushort4 vh, vl;
      vh.x = f2bf(v.x); vl.x = f2bf(v.x - bfhi(vh.x));
      vh.y = f2bf(v.y); vl.y = f2bf(v.y - bfhi(vh.y));
      vh.z = f2bf(v.z); vl.z = f2bf(v.z - bfhi(vh.z));
      vh.w = f2bf(v.w); vl.w = f2bf(v.w - bfhi(vh.w));
      *(ushort4*)(w3h + o + 4 * j) = vh;
      *(ushort4*)(w3l + o + 4 * j) = vl;
    }
  } else if (z < 4) {
    const float* w = (z == 1) ? w0 : (z == 2) ? w1 : w2;
    unsigned short* oh = (z == 1) ? w0th : (z == 2) ? w1th : w2th;
    unsigned short* ol = (z == 1) ? w0tl : (z == 2) ? w1tl : w2tl;
    int k0 = blockIdx.x * 64, j0 = blockIdx.y * 64;
    __shared__ unsigned int W[64][65];
    int kl = t >> 2, jb = (t & 3) * 16;
    const float* src = w + (size_t)(k0 + kl) * CD + j0 + jb;
#pragma unroll
    for (int j = 0; j < 4; ++j) {
      float4 v = *(const float4*)(src + 4 * j);
      unsigned short h0 = f2bf(v.x), h1 = f2bf(v.y), h2 = f2bf(v.z), h3 = f2bf(v.w);
      W[kl][jb + 4 * j + 0] = (((unsigned int)h0) << 16) | f2bf(v.x - bfhi(h0));
      W[kl][jb + 4 * j + 1] = (((unsigned int)h1) << 16) | f2bf(v.y - bfhi(h1));
      W[kl][jb + 4 * j + 2] = (((unsigned int)h2) << 16) | f2bf(v.z - bfhi(h2));
      W[kl][jb + 4 * j + 3] = (((unsigned int)h3) << 16) | f2bf(v.w - bfhi(h3));
    }
    __syncthreads();
    int jl = t >> 2, kb = (t & 3) * 16;
    size_t o = (size_t)(j0 + jl) * CD + k0 + kb;
#pragma unroll
    for (int j = 0; j < 4; ++j) {
      unsigned int a0 = W[kb + 4 * j + 0][jl];
      unsigned int a1 = W[kb + 4 * j + 1][jl];
      unsigned int a2 = W[kb + 4 * j + 2][jl];
      unsigned int a3 = W[kb + 4 * j + 3][jl];
      ushort4 vh, vl;
      vh.x = (unsigned short)(a0 >> 16); vl.x = (unsigned short)(a0 & 0xffff);
      vh.y = (unsigned short)(a1 >> 16); vl.y = (unsigned short)(a1 & 0xffff);
      vh.z = (unsigned short)(a2 >> 16); vl.z = (unsigned short)(a2 & 0xffff);
      vh.w = (unsigned short)(a3 >> 16); vl.w = (unsigned short)(a3 & 0xffff);
      *(ushort4*)(oh + o + 4 * j) = vh;
      *(ushort4*)(ol + o + 4 * j) = vl;
    }
  } else {
    int task = blockIdx.x * 4 + blockIdx.y;
    if (task < 8) {
      __shared__ float vin[64];
      int seg = task & 3;
      const float* W = (task < 4) ? w1 : w2;
      const float* v = (task < 4) ? b2 : b1;
      float* dst = (task < 4) ? (vp + seg * CD) : (bpv + seg * CD);
      if (t < 64) vin[t] = v[seg * 64 + t];
      __syncthreads();
      float a = 0.f;
#pragma unroll 16
      for (int kk = 0; kk < 64; ++kk)
        a += W[(size_t)(seg * 64 + kk) * CD + t] * vin[kk];
      dst[t] = a;
    } else if (task < 12) {
      int lane = t & 63, wv = t >> 6;
      float4 bv = *(const float4*)(b0 + lane * 4);
#pragma unroll 4
      for (int i = 0; i < 16; ++i) {
        int o = (task - 8) * 64 + wv * 16 + i;
        float4 v = *(const float4*)(w3 + (size_t)o * CD + lane * 4);
        float a = v.x * bv.x + v.y * bv.y + v.z * bv.z + v.w * bv.w;
        a += __shfl_xor(a, 1);  a += __shfl_xor(a, 2);  a += __shfl_xor(a, 4);
        a += __shfl_xor(a, 8);  a += __shfl_xor(a, 16); a += __shfl_xor(a, 32);
        if (lane == 0) dlt[o] = a;
      }
    } else if (task == 12) {
      __shared__ float red[256];
      red[t] = b1[t] * b2[t];
      __syncthreads();
      for (int off = 128; off > 0; off >>= 1) {
        if (t < off) red[t] += red[t + off];
        __syncthreads();
      }
      if (t == 0) scal1[0] = red[0];
    }
  }
}

// ---------- shared MFMA NT core: acc[i 64-rows x j 32-cols per wave], K=256, BK=64 ----------
__device__ __forceinline__ void mfma_nt_core(
    const unsigned short* __restrict__ pH, const unsigned short* __restrict__ pL,
    const unsigned short* __restrict__ qH, const unsigned short* __restrict__ qL,
    int i0, int j0, int kBegin, int ldP, int ldQ, unsigned short* sm,
    f32x4 acc[4][2]) {
  int t = threadIdx.x;
  int lane = t & 63, wid = t >> 6;
  int wr = wid >> 2, wc = wid & 3;
  int lrow = lane & 15, lkb = lane >> 4;
  int tsel = wid >> 1;
  int gbase = (wid & 1) * 8;
  const unsigned short* bp2 = (tsel == 0) ? pH : (tsel == 1) ? pL : (tsel == 2) ? qH : qL;
  int tb = (tsel < 2) ? i0 : j0;
  int ldT = (tsel < 2) ? ldP : ldQ;
  int rsub = lane >> 3;
  int gc = (lane & 7) ^ rsub;
  unsigned short* ldsT = sm + tsel * 8192;

#pragma unroll
  for (int m = 0; m < 4; ++m)
#pragma unroll
    for (int q = 0; q < 2; ++q) acc[m][q] = (f32x4){0.f, 0.f, 0.f, 0.f};

  for (int k0 = 0; k0 < 256; k0 += 64) {
    int kb = kBegin + k0;
#pragma unroll
    for (int s = 0; s < 8; ++s) {
      int g = gbase + s;
      gload16(bp2 + (size_t)(tb + g * 8 + rsub) * ldT + kb + gc * 8, ldsT + g * 512);
    }
    __syncthreads();
#pragma unroll
    for (int ks2 = 0; ks2 < 2; ++ks2) {
      bf16x8 ah[4], al[4], bh[2], bl[2];
#pragma unroll
      for (int m = 0; m < 4; ++m) {
        int r = wr * 64 + m * 16 + lrow;
        int sw = ((ks2 * 4 + lkb) ^ (r & 7)) * 8;
        ah[m] = *(const bf16x8*)(sm + 0 * 8192 + r * 64 + sw);
        al[m] = *(const bf16x8*)(sm + 1 * 8192 + r * 64 + sw);
      }
#pragma unroll
      for (int q = 0; q < 2; ++q) {
        int r = wc * 32 + q * 16 + lrow;
        int sw = ((ks2 * 4 + lkb) ^ (r & 7)) * 8;
        bh[q] = *(const bf16x8*)(sm + 2 * 8192 + r * 64 + sw);
        bl[q] = *(const bf16x8*)(sm + 3 * 8192 + r * 64 + sw);
      }
#pragma unroll
      for (int m = 0; m < 4; ++m)
#pragma unroll
        for (int q = 0; q < 2; ++q) {
          acc[m][q] = __builtin_amdgcn_mfma_f32_16x16x32_bf16(ah[m], bh[q], acc[m][q], 0, 0, 0);
          acc[m][q] = __builtin_amdgcn_mfma_f32_16x16x32_bf16(ah[m], bl[q], acc[m][q], 0, 0, 0);
          acc[m][q] = __builtin_amdgcn_mfma_f32_16x16x32_bf16(al[m], bh[q], acc[m][q], 0, 0, 0);
        }
    }
    __syncthreads();
  }
}

#define EPI_ROWCOL()                                              \
  int lane = threadIdx.x & 63, wid = threadIdx.x >> 6;            \
  int wr = wid >> 2, wc = wid & 3;                                \
  (void)wr; (void)wc;

// ---------- gram (symmetric: tiles (0,0),(0,1),(1,1)) ----------
__global__ __launch_bounds__(512) void k_gram(const unsigned short* __restrict__ Uhi,
                                              const unsigned short* __restrict__ Ulo,
                                              float* __restrict__ Gp) {
  int zz = blockIdx.y;
  int n = zz >> 4, ks = zz & 15;
  int bx = blockIdx.x;
  int i0 = (bx == 2) ? 128 : 0;
  int j0 = (bx == 0) ? 0 : 128;
  const unsigned short* pH = Uhi + (size_t)n * CD * HW;
  const unsigned short* pL = Ulo + (size_t)n * CD * HW;
  __shared__ __align__(16) unsigned short sm[4 * 8192];
  f32x4 acc[4][2];
  mfma_nt_core(pH, pL, pH, pL, i0, j0, ks * 256, HW, HW, sm, acc);
  EPI_ROWCOL();
  float* cPtr = Gp + ((size_t)ks * NB + n) * CC;
#pragma unroll
  for (int m = 0; m < 4; ++m) {
    int row = i0 + wr * 64 + m * 16 + (lane >> 4) * 4;
#pragma unroll
    for (int q = 0; q < 2; ++q) {
      int col = j0 + wc * 32 + q * 16 + (lane & 15);
#pragma unroll
      for (int e = 0; e < 4; ++e)
        cPtr[(size_t)(row + e) * CD + col] = acc[m][q][e];
    }
  }
}

// ---------- E / Ft via MFMA: z=0: E=NT(w3,w0t) -> Ehl + Et(f32); z=1: Ft=NT(w2t,w1t) -> Fthl + F(f32) ----------
__global__ __launch_bounds__(512) void k_EFm(
    const unsigned short* __restrict__ w3h, const unsigned short* __restrict__ w3l,
    const unsigned short* __restrict__ w0th, const unsigned short* __restrict__ w0tl,
    const unsigned short* __restrict__ w1th, const unsigned short* __restrict__ w1tl,
    const unsigned short* __restrict__ w2th, const unsigned short* __restrict__ w2tl,
    unsigned short* __restrict__ Eh, unsigned short* __restrict__ El,
    float* __restrict__ Et, unsigned short* __restrict__ Fth,
    unsigned short* __restrict__ Ftl, float* __restrict__ Ff) {
  int z = blockIdx.z;
  const unsigned short* pH = z ? w2th : w3h;
  const unsigned short* pL = z ? w2tl : w3l;
  const unsigned short* qH = z ? w1th : w0th;
  const unsigned short* qL = z ? w1tl : w0tl;
  unsigned short* oh = z ? Fth : Eh;
  unsigned short* ol = z ? Ftl : El;
  float* tf = z ? Ff : Et;
  int i0 = blockIdx.x * 128, j0 = blockIdx.y * 128;
  __shared__ __align__(16) unsigned short sm[4 * 8192];
  f32x4 acc[4][2];
  mfma_nt_core(pH, pL, qH, qL, i0, j0, 0, CD, CD, sm, acc);
  EPI_ROWCOL();
#pragma unroll
  for (int m = 0; m < 4; ++m) {
    int row = i0 + wr * 64 + m * 16 + (lane >> 4) * 4;
#pragma unroll
    for (int q = 0; q < 2; ++q) {
      int col = j0 + wc * 32 + q * 16 + (lane & 15);
#pragma unroll
      for (int e = 0; e < 4; ++e) {
        float v = acc[m][q][e];
        unsigned short hh = f2bf(v), ll = f2bf(v - bfhi(hh));
        oh[(size_t)(row + e) * CD + col] = hh;
        ol[(size_t)(row + e) * CD + col] = ll;
        tf[(size_t)col * CD + row + e] = v;
      }
    }
  }
}

// ---------- gram reduce (+mirror, +bf16 hi/lo) fused with sag ----------
__global__ __launch_bounds__(256) void k_red_sag(
    const float* __restrict__ Gp, float* __restrict__ G,
    unsigned short* __restrict__ Gh, unsigned short* __restrict__ Gl,
    const float* __restrict__ psum, const float* __restrict__ vp,
    const float* __restrict__ Ff, const float* __restrict__ Et,
    float* __restrict__ alp, float* __restrict__ gam, float* __restrict__ scal0) {
  int b = blockIdx.x, t = threadIdx.x;
  if (b < 768) {
    int quad = b >> 8;
    int r = b & 255;
    int n = r >> 6;
    int idx = (r & 63) * 256 + t;
    int i = (idx >> 7) + ((quad == 2) ? 128 : 0);
    int j = (idx & 127) + ((quad >= 1) ? 128 : 0);
    float a = 0.f;
#pragma unroll
    for (int ks = 0; ks < KSG; ++ks)
      a += Gp[((size_t)ks * NB + n) * CC + (size_t)i * CD + j];
    size_t o = (size_t)n * CC + (size_t)i * CD + j;
    unsigned short hh = f2bf(a), ll = f2bf(a - bfhi(hh));
    G[o] = a; Gh[o] = hh; Gl[o] = ll;
    if (quad == 1) {
      size_t o2 = (size_t)n * CC + (size_t)j * CD + i;
      G[o2] = a; Gh[o2] = hh; Gl[o2] = ll;
    }
  } else {
    int n = b - 768;
    __shared__ float ss[CD];
    __shared__ float red[256];
    float a = 0.f;
#pragma unroll 16
    for (int pt = 0; pt < 64; ++pt) a += psum[((size_t)n * 64 + pt) * CD + t];
    ss[t] = a;
    float v1c = vp[t] + vp[CD + t] + vp[2 * CD + t] + vp[3 * CD + t];
    red[t] = a * v1c;
    __syncthreads();
    for (int off = 128; off > 0; off >>= 1) {
      if (t < off) red[t] += red[t + off];
      __syncthreads();
    }
    if (t == 0) scal0[n] = red[0];
    float al = 0.f, ga = 0.f;
#pragma unroll 16
    for (int k = 0; k < CD; ++k) {
      float sk = ss[k];
      al += Ff[(size_t)k * CD + t] * sk;
      ga += Et[(size_t)k * CD + t] * sk;
    }
    alp[n * CD + t] = al;
    gam[n * CD + t] = ga;
  }
}

// ---------- R = NT(E, G) -> bf16 hi/lo ----------
__global__ __launch_bounds__(512) void k_Rm(const unsigned short* __restrict__ Eh,
                                            const unsigned short* __restrict__ El,
                                            const unsigned short* __restrict__ Gh,
                                            const unsigned short* __restrict__ Gl,
                                            unsigned short* __restrict__ Rh,
                                            unsigned short* __restrict__ Rl) {
  int n = blockIdx.z;
  int i0 = blockIdx.x * 128, j0 = blockIdx.y * 128;
  __shared__ __align__(16) unsigned short sm[4 * 8192];
  f32x4 acc[4][2];
  mfma_nt_core(Eh, El, Gh + (size_t)n * CC, Gl + (size_t)n * CC, i0, j0, 0, CD, CD, sm,
               acc);
  EPI_ROWCOL();
#pragma unroll
  for (int m = 0; m < 4; ++m) {
    int row = i0 + wr * 64 + m * 16 + (lane >> 4) * 4;
#pragma unroll
    for (int q = 0; q < 2; ++q) {
      int col = j0 + wc * 32 + q * 16 + (lane & 15);
#pragma unroll
      for (int e = 0; e < 4; ++e) {
        float v = acc[m][q][e];
        unsigned short hh = f2bf(v), ll = f2bf(v - bfhi(hh));
        Rh[(size_t)n * CC + (size_t)(row + e) * CD + col] = hh;
        Rl[(size_t)n * CC + (size_t)(row + e) * CD + col] = ll;
      }
    }
  }
}

// ---------- At = (NT(R,Ft) + dlt*alp^T + gam*bet^T)/HW + dlt*bet^T -> bf16 hi/lo ----------
__global__ __launch_bounds__(512) void k_Atm(
    const unsigned short* __restrict__ Rh, const unsigned short* __restrict__ Rl,
    const unsigned short* __restrict__ Fth, const unsigned short* __restrict__ Ftl,
    unsigned short* __restrict__ Athi, unsigned short* __restrict__ Atlo,
    const float* __restrict__ dlt, const float* __restrict__ alp,
    const float* __restrict__ gam, const float* __restrict__ bpv) {
  int n = blockIdx.z;
  int i0 = blockIdx.x * 128, j0 = blockIdx.y * 128;
  __shared__ __align__(16) unsigned short sm[4 * 8192];
  f32x4 acc[4][2];
  mfma_nt_core(Rh + (size_t)n * CC, Rl + (size_t)n * CC, Fth, Ftl, i0, j0, 0, CD, CD, sm,
               acc);
  EPI_ROWCOL();
#pragma unroll
  for (int m = 0; m < 4; ++m) {
    int row = i0 + wr * 64 + m * 16 + (lane >> 4) * 4;
#pragma unroll
    for (int q = 0; q < 2; ++q) {
      int col = j0 + wc * 32 + q * 16 + (lane & 15);
      float bj = bpv[col] + bpv[CD + col] + bpv[2 * CD + col] + bpv[3 * CD + col];
      float aj = alp[n * CD + col];
#pragma unroll
      for (int e = 0; e < 4; ++e) {
        float di = dlt[row + e];
        float gi = gam[n * CD + row + e];
        float v = (acc[m][q][e] + di * aj + gi * bj) * (1.0f / HW) + di * bj;
        unsigned short hh = f2bf(v), ll = f2bf(v - bfhi(hh));
        Athi[(size_t)n * CC + (size_t)(row + e) * CD + col] = hh;
        Atlo[(size_t)n * CC + (size_t)(row + e) * CD + col] = ll;
      }
    }
  }
}

// ---------- cv[n] = (E (G v1) + scal0 dlt + scal1 (gam + HW dlt))/HW + b3 ----------
__global__ __launch_bounds__(256) void k_cv(const float* __restrict__ G,
                                            const float* __restrict__ Et,
                                            const float* __restrict__ vp,
                                            const float* __restrict__ dlt,
                                            const float* __restrict__ gam,
                                            const float* __restrict__ scal0,
                                            const float* __restrict__ scal1,
                                            const float* __restrict__ b3,
                                            float* __restrict__ cv) {
  int n = blockIdx.x, o = threadIdx.x;
  __shared__ float vsh[CD], g1[CD];
  vsh[o] = vp[o] + vp[CD + o] + vp[2 * CD + o] + vp[3 * CD + o];
  __syncthreads();
  const float* Gn = G + (size_t)n * CC;
  float a = 0.f;
#pragma unroll 16
  for (int k = 0; k < CD; ++k) a += Gn[(size_t)k * CD + o] * vsh[k];  // G symmetric
  g1[o] = a;
  __syncthreads();
  float c2 = 0.f;
#pragma unroll 16
  for (int k = 0; k < CD; ++k) c2 += Et[(size_t)k * CD + o] * g1[k];
  float s0 = scal0[n], s1 = scal1[0];
  cv[n * CD + o] =
      (c2 + s0 * dlt[o] + s1 * (gam[n * CD + o] + (float)HW * dlt[o])) * (1.0f / HW) +
      b3[o];
}

// ---------- out = NT(At, Xt) + cv ----------
__global__ __launch_bounds__(512) void k_final(const unsigned short* __restrict__ Athi,
                                               const unsigned short* __restrict__ Atlo,
                                               const unsigned short* __restrict__ Xthi,
                                               const unsigned short* __restrict__ Xtlo,
                                               const float* __restrict__ cv,
                                               float* __restrict__ out) {
  int n = blockIdx.z;
  int i0 = blockIdx.x * 128, j0 = blockIdx.y * 128;
  __shared__ __align__(16) unsigned short sm[4 * 8192];
  f32x4 acc[4][2];
  mfma_nt_core(Athi + (size_t)n * CC, Atlo + (size_t)n * CC,
               Xthi + (size_t)n * HW * CD, Xtlo + (size_t)n * HW * CD, i0, j0, 0, CD, CD,
               sm, acc);
  EPI_ROWCOL();
  float* On = out + (size_t)n * CD * HW;
#pragma unroll
  for (int m = 0; m < 4; ++m) {
    int row = i0 + wr * 64 + m * 16 + (lane >> 4) * 4;
#pragma unroll
    for (int q = 0; q < 2; ++q) {
      int col = j0 + wc * 32 + q * 16 + (lane & 15);
#pragma unroll
      for (int e = 0; e < 4; ++e)
        On[(size_t)(row + e) * HW + col] = acc[m][q][e] + cv[n * CD + row + e];
    }
  }
}

extern "C" void kernel_launch(void* const* d_in, const int* in_sizes, int n_in,
                              void* d_out, int out_size, void* d_ws, size_t ws_size,
                              hipStream_t stream) {
  const float* X = (const float*)d_in[0];
  const float* w0 = (const float*)d_in[1];
  const float* b0 = (const float*)d_in[2];
  const float* w1 = (const float*)d_in[3];
  const float* b1 = (const float*)d_in[4];
  const float* w2 = (const float*)d_in[5];
  const float* b2 = (const float*)d_in[6];
  const float* w3 = (const float*)d_in[7];
  const float* b3 = (const float*)d_in[8];
  float* out = (float*)d_out;
  float* ws = (float*)d_ws;

  float* cv    = ws;
  float* alp   = ws + 1024;
  float* gam   = ws + 2048;
  float* dlt   = ws + 3072;
  float* vp    = ws + 4096;
  float* bpv   = ws + 5120;
  float* scal0 = ws + 6144;
  float* scal1 = ws + 6176;
  float* psum  = ws + 8192;             // 65536
  float* Et    = psum + 65536;
  float* Ff    = Et + CC;
  float* G     = Ff + CC;               // NB*CC
  float* Gp    = G + (size_t)NB * CC;   // KSG*NB*CC
  unsigned short* w3h  = (unsigned short*)(Gp + (size_t)KSG * NB * CC);
  unsigned short* w3l  = w3h + CC;
  unsigned short* w0th = w3l + CC;
  unsigned short* w0tl = w0th + CC;
  unsigned short* w1th = w0tl + CC;
  unsigned short* w1tl = w1th + CC;
  unsigned short* w2th = w1tl + CC;
  unsigned short* w2tl = w2th + CC;
  unsigned short* Eh   = w2tl + CC;
  unsigned short* El   = Eh + CC;
  unsigned short* Fth  = El + CC;
  unsigned short* Ftl  = Fth + CC;
  unsigned short* Gh   = Ftl + CC;
  unsigned short* Gl   = Gh + (size_t)NB * CC;
  unsigned short* Rh   = Gl + (size_t)NB * CC;
  unsigned short* Rl   = Rh + (size_t)NB * CC;
  unsigned short* Athi = Rl + (size_t)NB * CC;
  unsigned short* Atlo = Athi + (size_t)NB * CC;
  unsigned short* Uhi  = Atlo + (size_t)NB * CC;
  unsigned short* Ulo  = Uhi + (size_t)NB * CD * HW;
  unsigned short* Xthi = Ulo + (size_t)NB * CD * HW;
  unsigned short* Xtlo = Xthi + (size_t)NB * CD * HW;

  k_convert<<<dim3(HW / 64, CD / 64, NB), 256, 0, stream>>>(X, Uhi, Ulo, Xthi, Xtlo, psum);
  k_wconv_wv<<<dim3(4, 4, 5), 256, 0, stream>>>(w0, w1, w2, w3, b0, b1, b2, w3h, w3l,
                                                w0th, w0tl, w1th, w1tl, w2th, w2tl, vp,
                                                bpv, dlt, scal1);
  k_gram<<<dim3(3, NB * KSG), 512, 0, stream>>>(Uhi, Ulo, Gp);
  k_EFm<<<dim3(2, 2, 2), 512, 0, stream>>>(w3h, w3l, w0th, w0tl, w1th, w1tl, w2th, w2tl,
                                           Eh, El, Et, Fth, Ftl, Ff);
  k_red_sag<<<dim3(772), 256, 0, stream>>>(Gp, G, Gh, Gl, psum, vp, Ff, Et, alp, gam,
                                           scal0);
  k_Rm<<<dim3(2, 2, NB), 512, 0, stream>>>(Eh, El, Gh, Gl, Rh, Rl);
  k_cv<<<dim3(NB), 256, 0, stream>>>(G, Et, vp, dlt, gam, scal0, scal1, b3, cv);
  k_Atm<<<dim3(2, 2, NB), 512, 0, stream>>>(Rh, Rl, Fth, Ftl, Athi, Atlo, dlt, alp, gam,
                                            bpv);
  k_final<<<dim3(2, 32, NB), 512, 0, stream>>>(Athi, Atlo, Xthi, Xtlo, cv, out);
}

// Round 7
// 105.891 us; speedup vs baseline: 1.6428x; 1.0105x over previous
//
#include <hip/hip_runtime.h>

#define NB 4
#define CD 256
#define HW 4096
#define KSG 16
#define CC (CD * CD)

typedef __attribute__((ext_vector_type(8))) short bf16x8;
typedef __attribute__((ext_vector_type(4))) float f32x4;

__device__ inline unsigned short f2bf(float x) {
  unsigned int u = __float_as_uint(x);
  unsigned int r = (u + 0x7FFFu + ((u >> 16) & 1u)) >> 16;
  return (unsigned short)r;
}
__device__ inline float bfhi(unsigned short h) {
  return __uint_as_float(((unsigned int)h) << 16);
}
__device__ __forceinline__ void gload16(const unsigned short* g, unsigned short* l) {
  __builtin_amdgcn_global_load_lds((const __attribute__((address_space(1))) void*)g,
                                   (__attribute__((address_space(3))) void*)l, 16, 0, 0);
}

// ---------- shared MFMA NT core: per-wave 64x32 tile in 2x4 wave grid, K=256, BK=64 ----------
__device__ __forceinline__ void mfma_nt_core(
    const unsigned short* __restrict__ pH, const unsigned short* __restrict__ pL,
    const unsigned short* __restrict__ qH, const unsigned short* __restrict__ qL,
    int i0, int j0, int kBegin, int ldP, int ldQ, unsigned short* sm,
    f32x4 acc[4][2]) {
  int t = threadIdx.x;
  int lane = t & 63, wid = t >> 6;
  int wr = wid >> 2, wc = wid & 3;
  int lrow = lane & 15, lkb = lane >> 4;
  int tsel = wid >> 1;
  int gbase = (wid & 1) * 8;
  const unsigned short* bp2 = (tsel == 0) ? pH : (tsel == 1) ? pL : (tsel == 2) ? qH : qL;
  int tb = (tsel < 2) ? i0 : j0;
  int ldT = (tsel < 2) ? ldP : ldQ;
  int rsub = lane >> 3;
  int gc = (lane & 7) ^ rsub;
  unsigned short* ldsT = sm + tsel * 8192;

#pragma unroll
  for (int m = 0; m < 4; ++m)
#pragma unroll
    for (int q = 0; q < 2; ++q) acc[m][q] = (f32x4){0.f, 0.f, 0.f, 0.f};

  for (int k0 = 0; k0 < 256; k0 += 64) {
    int kb = kBegin + k0;
#pragma unroll
    for (int s = 0; s < 8; ++s) {
      int g = gbase + s;
      gload16(bp2 + (size_t)(tb + g * 8 + rsub) * ldT + kb + gc * 8, ldsT + g * 512);
    }
    __syncthreads();
#pragma unroll
    for (int ks2 = 0; ks2 < 2; ++ks2) {
      bf16x8 ah[4], al[4], bh[2], bl[2];
#pragma unroll
      for (int m = 0; m < 4; ++m) {
        int r = wr * 64 + m * 16 + lrow;
        int sw = ((ks2 * 4 + lkb) ^ (r & 7)) * 8;
        ah[m] = *(const bf16x8*)(sm + 0 * 8192 + r * 64 + sw);
        al[m] = *(const bf16x8*)(sm + 1 * 8192 + r * 64 + sw);
      }
#pragma unroll
      for (int q = 0; q < 2; ++q) {
        int r = wc * 32 + q * 16 + lrow;
        int sw = ((ks2 * 4 + lkb) ^ (r & 7)) * 8;
        bh[q] = *(const bf16x8*)(sm + 2 * 8192 + r * 64 + sw);
        bl[q] = *(const bf16x8*)(sm + 3 * 8192 + r * 64 + sw);
      }
#pragma unroll
      for (int m = 0; m < 4; ++m)
#pragma unroll
        for (int q = 0; q < 2; ++q) {
          acc[m][q] = __builtin_amdgcn_mfma_f32_16x16x32_bf16(ah[m], bh[q], acc[m][q], 0, 0, 0);
          acc[m][q] = __builtin_amdgcn_mfma_f32_16x16x32_bf16(ah[m], bl[q], acc[m][q], 0, 0, 0);
          acc[m][q] = __builtin_amdgcn_mfma_f32_16x16x32_bf16(al[m], bh[q], acc[m][q], 0, 0, 0);
        }
    }
    __syncthreads();
  }
}

// ---------- coalesced fp32 epilogue: acc -> LDS (64KB, XOR-swz) -> float4 row stores ----------
// dst points at the tile origin (includes i0,j0); cvrow indexed by local row (or null).
__device__ __forceinline__ void epi_store(f32x4 acc[4][2], float* smf, float* dst,
                                          int ld, const float* cvrow) {
  int t = threadIdx.x, lane = t & 63, wid = t >> 6;
  int wr = wid >> 2, wc = wid & 3;
#pragma unroll
  for (int m = 0; m < 4; ++m) {
    int rbase = wr * 64 + m * 16 + ((lane >> 4) << 2);
#pragma unroll
    for (int q = 0; q < 2; ++q) {
      int col = wc * 32 + q * 16 + (lane & 15);
#pragma unroll
      for (int e = 0; e < 4; ++e) {
        int row = rbase + e;
        smf[row * 128 + (col ^ ((row & 4) << 2))] = acc[m][q][e];
      }
    }
  }
  __syncthreads();
#pragma unroll
  for (int it = 0; it < 8; ++it) {
    int row = it * 16 + wid * 2 + (lane >> 5);
    int col = (lane & 31) * 4;
    float4 v = *(const float4*)&smf[row * 128 + (col ^ ((row & 4) << 2))];
    if (cvrow) {
      float cb = cvrow[row];
      v.x += cb; v.y += cb; v.z += cb; v.w += cb;
    }
    *(float4*)(dst + (size_t)row * ld + col) = v;
  }
}

// ---------- node A: convert X (+psum) merged with weight conversions / small vectors ----------
__global__ __launch_bounds__(256) void kA(
    const float* __restrict__ X, unsigned short* __restrict__ Uhi,
    unsigned short* __restrict__ Ulo, unsigned short* __restrict__ Xthi,
    unsigned short* __restrict__ Xtlo, float* __restrict__ psum,
    const float* __restrict__ w0, const float* __restrict__ w1,
    const float* __restrict__ w2, const float* __restrict__ w3,
    const float* __restrict__ b0, const float* __restrict__ b1,
    const float* __restrict__ b2, unsigned short* __restrict__ w3h,
    unsigned short* __restrict__ w3l, unsigned short* __restrict__ w0th,
    unsigned short* __restrict__ w0tl, unsigned short* __restrict__ w1th,
    unsigned short* __restrict__ w1tl, unsigned short* __restrict__ w2th,
    unsigned short* __restrict__ w2tl, float* __restrict__ vp,
    float* __restrict__ bpv, float* __restrict__ dlt, float* __restrict__ scal1,
    unsigned int* __restrict__ barctr) {
  __shared__ unsigned int W[64][65];
  int z = blockIdx.z, t = threadIdx.x;
  if (z < 4) {
    if (z == 0 && blockIdx.x == 0 && blockIdx.y == 0 && t == 0) *barctr = 0u;
    int pt = blockIdx.x, ct = blockIdx.y, n = z;
    int cl = t >> 2, pb = (t & 3) * 16;
    const float* Xp = X + ((size_t)n * CD + ct * 64 + cl) * HW + pt * 64 + pb;
    float x[16];
#pragma unroll
    for (int j = 0; j < 4; ++j) {
      float4 v = *(const float4*)(Xp + 4 * j);
      x[4 * j + 0] = v.x; x[4 * j + 1] = v.y; x[4 * j + 2] = v.z; x[4 * j + 3] = v.w;
    }
    float xs = 0.f;
    unsigned short h[16], l[16];
#pragma unroll
    for (int j = 0; j < 16; ++j) {
      xs += x[j];
      h[j] = f2bf(x[j]);
      l[j] = f2bf(x[j] - bfhi(h[j]));
      W[cl][pb + j] = (((unsigned int)h[j]) << 16) | l[j];
    }
    xs += __shfl_xor(xs, 1);
    xs += __shfl_xor(xs, 2);
    if ((t & 3) == 0) psum[((size_t)n * 64 + pt) * CD + ct * 64 + cl] = xs;
    size_t rowOff = ((size_t)n * CD + ct * 64 + cl) * HW + pt * 64 + pb;
#pragma unroll
    for (int j = 0; j < 4; ++j) {
      ushort4 vh, vl;
      vh.x = h[4 * j]; vh.y = h[4 * j + 1]; vh.z = h[4 * j + 2]; vh.w = h[4 * j + 3];
      vl.x = l[4 * j]; vl.y = l[4 * j + 1]; vl.z = l[4 * j + 2]; vl.w = l[4 * j + 3];
      *(ushort4*)(Uhi + rowOff + 4 * j) = vh;
      *(ushort4*)(Ulo + rowOff + 4 * j) = vl;
    }
    __syncthreads();
    int pl = t >> 2, cb = (t & 3) * 16;
    size_t rowT = ((size_t)n * HW + pt * 64 + pl) * CD + ct * 64 + cb;
#pragma unroll
    for (int j = 0; j < 4; ++j) {
      ushort4 vh, vl;
      unsigned int a0 = W[cb + 4 * j + 0][pl];
      unsigned int a1 = W[cb + 4 * j + 1][pl];
      unsigned int a2 = W[cb + 4 * j + 2][pl];
      unsigned int a3 = W[cb + 4 * j + 3][pl];
      vh.x = (unsigned short)(a0 >> 16); vl.x = (unsigned short)(a0 & 0xffff);
      vh.y = (unsigned short)(a1 >> 16); vl.y = (unsigned short)(a1 & 0xffff);
      vh.z = (unsigned short)(a2 >> 16); vl.z = (unsigned short)(a2 & 0xffff);
      vh.w = (unsigned short)(a3 >> 16); vl.w = (unsigned short)(a3 & 0xffff);
      *(ushort4*)(Xthi + rowT + 4 * j) = vh;
      *(ushort4*)(Xtlo + rowT + 4 * j) = vl;
    }
    return;
  }
  int zc = z - 4;
  if (zc == 0) {
    if (blockIdx.x >= 4) return;
    int i0 = blockIdx.x * 64, k0 = blockIdx.y * 64;
    int r = t >> 2, cb = (t & 3) * 16;
    const float* src = w3 + (size_t)(i0 + r) * CD + k0 + cb;
    size_t o = (size_t)(i0 + r) * CD + k0 + cb;
#pragma unroll
    for (int j = 0; j < 4; ++j) {
      float4 v = *(const float4*)(src + 4 * j);
      ushort4 vh, vl;
      vh.x = f2bf(v.x); vl.x = f2bf(v.x - bfhi(vh.x));
      vh.y = f2bf(v.y); vl.y = f2bf(v.y - bfhi(vh.y));
      vh.z = f2bf(v.z); vl.z = f2bf(v.z - bfhi(vh.z));
      vh.w = f2bf(v.w); vl.w = f2bf(v.w - bfhi(vh.w));
      *(ushort4*)(w3h + o + 4 * j) = vh;
      *(ushort4*)(w3l + o + 4 * j) = vl;
    }
  } else if (zc < 4) {
    if (blockIdx.x >= 4) return;
    const float* w = (zc == 1) ? w0 : (zc == 2) ? w1 : w2;
    unsigned short* oh = (zc == 1) ? w0th : (zc == 2) ? w1th : w2th;
    unsigned short* ol = (zc == 1) ? w0tl : (zc == 2) ? w1tl : w2tl;
    int k0 = blockIdx.x * 64, j0 = blockIdx.y * 64;
    int kl = t >> 2, jb = (t & 3) * 16;
    const float* src = w + (size_t)(k0 + kl) * CD + j0 + jb;
#pragma unroll
    for (int j = 0; j < 4; ++j) {
      float4 v = *(const float4*)(src + 4 * j);
      unsigned short h0 = f2bf(v.x), h1 = f2bf(v.y), h2 = f2bf(v.z), h3 = f2bf(v.w);
      W[kl][jb + 4 * j + 0] = (((unsigned int)h0) << 16) | f2bf(v.x - bfhi(h0));
      W[kl][jb + 4 * j + 1] = (((unsigned int)h1) << 16) | f2bf(v.y - bfhi(h1));
      W[kl][jb + 4 * j + 2] = (((unsigned int)h2) << 16) | f2bf(v.z - bfhi(h2));
      W[kl][jb + 4 * j + 3] = (((unsigned int)h3) << 16) | f2bf(v.w - bfhi(h3));
    }
    __syncthreads();
    int jl = t >> 2, kb = (t & 3) * 16;
    size_t o = (size_t)(j0 + jl) * CD + k0 + kb;
#pragma unroll
    for (int j = 0; j < 4; ++j) {
      unsigned int a0 = W[kb + 4 * j + 0][jl];
      unsigned int a1 = W[kb + 4 * j + 1][jl];
      unsigned int a2 = W[kb + 4 * j + 2][jl];
      unsigned int a3 = W[kb + 4 * j + 3][jl];
      ushort4 vh, vl;
      vh.x = (unsigned short)(a0 >> 16); vl.x = (unsigned short)(a0 & 0xffff);
      vh.y = (unsigned short)(a1 >> 16); vl.y = (unsigned short)(a1 & 0xffff);
      vh.z = (unsigned short)(a2 >> 16); vl.z = (unsigned short)(a2 & 0xffff);
      vh.w = (unsigned short)(a3 >> 16); vl.w = (unsigned short)(a3 & 0xffff);
      *(ushort4*)(oh + o + 4 * j) = vh;
      *(ushort4*)(ol + o + 4 * j) = vl;
    }
  } else {
    if (blockIdx.x >= 4) return;
    int task = blockIdx.x * 4 + blockIdx.y;
    if (task < 8) {
      float* vin = (float*)W;
      int seg = task & 3;
      const float* Wm = (task < 4) ? w1 : w2;
      const float* v = (task < 4) ? b2 : b1;
      float* dst = (task < 4) ? (vp + seg * CD) : (bpv + seg * CD);
      if (t < 64) vin[t] = v[seg * 64 + t];
      __syncthreads();
      float a = 0.f;
#pragma unroll 16
      for (int kk = 0; kk < 64; ++kk)
        a += Wm[(size_t)(seg * 64 + kk) * CD + t] * vin[kk];
      dst[t] = a;
    } else if (task < 12) {
      int lane = t & 63, wv = t >> 6;
      float4 bv = *(const float4*)(b0 + lane * 4);
#pragma unroll 4
      for (int i = 0; i < 16; ++i) {
        int o = (task - 8) * 64 + wv * 16 + i;
        float4 v = *(const float4*)(w3 + (size_t)o * CD + lane * 4);
        float a = v.x * bv.x + v.y * bv.y + v.z * bv.z + v.w * bv.w;
        a += __shfl_xor(a, 1);  a += __shfl_xor(a, 2);  a += __shfl_xor(a, 4);
        a += __shfl_xor(a, 8);  a += __shfl_xor(a, 16); a += __shfl_xor(a, 32);
        if (lane == 0) dlt[o] = a;
      }
    } else if (task == 12) {
      float* red = (float*)W;
      red[t] = b1[t] * b2[t];
      __syncthreads();
      for (int off = 128; off > 0; off >>= 1) {
        if (t < off) red[t] += red[t + off];
        __syncthreads();
      }
      if (t == 0) scal1[0] = red[0];
    }
  }
}

// ---------- node B: gram (symmetric, 3 tiles x 64 z) + EFm (8 blocks at y==64) ----------
__global__ __launch_bounds__(512) void kB(
    const unsigned short* __restrict__ Uhi, const unsigned short* __restrict__ Ulo,
    float* __restrict__ Gp, const unsigned short* __restrict__ w3h,
    const unsigned short* __restrict__ w3l, const unsigned short* __restrict__ w0th,
    const unsigned short* __restrict__ w0tl, const unsigned short* __restrict__ w1th,
    const unsigned short* __restrict__ w1tl, const unsigned short* __restrict__ w2th,
    const unsigned short* __restrict__ w2tl, unsigned short* __restrict__ Eh,
    unsigned short* __restrict__ El, float* __restrict__ Et,
    unsigned short* __restrict__ Fth, unsigned short* __restrict__ Ftl,
    float* __restrict__ Ff) {
  __shared__ __align__(16) unsigned short sm[4 * 8192];
  int x = blockIdx.x, y = blockIdx.y;
  if (y < 64) {
    if (x >= 3) return;
    int n = y >> 4, ks = y & 15;
    int i0 = (x == 2) ? 128 : 0;
    int j0 = (x == 0) ? 0 : 128;
    const unsigned short* pH = Uhi + (size_t)n * CD * HW;
    const unsigned short* pL = Ulo + (size_t)n * CD * HW;
    f32x4 acc[4][2];
    mfma_nt_core(pH, pL, pH, pL, i0, j0, ks * 256, HW, HW, sm, acc);
    float* base = Gp + ((size_t)ks * NB + n) * CC + (size_t)i0 * CD + j0;
    epi_store(acc, (float*)sm, base, CD, nullptr);
  } else {
    int zc = x >> 2, j0 = ((x >> 1) & 1) * 128, i0 = (x & 1) * 128;
    const unsigned short* pH = zc ? w2th : w3h;
    const unsigned short* pL = zc ? w2tl : w3l;
    const unsigned short* qH = zc ? w1th : w0th;
    const unsigned short* qL = zc ? w1tl : w0tl;
    unsigned short* oh = zc ? Fth : Eh;
    unsigned short* ol = zc ? Ftl : El;
    float* tf = zc ? Ff : Et;
    f32x4 acc[4][2];
    mfma_nt_core(pH, pL, qH, qL, i0, j0, 0, CD, CD, sm, acc);
    int lane = threadIdx.x & 63, wid = threadIdx.x >> 6;
    int wr = wid >> 2, wc = wid & 3;
#pragma unroll
    for (int m = 0; m < 4; ++m) {
      int row = i0 + wr * 64 + m * 16 + ((lane >> 4) << 2);
#pragma unroll
      for (int q = 0; q < 2; ++q) {
        int col = j0 + wc * 32 + q * 16 + (lane & 15);
#pragma unroll
        for (int e = 0; e < 4; ++e) {
          float v = acc[m][q][e];
          unsigned short hh = f2bf(v), ll = f2bf(v - bfhi(hh));
          oh[(size_t)(row + e) * CD + col] = hh;
          ol[(size_t)(row + e) * CD + col] = ll;
          tf[(size_t)col * CD + row + e] = v;
        }
      }
    }
  }
}

// ---------- node C: gram reduce (+mirror, +bf16 hi/lo) fused with s/alp/gam/scal0 ----------
__global__ __launch_bounds__(256) void k_red_sag(
    const float* __restrict__ Gp, float* __restrict__ G,
    unsigned short* __restrict__ Gh, unsigned short* __restrict__ Gl,
    const float* __restrict__ psum, const float* __restrict__ vp,
    const float* __restrict__ Ff, const float* __restrict__ Et,
    float* __restrict__ alp, float* __restrict__ gam, float* __restrict__ scal0) {
  int b = blockIdx.x, t = threadIdx.x;
  if (b < 768) {
    int quad = b >> 8;
    int r = b & 255;
    int n = r >> 6;
    int idx = (r & 63) * 256 + t;
    int i = (idx >> 7) + ((quad == 2) ? 128 : 0);
    int j = (idx & 127) + ((quad >= 1) ? 128 : 0);
    float a = 0.f;
#pragma unroll
    for (int ks = 0; ks < KSG; ++ks)
      a += Gp[((size_t)ks * NB + n) * CC + (size_t)i * CD + j];
    size_t o = (size_t)n * CC + (size_t)i * CD + j;
    unsigned short hh = f2bf(a), ll = f2bf(a - bfhi(hh));
    G[o] = a; Gh[o] = hh; Gl[o] = ll;
    if (quad == 1) {
      size_t o2 = (size_t)n * CC + (size_t)j * CD + i;
      G[o2] = a; Gh[o2] = hh; Gl[o2] = ll;
    }
  } else {
    int n = b - 768;
    __shared__ float ss[CD];
    __shared__ float red[256];
    float a = 0.f;
#pragma unroll 16
    for (int pt = 0; pt < 64; ++pt) a += psum[((size_t)n * 64 + pt) * CD + t];
    ss[t] = a;
    float v1c = vp[t] + vp[CD + t] + vp[2 * CD + t] + vp[3 * CD + t];
    red[t] = a * v1c;
    __syncthreads();
    for (int off = 128; off > 0; off >>= 1) {
      if (t < off) red[t] += red[t + off];
      __syncthreads();
    }
    if (t == 0) scal0[n] = red[0];
    float al = 0.f, ga = 0.f;
#pragma unroll 16
    for (int k = 0; k < CD; ++k) {
      float sk = ss[k];
      al += Ff[(size_t)k * CD + t] * sk;
      ga += Et[(size_t)k * CD + t] * sk;
    }
    alp[n * CD + t] = al;
    gam[n * CD + t] = ga;
  }
}

// ---------- node D: Rm + cv, device barrier, Atm (20 blocks, all co-resident) ----------
__global__ __launch_bounds__(512) void kD(
    const unsigned short* __restrict__ Eh, const unsigned short* __restrict__ El,
    const unsigned short* __restrict__ Gh, const unsigned short* __restrict__ Gl,
    unsigned short* __restrict__ Rh, unsigned short* __restrict__ Rl,
    const float* __restrict__ G, const float* __restrict__ Et,
    const float* __restrict__ vp, const float* __restrict__ dlt,
    const float* __restrict__ gam, const float* __restrict__ scal0,
    const float* __restrict__ scal1, const float* __restrict__ b3,
    float* __restrict__ cv, const unsigned short* __restrict__ Fth,
    const unsigned short* __restrict__ Ftl, unsigned short* __restrict__ Athi,
    unsigned short* __restrict__ Atlo, const float* __restrict__ alp,
    const float* __restrict__ bpv, unsigned int* __restrict__ barctr) {
  __shared__ __align__(16) unsigned short sm[4 * 8192];
  int b = blockIdx.x, t = threadIdx.x;
  if (b < 16) {
    int n = b >> 2, i0 = ((b >> 1) & 1) * 128, j0 = (b & 1) * 128;
    f32x4 acc[4][2];
    mfma_nt_core(Eh, El, Gh + (size_t)n * CC, Gl + (size_t)n * CC, i0, j0, 0, CD, CD, sm,
                 acc);
    int lane = t & 63, wid = t >> 6, wr = wid >> 2, wc = wid & 3;
#pragma unroll
    for (int m = 0; m < 4; ++m) {
      int row = i0 + wr * 64 + m * 16 + ((lane >> 4) << 2);
#pragma unroll
      for (int q = 0; q < 2; ++q) {
        int col = j0 + wc * 32 + q * 16 + (lane & 15);
#pragma unroll
        for (int e = 0; e < 4; ++e) {
          float v = acc[m][q][e];
          unsigned short hh = f2bf(v), ll = f2bf(v - bfhi(hh));
          Rh[(size_t)n * CC + (size_t)(row + e) * CD + col] = hh;
          Rl[(size_t)n * CC + (size_t)(row + e) * CD + col] = ll;
        }
      }
    }
  } else {
    int n = b - 16;
    float* vsh = (float*)sm;
    float* g1 = vsh + CD;
    if (t < CD) vsh[t] = vp[t] + vp[CD + t] + vp[2 * CD + t] + vp[3 * CD + t];
    __syncthreads();
    if (t < CD) {
      const float* Gn = G + (size_t)n * CC;
      float a = 0.f;
#pragma unroll 8
      for (int k = 0; k < CD; ++k) a += Gn[(size_t)k * CD + t] * vsh[k];
      g1[t] = a;
    }
    __syncthreads();
    if (t < CD) {
      float c2 = 0.f;
#pragma unroll 8
      for (int k = 0; k < CD; ++k) c2 += Et[(size_t)k * CD + t] * g1[k];
      float s0 = scal0[n], s1 = scal1[0];
      cv[n * CD + t] =
          (c2 + s0 * dlt[t] + s1 * (gam[n * CD + t] + (float)HW * dlt[t])) * (1.0f / HW) +
          b3[t];
    }
  }
  // device-scope grid barrier (20 blocks, monotone counter zeroed by kA each call)
  __syncthreads();
  if (t == 0) {
    __threadfence();
    atomicAdd(barctr, 1u);
    while (__hip_atomic_load(barctr, __ATOMIC_ACQUIRE, __HIP_MEMORY_SCOPE_AGENT) < 20u) {
    }
    __threadfence();
  }
  __syncthreads();
  if (b < 16) {
    int n = b >> 2, i0 = ((b >> 1) & 1) * 128, j0 = (b & 1) * 128;
    f32x4 acc[4][2];
    mfma_nt_core(Rh + (size_t)n * CC, Rl + (size_t)n * CC, Fth, Ftl, i0, j0, 0, CD, CD,
                 sm, acc);
    int lane = t & 63, wid = t >> 6, wr = wid >> 2, wc = wid & 3;
#pragma unroll
    for (int m = 0; m < 4; ++m) {
      int row = i0 + wr * 64 + m * 16 + ((lane >> 4) << 2);
#pragma unroll
      for (int q = 0; q < 2; ++q) {
        int col = j0 + wc * 32 + q * 16 + (lane & 15);
        float bj = bpv[col] + bpv[CD + col] + bpv[2 * CD + col] + bpv[3 * CD + col];
        float aj = alp[n * CD + col];
#pragma unroll
        for (int e = 0; e < 4; ++e) {
          float di = dlt[row + e], gi = gam[n * CD + row + e];
          float v = (acc[m][q][e] + di * aj + gi * bj) * (1.0f / HW) + di * bj;
          unsigned short hh = f2bf(v), ll = f2bf(v - bfhi(hh));
          Athi[(size_t)n * CC + (size_t)(row + e) * CD + col] = hh;
          Atlo[(size_t)n * CC + (size_t)(row + e) * CD + col] = ll;
        }
      }
    }
  }
}

// ---------- node F: out = NT(At, Xt) + cv, coalesced epilogue ----------
__global__ __launch_bounds__(512) void kF(const unsigned short* __restrict__ Athi,
                                          const unsigned short* __restrict__ Atlo,
                                          const unsigned short* __restrict__ Xthi,
                                          const unsigned short* __restrict__ Xtlo,
                                          const float* __restrict__ cv,
                                          float* __restrict__ out) {
  int n = blockIdx.z;
  int i0 = blockIdx.x * 128, j0 = blockIdx.y * 128;
  __shared__ __align__(16) unsigned short sm[4 * 8192];
  f32x4 acc[4][2];
  mfma_nt_core(Athi + (size_t)n * CC, Atlo + (size_t)n * CC, Xthi + (size_t)n * HW * CD,
               Xtlo + (size_t)n * HW * CD, i0, j0, 0, CD, CD, sm, acc);
  epi_store(acc, (float*)sm, out + (size_t)n * CD * HW + (size_t)i0 * HW + j0, HW,
            cv + n * CD + i0);
}

extern "C" void kernel_launch(void* const* d_in, const int* in_sizes, int n_in,
                              void* d_out, int out_size, void* d_ws, size_t ws_size,
                              hipStream_t stream) {
  const float* X = (const float*)d_in[0];
  const float* w0 = (const float*)d_in[1];
  const float* b0 = (const float*)d_in[2];
  const float* w1 = (const float*)d_in[3];
  const float* b1 = (const float*)d_in[4];
  const float* w2 = (const float*)d_in[5];
  const float* b2 = (const float*)d_in[6];
  const float* w3 = (const float*)d_in[7];
  const float* b3 = (const float*)d_in[8];
  float* out = (float*)d_out;
  float* ws = (float*)d_ws;

  float* cv    = ws;
  float* alp   = ws + 1024;
  float* gam   = ws + 2048;
  float* dlt   = ws + 3072;
  float* vp    = ws + 4096;
  float* bpv   = ws + 5120;
  float* scal0 = ws + 6144;
  float* scal1 = ws + 6176;
  unsigned int* barctr = (unsigned int*)(ws + 6208);
  float* psum  = ws + 8192;             // 65536
  float* Et    = psum + 65536;
  float* Ff    = Et + CC;
  float* G     = Ff + CC;               // NB*CC
  float* Gp    = G + (size_t)NB * CC;   // KSG*NB*CC
  unsigned short* w3h  = (unsigned short*)(Gp + (size_t)KSG * NB * CC);
  unsigned short* w3l  = w3h + CC;
  unsigned short* w0th = w3l + CC;
  unsigned short* w0tl = w0th + CC;
  unsigned short* w1th = w0tl + CC;
  unsigned short* w1tl = w1th + CC;
  unsigned short* w2th = w1tl + CC;
  unsigned short* w2tl = w2th + CC;
  unsigned short* Eh   = w2tl + CC;
  unsigned short* El   = Eh + CC;
  unsigned short* Fth  = El + CC;
  unsigned short* Ftl  = Fth + CC;
  unsigned short* Gh   = Ftl + CC;
  unsigned short* Gl   = Gh + (size_t)NB * CC;
  unsigned short* Rh   = Gl + (size_t)NB * CC;
  unsigned short* Rl   = Rh + (size_t)NB * CC;
  unsigned short* Athi = Rl + (size_t)NB * CC;
  unsigned short* Atlo = Athi + (size_t)NB * CC;
  unsigned short* Uhi  = Atlo + (size_t)NB * CC;
  unsigned short* Ulo  = Uhi + (size_t)NB * CD * HW;
  unsigned short* Xthi = Ulo + (size_t)NB * CD * HW;
  unsigned short* Xtlo = Xthi + (size_t)NB * CD * HW;

  kA<<<dim3(64, 4, 9), 256, 0, stream>>>(X, Uhi, Ulo, Xthi, Xtlo, psum, w0, w1, w2, w3,
                                         b0, b1, b2, w3h, w3l, w0th, w0tl, w1th, w1tl,
                                         w2th, w2tl, vp, bpv, dlt, scal1, barctr);
  kB<<<dim3(8, 65, 1), 512, 0, stream>>>(Uhi, Ulo, Gp, w3h, w3l, w0th, w0tl, w1th, w1tl,
                                         w2th, w2tl, Eh, El, Et, Fth, Ftl, Ff);
  k_red_sag<<<dim3(772), 256, 0, stream>>>(Gp, G, Gh, Gl, psum, vp, Ff, Et, alp, gam,
                                           scal0);
  kD<<<dim3(20), 512, 0, stream>>>(Eh, El, Gh, Gl, Rh, Rl, G, Et, vp, dlt, gam, scal0,
                                   scal1, b3, cv, Fth, Ftl, Athi, Atlo, alp, bpv, barctr);
  kF<<<dim3(2, 32, NB), 512, 0, stream>>>(Athi, Atlo, Xthi, Xtlo, cv, out);
}

// Round 8
// 102.424 us; speedup vs baseline: 1.6984x; 1.0338x over previous
//
#include <hip/hip_runtime.h>

#define NB 4
#define CD 256
#define HW 4096
#define KSG 16
#define CC (CD * CD)

typedef __attribute__((ext_vector_type(8))) short bf16x8;
typedef __attribute__((ext_vector_type(4))) float f32x4;

__device__ inline unsigned short f2bf(float x) {
  unsigned int u = __float_as_uint(x);
  unsigned int r = (u + 0x7FFFu + ((u >> 16) & 1u)) >> 16;
  return (unsigned short)r;
}
__device__ inline float bfhi(unsigned short h) {
  return __uint_as_float(((unsigned int)h) << 16);
}
__device__ __forceinline__ void gload16(const unsigned short* g, unsigned short* l) {
  __builtin_amdgcn_global_load_lds((const __attribute__((address_space(1))) void*)g,
                                   (__attribute__((address_space(3))) void*)l, 16, 0, 0);
}

// ---------- shared MFMA compute body: reads swizzled LDS (Ah|Al|Bh|Bl @ 8192-elem tiles) ----------
__device__ __forceinline__ void mfma_body(unsigned short* sm, f32x4 acc[4][2]) {
  int t = threadIdx.x, lane = t & 63, wid = t >> 6;
  int wr = wid >> 2, wc = wid & 3;
  int lrow = lane & 15, lkb = lane >> 4;
#pragma unroll
  for (int ks2 = 0; ks2 < 2; ++ks2) {
    bf16x8 ah[4], al[4], bh[2], bl[2];
#pragma unroll
    for (int m = 0; m < 4; ++m) {
      int r = wr * 64 + m * 16 + lrow;
      int sw = ((ks2 * 4 + lkb) ^ (r & 7)) * 8;
      ah[m] = *(const bf16x8*)(sm + r * 64 + sw);
      al[m] = *(const bf16x8*)(sm + 8192 + r * 64 + sw);
    }
#pragma unroll
    for (int q = 0; q < 2; ++q) {
      int r = wc * 32 + q * 16 + lrow;
      int sw = ((ks2 * 4 + lkb) ^ (r & 7)) * 8;
      bh[q] = *(const bf16x8*)(sm + 16384 + r * 64 + sw);
      bl[q] = *(const bf16x8*)(sm + 24576 + r * 64 + sw);
    }
#pragma unroll
    for (int m = 0; m < 4; ++m)
#pragma unroll
      for (int q = 0; q < 2; ++q) {
        acc[m][q] = __builtin_amdgcn_mfma_f32_16x16x32_bf16(ah[m], bh[q], acc[m][q], 0, 0, 0);
        acc[m][q] = __builtin_amdgcn_mfma_f32_16x16x32_bf16(ah[m], bl[q], acc[m][q], 0, 0, 0);
        acc[m][q] = __builtin_amdgcn_mfma_f32_16x16x32_bf16(al[m], bh[q], acc[m][q], 0, 0, 0);
      }
  }
}

// ---------- bf16-operand NT core (all 4 tensors materialized, global_load_lds) ----------
__device__ __forceinline__ void mfma_nt_core(
    const unsigned short* __restrict__ pH, const unsigned short* __restrict__ pL,
    const unsigned short* __restrict__ qH, const unsigned short* __restrict__ qL,
    int i0, int j0, int kBegin, int ldP, int ldQ, unsigned short* sm,
    f32x4 acc[4][2]) {
  int t = threadIdx.x;
  int lane = t & 63, wid = t >> 6;
  int tsel = wid >> 1;
  int gbase = (wid & 1) * 8;
  const unsigned short* bp2 = (tsel == 0) ? pH : (tsel == 1) ? pL : (tsel == 2) ? qH : qL;
  int tb = (tsel < 2) ? i0 : j0;
  int ldT = (tsel < 2) ? ldP : ldQ;
  int rsub = lane >> 3;
  int gc = (lane & 7) ^ rsub;
  unsigned short* ldsT = sm + tsel * 8192;
#pragma unroll
  for (int m = 0; m < 4; ++m)
#pragma unroll
    for (int q = 0; q < 2; ++q) acc[m][q] = (f32x4){0.f, 0.f, 0.f, 0.f};
  for (int k0 = 0; k0 < 256; k0 += 64) {
    int kb = kBegin + k0;
#pragma unroll
    for (int s = 0; s < 8; ++s) {
      int g = gbase + s;
      gload16(bp2 + (size_t)(tb + g * 8 + rsub) * ldT + kb + gc * 8, ldsT + g * 512);
    }
    __syncthreads();
    mfma_body(sm, acc);
    __syncthreads();
  }
}

// ---------- gram core: both operands from X fp32, on-the-fly hi/lo split; psum partials ----------
__device__ __forceinline__ void gram_core(const float* __restrict__ Xn, int i0, int j0,
                                          int kBegin, unsigned short* sm,
                                          f32x4 acc[4][2], float* __restrict__ psumRow) {
  int t = threadIdx.x;
  int r16 = t >> 4, k4 = (t & 15) * 4;
  int kg = k4 >> 3, kr = k4 & 7;
#pragma unroll
  for (int m = 0; m < 4; ++m)
#pragma unroll
    for (int q = 0; q < 2; ++q) acc[m][q] = (f32x4){0.f, 0.f, 0.f, 0.f};
  float ps[4] = {0.f, 0.f, 0.f, 0.f};
  for (int k0 = 0; k0 < 256; k0 += 64) {
    float4 av[4], bv[4];
#pragma unroll
    for (int j = 0; j < 4; ++j) {
      int r = j * 32 + r16;
      av[j] = *(const float4*)(Xn + (size_t)(i0 + r) * HW + kBegin + k0 + k4);
      bv[j] = *(const float4*)(Xn + (size_t)(j0 + r) * HW + kBegin + k0 + k4);
    }
    // prior iteration's trailing __syncthreads protects these writes
#pragma unroll
    for (int j = 0; j < 4; ++j) {
      int r = j * 32 + r16;
      int off = r * 64 + ((kg ^ (r & 7)) << 3) + kr;
      ushort4 h, l;
      h.x = f2bf(av[j].x); l.x = f2bf(av[j].x - bfhi(h.x));
      h.y = f2bf(av[j].y); l.y = f2bf(av[j].y - bfhi(h.y));
      h.z = f2bf(av[j].z); l.z = f2bf(av[j].z - bfhi(h.z));
      h.w = f2bf(av[j].w); l.w = f2bf(av[j].w - bfhi(h.w));
      *(ushort4*)(sm + off) = h;
      *(ushort4*)(sm + 8192 + off) = l;
      ps[j] += av[j].x + av[j].y + av[j].z + av[j].w;
      h.x = f2bf(bv[j].x); l.x = f2bf(bv[j].x - bfhi(h.x));
      h.y = f2bf(bv[j].y); l.y = f2bf(bv[j].y - bfhi(h.y));
      h.z = f2bf(bv[j].z); l.z = f2bf(bv[j].z - bfhi(h.z));
      h.w = f2bf(bv[j].w); l.w = f2bf(bv[j].w - bfhi(h.w));
      *(ushort4*)(sm + 16384 + off) = h;
      *(ushort4*)(sm + 24576 + off) = l;
    }
    __syncthreads();
    mfma_body(sm, acc);
    __syncthreads();
  }
  if (psumRow) {
#pragma unroll
    for (int j = 0; j < 4; ++j) {
      float v = ps[j];
      v += __shfl_xor(v, 1); v += __shfl_xor(v, 2);
      v += __shfl_xor(v, 4); v += __shfl_xor(v, 8);
      if ((t & 15) == 0) psumRow[j * 32 + r16] = v;
    }
  }
}

// ---------- final core: A = At bf16 hi/lo via gload16; B = X fp32 transpose-staged ----------
__device__ __forceinline__ void final_core(const unsigned short* __restrict__ aH,
                                           const unsigned short* __restrict__ aL,
                                           const float* __restrict__ Xn, int i0, int j0,
                                           unsigned short* sm, f32x4 acc[4][2]) {
  int t = threadIdx.x, lane = t & 63, wid = t >> 6;
  const unsigned short* ap = (wid & 4) ? aL : aH;
  unsigned short* ldsA = sm + ((wid & 4) ? 8192 : 0);
  int rsub = lane >> 3;
  int gc = (lane & 7) ^ rsub;
  int gq = wid & 3;
#pragma unroll
  for (int m = 0; m < 4; ++m)
#pragma unroll
    for (int q = 0; q < 2; ++q) acc[m][q] = (f32x4){0.f, 0.f, 0.f, 0.f};
  for (int k0 = 0; k0 < 256; k0 += 64) {
#pragma unroll
    for (int s = 0; s < 4; ++s) {
      int g = gq * 4 + s;
      gload16(ap + (size_t)(i0 + g * 8 + rsub) * CD + k0 + gc * 8, ldsA + g * 512);
    }
    float xa[8], xb[8];
#pragma unroll
    for (int ee = 0; ee < 8; ++ee) {
      int flat = ee * 512 + t;
      int c2 = flat >> 7;       // 0..31 -> c = 2*c2
      int p = flat & 127;
      const float* src = Xn + (size_t)(k0 + 2 * c2) * HW + j0 + p;
      xa[ee] = src[0];
      xb[ee] = src[HW];
    }
    // prior trailing sync protects B writes
#pragma unroll
    for (int ee = 0; ee < 8; ++ee) {
      int flat = ee * 512 + t;
      int c2 = flat >> 7;
      int p = flat & 127;
      int c = 2 * c2;
      int off = p * 64 + ((((c >> 3)) ^ (p & 7)) << 3) + (c & 7);
      unsigned short ha = f2bf(xa[ee]), hb = f2bf(xb[ee]);
      unsigned short la = f2bf(xa[ee] - bfhi(ha)), lb = f2bf(xb[ee] - bfhi(hb));
      ushort2 hv; hv.x = ha; hv.y = hb;
      ushort2 lv; lv.x = la; lv.y = lb;
      *(ushort2*)(sm + 16384 + off) = hv;
      *(ushort2*)(sm + 24576 + off) = lv;
    }
    __syncthreads();
    mfma_body(sm, acc);
    __syncthreads();
  }
}

// ---------- coalesced fp32 epilogue: acc -> LDS (64KB, XOR-swz) -> float4 row stores ----------
__device__ __forceinline__ void epi_store(f32x4 acc[4][2], float* smf, float* dst,
                                          int ld, const float* cvrow) {
  int t = threadIdx.x, lane = t & 63, wid = t >> 6;
  int wr = wid >> 2, wc = wid & 3;
#pragma unroll
  for (int m = 0; m < 4; ++m) {
    int rbase = wr * 64 + m * 16 + ((lane >> 4) << 2);
#pragma unroll
    for (int q = 0; q < 2; ++q) {
      int col = wc * 32 + q * 16 + (lane & 15);
#pragma unroll
      for (int e = 0; e < 4; ++e) {
        int row = rbase + e;
        smf[row * 128 + (col ^ ((row & 4) << 2))] = acc[m][q][e];
      }
    }
  }
  __syncthreads();
#pragma unroll
  for (int it = 0; it < 8; ++it) {
    int row = it * 16 + wid * 2 + (lane >> 5);
    int col = (lane & 31) * 4;
    float4 v = *(const float4*)&smf[row * 128 + (col ^ ((row & 4) << 2))];
    if (cvrow) {
      float cb = cvrow[row];
      v.x += cb; v.y += cb; v.z += cb; v.w += cb;
    }
    *(float4*)(dst + (size_t)row * ld + col) = v;
  }
}

// ---------- kW: weights -> bf16 hi/lo (w3 direct; w0,w1,w2 transposed) + small vectors ----------
__global__ __launch_bounds__(256) void kW(
    const float* __restrict__ w0, const float* __restrict__ w1,
    const float* __restrict__ w2, const float* __restrict__ w3,
    const float* __restrict__ b0, const float* __restrict__ b1,
    const float* __restrict__ b2, unsigned short* __restrict__ w3h,
    unsigned short* __restrict__ w3l, unsigned short* __restrict__ w0th,
    unsigned short* __restrict__ w0tl, unsigned short* __restrict__ w1th,
    unsigned short* __restrict__ w1tl, unsigned short* __restrict__ w2th,
    unsigned short* __restrict__ w2tl, float* __restrict__ vp,
    float* __restrict__ bpv, float* __restrict__ dlt, float* __restrict__ scal1,
    unsigned int* __restrict__ barctr) {
  __shared__ unsigned int W[64][65];
  int z = blockIdx.z, t = threadIdx.x;
  if (z == 0) {
    int i0 = blockIdx.x * 64, k0 = blockIdx.y * 64;
    int r = t >> 2, cb = (t & 3) * 16;
    const float* src = w3 + (size_t)(i0 + r) * CD + k0 + cb;
    size_t o = (size_t)(i0 + r) * CD + k0 + cb;
#pragma unroll
    for (int j = 0; j < 4; ++j) {
      float4 v = *(const float4*)(src + 4 * j);
      ushort4 vh, vl;
      vh.x = f2bf(v.x); vl.x = f2bf(v.x - bfhi(vh.x));
      vh.y = f2bf(v.y); vl.y = f2bf(v.y - bfhi(vh.y));
      vh.z = f2bf(v.z); vl.z = f2bf(v.z - bfhi(vh.z));
      vh.w = f2bf(v.w); vl.w = f2bf(v.w - bfhi(vh.w));
      *(ushort4*)(w3h + o + 4 * j) = vh;
      *(ushort4*)(w3l + o + 4 * j) = vl;
    }
  } else if (z < 4) {
    const float* w = (z == 1) ? w0 : (z == 2) ? w1 : w2;
    unsigned short* oh = (z == 1) ? w0th : (z == 2) ? w1th : w2th;
    unsigned short* ol = (z == 1) ? w0tl : (z == 2) ? w1tl : w2tl;
    int k0 = blockIdx.x * 64, j0 = blockIdx.y * 64;
    int kl = t >> 2, jb = (t & 3) * 16;
    const float* src = w + (size_t)(k0 + kl) * CD + j0 + jb;
#pragma unroll
    for (int j = 0; j < 4; ++j) {
      float4 v = *(const float4*)(src + 4 * j);
      unsigned short h0 = f2bf(v.x), h1 = f2bf(v.y), h2 = f2bf(v.z), h3 = f2bf(v.w);
      W[kl][jb + 4 * j + 0] = (((unsigned int)h0) << 16) | f2bf(v.x - bfhi(h0));
      W[kl][jb + 4 * j + 1] = (((unsigned int)h1) << 16) | f2bf(v.y - bfhi(h1));
      W[kl][jb + 4 * j + 2] = (((unsigned int)h2) << 16) | f2bf(v.z - bfhi(h2));
      W[kl][jb + 4 * j + 3] = (((unsigned int)h3) << 16) | f2bf(v.w - bfhi(h3));
    }
    __syncthreads();
    int jl = t >> 2, kb = (t & 3) * 16;
    size_t o = (size_t)(j0 + jl) * CD + k0 + kb;
#pragma unroll
    for (int j = 0; j < 4; ++j) {
      unsigned int a0 = W[kb + 4 * j + 0][jl];
      unsigned int a1 = W[kb + 4 * j + 1][jl];
      unsigned int a2 = W[kb + 4 * j + 2][jl];
      unsigned int a3 = W[kb + 4 * j + 3][jl];
      ushort4 vh, vl;
      vh.x = (unsigned short)(a0 >> 16); vl.x = (unsigned short)(a0 & 0xffff);
      vh.y = (unsigned short)(a1 >> 16); vl.y = (unsigned short)(a1 & 0xffff);
      vh.z = (unsigned short)(a2 >> 16); vl.z = (unsigned short)(a2 & 0xffff);
      vh.w = (unsigned short)(a3 >> 16); vl.w = (unsigned short)(a3 & 0xffff);
      *(ushort4*)(oh + o + 4 * j) = vh;
      *(ushort4*)(ol + o + 4 * j) = vl;
    }
  } else {
    int task = blockIdx.x * 4 + blockIdx.y;
    if (task == 0 && t == 0) *barctr = 0u;
    if (task < 8) {
      float* vin = (float*)W;
      int seg = task & 3;
      const float* Wm = (task < 4) ? w1 : w2;
      const float* v = (task < 4) ? b2 : b1;
      float* dst = (task < 4) ? (vp + seg * CD) : (bpv + seg * CD);
      if (t < 64) vin[t] = v[seg * 64 + t];
      __syncthreads();
      float a = 0.f;
#pragma unroll 16
      for (int kk = 0; kk < 64; ++kk)
        a += Wm[(size_t)(seg * 64 + kk) * CD + t] * vin[kk];
      dst[t] = a;
    } else if (task < 12) {
      int lane = t & 63, wv = t >> 6;
      float4 bv = *(const float4*)(b0 + lane * 4);
#pragma unroll 4
      for (int i = 0; i < 16; ++i) {
        int o = (task - 8) * 64 + wv * 16 + i;
        float4 v = *(const float4*)(w3 + (size_t)o * CD + lane * 4);
        float a = v.x * bv.x + v.y * bv.y + v.z * bv.z + v.w * bv.w;
        a += __shfl_xor(a, 1);  a += __shfl_xor(a, 2);  a += __shfl_xor(a, 4);
        a += __shfl_xor(a, 8);  a += __shfl_xor(a, 16); a += __shfl_xor(a, 32);
        if (lane == 0) dlt[o] = a;
      }
    } else if (task == 12) {
      float* red = (float*)W;
      red[t] = b1[t] * b2[t];
      __syncthreads();
      for (int off = 128; off > 0; off >>= 1) {
        if (t < off) red[t] += red[t + off];
        __syncthreads();
      }
      if (t == 0) scal1[0] = red[0];
    }
  }
}

// ---------- kB: gram from X fp32 (3 symmetric tiles x 64) + EFm (8 blocks at y==64) ----------
__global__ __launch_bounds__(512) void kB(
    const float* __restrict__ X, float* __restrict__ Gp, float* __restrict__ psum2,
    const unsigned short* __restrict__ w3h, const unsigned short* __restrict__ w3l,
    const unsigned short* __restrict__ w0th, const unsigned short* __restrict__ w0tl,
    const unsigned short* __restrict__ w1th, const unsigned short* __restrict__ w1tl,
    const unsigned short* __restrict__ w2th, const unsigned short* __restrict__ w2tl,
    unsigned short* __restrict__ Eh, unsigned short* __restrict__ El,
    float* __restrict__ Et, unsigned short* __restrict__ Fth,
    unsigned short* __restrict__ Ftl, float* __restrict__ Ff) {
  __shared__ __align__(16) unsigned short sm[4 * 8192];
  int x = blockIdx.x, y = blockIdx.y;
  if (y < 64) {
    if (x >= 3) return;
    int n = y >> 4, ks = y & 15;
    int i0 = (x == 2) ? 128 : 0;
    int j0 = (x == 0) ? 0 : 128;
    const float* Xn = X + (size_t)n * CD * HW;
    float* psRow = nullptr;
    if (x == 0) psRow = psum2 + ((size_t)n * 16 + ks) * 256;
    else if (x == 2) psRow = psum2 + ((size_t)n * 16 + ks) * 256 + 128;
    f32x4 acc[4][2];
    gram_core(Xn, i0, j0, ks * 256, sm, acc, psRow);
    epi_store(acc, (float*)sm, Gp + ((size_t)ks * NB + n) * CC + (size_t)i0 * CD + j0,
              CD, nullptr);
  } else {
    int zc = x >> 2, j0 = ((x >> 1) & 1) * 128, i0 = (x & 1) * 128;
    const unsigned short* pH = zc ? w2th : w3h;
    const unsigned short* pL = zc ? w2tl : w3l;
    const unsigned short* qH = zc ? w1th : w0th;
    const unsigned short* qL = zc ? w1tl : w0tl;
    unsigned short* oh = zc ? Fth : Eh;
    unsigned short* ol = zc ? Ftl : El;
    float* tf = zc ? Ff : Et;
    f32x4 acc[4][2];
    mfma_nt_core(pH, pL, qH, qL, i0, j0, 0, CD, CD, sm, acc);
    int lane = threadIdx.x & 63, wid = threadIdx.x >> 6;
    int wr = wid >> 2, wc = wid & 3;
#pragma unroll
    for (int m = 0; m < 4; ++m) {
      int row = i0 + wr * 64 + m * 16 + ((lane >> 4) << 2);
#pragma unroll
      for (int q = 0; q < 2; ++q) {
        int col = j0 + wc * 32 + q * 16 + (lane & 15);
#pragma unroll
        for (int e = 0; e < 4; ++e) {
          float v = acc[m][q][e];
          unsigned short hh = f2bf(v), ll = f2bf(v - bfhi(hh));
          oh[(size_t)(row + e) * CD + col] = hh;
          ol[(size_t)(row + e) * CD + col] = ll;
          tf[(size_t)col * CD + row + e] = v;
        }
      }
    }
  }
}

// ---------- kC: gram reduce (+mirror, +bf16 hi/lo) fused with s/alp/gam/scal0 ----------
__global__ __launch_bounds__(256) void k_red_sag(
    const float* __restrict__ Gp, float* __restrict__ G,
    unsigned short* __restrict__ Gh, unsigned short* __restrict__ Gl,
    const float* __restrict__ psum2, const float* __restrict__ vp,
    const float* __restrict__ Ff, const float* __restrict__ Et,
    float* __restrict__ alp, float* __restrict__ gam, float* __restrict__ scal0) {
  int b = blockIdx.x, t = threadIdx.x;
  if (b < 768) {
    int quad = b >> 8;
    int r = b & 255;
    int n = r >> 6;
    int idx = (r & 63) * 256 + t;
    int i = (idx >> 7) + ((quad == 2) ? 128 : 0);
    int j = (idx & 127) + ((quad >= 1) ? 128 : 0);
    float a = 0.f;
#pragma unroll
    for (int ks = 0; ks < KSG; ++ks)
      a += Gp[((size_t)ks * NB + n) * CC + (size_t)i * CD + j];
    size_t o = (size_t)n * CC + (size_t)i * CD + j;
    unsigned short hh = f2bf(a), ll = f2bf(a - bfhi(hh));
    G[o] = a; Gh[o] = hh; Gl[o] = ll;
    if (quad == 1) {
      size_t o2 = (size_t)n * CC + (size_t)j * CD + i;
      G[o2] = a; Gh[o2] = hh; Gl[o2] = ll;
    }
  } else {
    int n = b - 768;
    __shared__ float ss[CD];
    __shared__ float red[256];
    float a = 0.f;
#pragma unroll
    for (int ks = 0; ks < 16; ++ks) a += psum2[((size_t)n * 16 + ks) * 256 + t];
    ss[t] = a;
    float v1c = vp[t] + vp[CD + t] + vp[2 * CD + t] + vp[3 * CD + t];
    red[t] = a * v1c;
    __syncthreads();
    for (int off = 128; off > 0; off >>= 1) {
      if (t < off) red[t] += red[t + off];
      __syncthreads();
    }
    if (t == 0) scal0[n] = red[0];
    float al = 0.f, ga = 0.f;
#pragma unroll 16
    for (int k = 0; k < CD; ++k) {
      float sk = ss[k];
      al += Ff[(size_t)k * CD + t] * sk;
      ga += Et[(size_t)k * CD + t] * sk;
    }
    alp[n * CD + t] = al;
    gam[n * CD + t] = ga;
  }
}

// ---------- kD: Rm + cv, device barrier, Atm (20 blocks, all co-resident) ----------
__global__ __launch_bounds__(512) void kD(
    const unsigned short* __restrict__ Eh, const unsigned short* __restrict__ El,
    const unsigned short* __restrict__ Gh, const unsigned short* __restrict__ Gl,
    unsigned short* __restrict__ Rh, unsigned short* __restrict__ Rl,
    const float* __restrict__ G, const float* __restrict__ Et,
    const float* __restrict__ vp, const float* __restrict__ dlt,
    const float* __restrict__ gam, const float* __restrict__ scal0,
    const float* __restrict__ scal1, const float* __restrict__ b3,
    float* __restrict__ cv, const unsigned short* __restrict__ Fth,
    const unsigned short* __restrict__ Ftl, unsigned short* __restrict__ Athi,
    unsigned short* __restrict__ Atlo, const float* __restrict__ alp,
    const float* __restrict__ bpv, unsigned int* __restrict__ barctr) {
  __shared__ __align__(16) unsigned short sm[4 * 8192];
  int b = blockIdx.x, t = threadIdx.x;
  if (b < 16) {
    int n = b >> 2, i0 = ((b >> 1) & 1) * 128, j0 = (b & 1) * 128;
    f32x4 acc[4][2];
    mfma_nt_core(Eh, El, Gh + (size_t)n * CC, Gl + (size_t)n * CC, i0, j0, 0, CD, CD, sm,
                 acc);
    int lane = t & 63, wid = t >> 6, wr = wid >> 2, wc = wid & 3;
#pragma unroll
    for (int m = 0; m < 4; ++m) {
      int row = i0 + wr * 64 + m * 16 + ((lane >> 4) << 2);
#pragma unroll
      for (int q = 0; q < 2; ++q) {
        int col = j0 + wc * 32 + q * 16 + (lane & 15);
#pragma unroll
        for (int e = 0; e < 4; ++e) {
          float v = acc[m][q][e];
          unsigned short hh = f2bf(v), ll = f2bf(v - bfhi(hh));
          Rh[(size_t)n * CC + (size_t)(row + e) * CD + col] = hh;
          Rl[(size_t)n * CC + (size_t)(row + e) * CD + col] = ll;
        }
      }
    }
  } else {
    int n = b - 16;
    float* vsh = (float*)sm;
    float* g1 = vsh + CD;
    if (t < CD) vsh[t] = vp[t] + vp[CD + t] + vp[2 * CD + t] + vp[3 * CD + t];
    __syncthreads();
    if (t < CD) {
      const float* Gn = G + (size_t)n * CC;
      float a = 0.f;
#pragma unroll 8
      for (int k = 0; k < CD; ++k) a += Gn[(size_t)k * CD + t] * vsh[k];
      g1[t] = a;
    }
    __syncthreads();
    if (t < CD) {
      float c2 = 0.f;
#pragma unroll 8
      for (int k = 0; k < CD; ++k) c2 += Et[(size_t)k * CD + t] * g1[k];
      float s0 = scal0[n], s1 = scal1[0];
      cv[n * CD + t] =
          (c2 + s0 * dlt[t] + s1 * (gam[n * CD + t] + (float)HW * dlt[t])) * (1.0f / HW) +
          b3[t];
    }
  }
  __syncthreads();
  if (t == 0) {
    __threadfence();
    atomicAdd(barctr, 1u);
    while (__hip_atomic_load(barctr, __ATOMIC_ACQUIRE, __HIP_MEMORY_SCOPE_AGENT) < 20u) {
    }
    __threadfence();
  }
  __syncthreads();
  if (b < 16) {
    int n = b >> 2, i0 = ((b >> 1) & 1) * 128, j0 = (b & 1) * 128;
    f32x4 acc[4][2];
    mfma_nt_core(Rh + (size_t)n * CC, Rl + (size_t)n * CC, Fth, Ftl, i0, j0, 0, CD, CD,
                 sm, acc);
    int lane = t & 63, wid = t >> 6, wr = wid >> 2, wc = wid & 3;
#pragma unroll
    for (int m = 0; m < 4; ++m) {
      int row = i0 + wr * 64 + m * 16 + ((lane >> 4) << 2);
#pragma unroll
      for (int q = 0; q < 2; ++q) {
        int col = j0 + wc * 32 + q * 16 + (lane & 15);
        float bj = bpv[col] + bpv[CD + col] + bpv[2 * CD + col] + bpv[3 * CD + col];
        float aj = alp[n * CD + col];
#pragma unroll
        for (int e = 0; e < 4; ++e) {
          float di = dlt[row + e], gi = gam[n * CD + row + e];
          float v = (acc[m][q][e] + di * aj + gi * bj) * (1.0f / HW) + di * bj;
          unsigned short hh = f2bf(v), ll = f2bf(v - bfhi(hh));
          Athi[(size_t)n * CC + (size_t)(row + e) * CD + col] = hh;
          Atlo[(size_t)n * CC + (size_t)(row + e) * CD + col] = ll;
        }
      }
    }
  }
}

// ---------- kF: out = At x X (B transposed+split on the fly) + cv ----------
__global__ __launch_bounds__(512) void kF(const unsigned short* __restrict__ Athi,
                                          const unsigned short* __restrict__ Atlo,
                                          const float* __restrict__ X,
                                          const float* __restrict__ cv,
                                          float* __restrict__ out) {
  int n = blockIdx.z;
  int i0 = blockIdx.x * 128, j0 = blockIdx.y * 128;
  __shared__ __align__(16) unsigned short sm[4 * 8192];
  f32x4 acc[4][2];
  final_core(Athi + (size_t)n * CC, Atlo + (size_t)n * CC, X + (size_t)n * CD * HW, i0,
             j0, sm, acc);
  epi_store(acc, (float*)sm, out + (size_t)n * CD * HW + (size_t)i0 * HW + j0, HW,
            cv + n * CD + i0);
}

extern "C" void kernel_launch(void* const* d_in, const int* in_sizes, int n_in,
                              void* d_out, int out_size, void* d_ws, size_t ws_size,
                              hipStream_t stream) {
  const float* X = (const float*)d_in[0];
  const float* w0 = (const float*)d_in[1];
  const float* b0 = (const float*)d_in[2];
  const float* w1 = (const float*)d_in[3];
  const float* b1 = (const float*)d_in[4];
  const float* w2 = (const float*)d_in[5];
  const float* b2 = (const float*)d_in[6];
  const float* w3 = (const float*)d_in[7];
  const float* b3 = (const float*)d_in[8];
  float* out = (float*)d_out;
  float* ws = (float*)d_ws;

  float* cv    = ws;
  float* alp   = ws + 1024;
  float* gam   = ws + 2048;
  float* dlt   = ws + 3072;
  float* vp    = ws + 4096;
  float* bpv   = ws + 5120;
  float* scal0 = ws + 6144;
  float* scal1 = ws + 6176;
  unsigned int* barctr = (unsigned int*)(ws + 6208);
  float* psum2 = ws + 8192;                    // NB*16*256 = 16384
  float* Et    = psum2 + 16384;
  float* Ff    = Et + CC;
  float* G     = Ff + CC;                      // NB*CC
  float* Gp    = G + (size_t)NB * CC;          // KSG*NB*CC
  unsigned short* w3h  = (unsigned short*)(Gp + (size_t)KSG * NB * CC);
  unsigned short* w3l  = w3h + CC;
  unsigned short* w0th = w3l + CC;
  unsigned short* w0tl = w0th + CC;
  unsigned short* w1th = w0tl + CC;
  unsigned short* w1tl = w1th + CC;
  unsigned short* w2th = w1tl + CC;
  unsigned short* w2tl = w2th + CC;
  unsigned short* Eh   = w2tl + CC;
  unsigned short* El   = Eh + CC;
  unsigned short* Fth  = El + CC;
  unsigned short* Ftl  = Fth + CC;
  unsigned short* Gh   = Ftl + CC;
  unsigned short* Gl   = Gh + (size_t)NB * CC;
  unsigned short* Rh   = Gl + (size_t)NB * CC;
  unsigned short* Rl   = Rh + (size_t)NB * CC;
  unsigned short* Athi = Rl + (size_t)NB * CC;
  unsigned short* Atlo = Athi + (size_t)NB * CC;

  kW<<<dim3(4, 4, 5), 256, 0, stream>>>(w0, w1, w2, w3, b0, b1, b2, w3h, w3l, w0th,
                                        w0tl, w1th, w1tl, w2th, w2tl, vp, bpv, dlt,
                                        scal1, barctr);
  kB<<<dim3(8, 65), 512, 0, stream>>>(X, Gp, psum2, w3h, w3l, w0th, w0tl, w1th, w1tl,
                                      w2th, w2tl, Eh, El, Et, Fth, Ftl, Ff);
  k_red_sag<<<dim3(772), 256, 0, stream>>>(Gp, G, Gh, Gl, psum2, vp, Ff, Et, alp, gam,
                                           scal0);
  kD<<<dim3(20), 512, 0, stream>>>(Eh, El, Gh, Gl, Rh, Rl, G, Et, vp, dlt, gam, scal0,
                                   scal1, b3, cv, Fth, Ftl, Athi, Atlo, alp, bpv, barctr);
  kF<<<dim3(2, 32, NB), 512, 0, stream>>>(Athi, Atlo, X, cv, out);
}

// Round 9
// 96.704 us; speedup vs baseline: 1.7989x; 1.0592x over previous
//
#include <hip/hip_runtime.h>

#define NB 4
#define CD 256
#define HW 4096
#define KSG 16
#define CC (CD * CD)

typedef __attribute__((ext_vector_type(8))) short bf16x8;
typedef __attribute__((ext_vector_type(4))) float f32x4;

__device__ inline unsigned short f2bf(float x) {
  unsigned int u = __float_as_uint(x);
  unsigned int r = (u + 0x7FFFu + ((u >> 16) & 1u)) >> 16;
  return (unsigned short)r;
}
__device__ inline float bfhi(unsigned short h) {
  return __uint_as_float(((unsigned int)h) << 16);
}
__device__ __forceinline__ void gload16(const unsigned short* g, unsigned short* l) {
  __builtin_amdgcn_global_load_lds((const __attribute__((address_space(1))) void*)g,
                                   (__attribute__((address_space(3))) void*)l, 16, 0, 0);
}

// ---------- MFMA body: A at sm[0]/sm[8192], B at sm[BOFF]/sm[BOFF+8192] ----------
template <int BOFF>
__device__ __forceinline__ void mfma_body(const unsigned short* sm, f32x4 acc[4][2]) {
  int t = threadIdx.x, lane = t & 63, wid = t >> 6;
  int wr = wid >> 2, wc = wid & 3;
  int lrow = lane & 15, lkb = lane >> 4;
#pragma unroll
  for (int ks2 = 0; ks2 < 2; ++ks2) {
    bf16x8 ah[4], al[4], bh[2], bl[2];
#pragma unroll
    for (int m = 0; m < 4; ++m) {
      int r = wr * 64 + m * 16 + lrow;
      int sw = ((ks2 * 4 + lkb) ^ (r & 7)) * 8;
      ah[m] = *(const bf16x8*)(sm + r * 64 + sw);
      al[m] = *(const bf16x8*)(sm + 8192 + r * 64 + sw);
    }
#pragma unroll
    for (int q = 0; q < 2; ++q) {
      int r = wc * 32 + q * 16 + lrow;
      int sw = ((ks2 * 4 + lkb) ^ (r & 7)) * 8;
      bh[q] = *(const bf16x8*)(sm + BOFF + r * 64 + sw);
      bl[q] = *(const bf16x8*)(sm + BOFF + 8192 + r * 64 + sw);
    }
#pragma unroll
    for (int m = 0; m < 4; ++m)
#pragma unroll
      for (int q = 0; q < 2; ++q) {
        acc[m][q] = __builtin_amdgcn_mfma_f32_16x16x32_bf16(ah[m], bh[q], acc[m][q], 0, 0, 0);
        acc[m][q] = __builtin_amdgcn_mfma_f32_16x16x32_bf16(ah[m], bl[q], acc[m][q], 0, 0, 0);
        acc[m][q] = __builtin_amdgcn_mfma_f32_16x16x32_bf16(al[m], bh[q], acc[m][q], 0, 0, 0);
      }
  }
}

// ---------- bf16-operand NT core (gload16 staging; used by kDC) ----------
__device__ __forceinline__ void mfma_nt_core(
    const unsigned short* __restrict__ pH, const unsigned short* __restrict__ pL,
    const unsigned short* __restrict__ qH, const unsigned short* __restrict__ qL,
    int i0, int j0, unsigned short* sm, f32x4 acc[4][2]) {
  int t = threadIdx.x;
  int lane = t & 63, wid = t >> 6;
  int tsel = wid >> 1;
  int gbase = (wid & 1) * 8;
  const unsigned short* bp2 = (tsel == 0) ? pH : (tsel == 1) ? pL : (tsel == 2) ? qH : qL;
  int tb = (tsel < 2) ? i0 : j0;
  int rsub = lane >> 3;
  int gc = (lane & 7) ^ rsub;
  unsigned short* ldsT = sm + tsel * 8192;
#pragma unroll
  for (int m = 0; m < 4; ++m)
#pragma unroll
    for (int q = 0; q < 2; ++q) acc[m][q] = (f32x4){0.f, 0.f, 0.f, 0.f};
  for (int k0 = 0; k0 < 256; k0 += 64) {
#pragma unroll
    for (int s = 0; s < 8; ++s) {
      int g = gbase + s;
      gload16(bp2 + (size_t)(tb + g * 8 + rsub) * CD + k0 + gc * 8, ldsT + g * 512);
    }
    __syncthreads();
    mfma_body<16384>(sm, acc);
    __syncthreads();
  }
}

// ---------- gram core: operands from X fp32, reg-prefetch; DIAG stages A only ----------
template <bool DIAG>
__device__ __forceinline__ void gram_core(const float* __restrict__ Xn, int i0, int j0,
                                          int kBegin, unsigned short* sm,
                                          f32x4 acc[4][2], float* __restrict__ psumRow) {
  int t = threadIdx.x;
  int r16 = t >> 4, k4 = (t & 15) * 4;
  int kg = k4 >> 3, kr = k4 & 7;
#pragma unroll
  for (int m = 0; m < 4; ++m)
#pragma unroll
    for (int q = 0; q < 2; ++q) acc[m][q] = (f32x4){0.f, 0.f, 0.f, 0.f};
  float ps[4] = {0.f, 0.f, 0.f, 0.f};
  float4 av[4], bv[4];
#pragma unroll
  for (int j = 0; j < 4; ++j) {
    av[j] = *(const float4*)(Xn + (size_t)(i0 + j * 32 + r16) * HW + kBegin + k4);
    if (!DIAG)
      bv[j] = *(const float4*)(Xn + (size_t)(j0 + j * 32 + r16) * HW + kBegin + k4);
  }
#pragma unroll
  for (int s = 0; s < 4; ++s) {
    float4 av2[4], bv2[4];
    if (s < 3) {
#pragma unroll
      for (int j = 0; j < 4; ++j) {
        av2[j] = *(const float4*)(Xn + (size_t)(i0 + j * 32 + r16) * HW + kBegin +
                                  (s + 1) * 64 + k4);
        if (!DIAG)
          bv2[j] = *(const float4*)(Xn + (size_t)(j0 + j * 32 + r16) * HW + kBegin +
                                    (s + 1) * 64 + k4);
      }
    }
#pragma unroll
    for (int j = 0; j < 4; ++j) {
      int r = j * 32 + r16;
      int off = r * 64 + ((kg ^ (r & 7)) << 3) + kr;
      ushort4 h, l;
      h.x = f2bf(av[j].x); l.x = f2bf(av[j].x - bfhi(h.x));
      h.y = f2bf(av[j].y); l.y = f2bf(av[j].y - bfhi(h.y));
      h.z = f2bf(av[j].z); l.z = f2bf(av[j].z - bfhi(h.z));
      h.w = f2bf(av[j].w); l.w = f2bf(av[j].w - bfhi(h.w));
      *(ushort4*)(sm + off) = h;
      *(ushort4*)(sm + 8192 + off) = l;
      ps[j] += av[j].x + av[j].y + av[j].z + av[j].w;
      if (!DIAG) {
        h.x = f2bf(bv[j].x); l.x = f2bf(bv[j].x - bfhi(h.x));
        h.y = f2bf(bv[j].y); l.y = f2bf(bv[j].y - bfhi(h.y));
        h.z = f2bf(bv[j].z); l.z = f2bf(bv[j].z - bfhi(h.z));
        h.w = f2bf(bv[j].w); l.w = f2bf(bv[j].w - bfhi(h.w));
        *(ushort4*)(sm + 16384 + off) = h;
        *(ushort4*)(sm + 24576 + off) = l;
      }
    }
    __syncthreads();
    mfma_body<DIAG ? 0 : 16384>(sm, acc);
    __syncthreads();
    if (s < 3) {
#pragma unroll
      for (int j = 0; j < 4; ++j) {
        av[j] = av2[j];
        if (!DIAG) bv[j] = bv2[j];
      }
    }
  }
  if (psumRow) {
#pragma unroll
    for (int j = 0; j < 4; ++j) {
      float v = ps[j];
      v += __shfl_xor(v, 1); v += __shfl_xor(v, 2);
      v += __shfl_xor(v, 4); v += __shfl_xor(v, 8);
      if ((t & 15) == 0) psumRow[j * 32 + r16] = v;
    }
  }
}

// ---------- ROW-stage: LDS[r][k] = W[r0+r][k0+k] (hi/lo), rows contiguous in k ----------
__device__ __forceinline__ void stage_rowA(const float* __restrict__ W, int ld, int r0,
                                           int k0, unsigned short* dst) {
  int t = threadIdx.x;
  int r16 = t >> 4, k4 = (t & 15) * 4;
  int kg = k4 >> 3, kr = k4 & 7;
#pragma unroll
  for (int j = 0; j < 4; ++j) {
    int r = j * 32 + r16;
    float4 v = *(const float4*)(W + (size_t)(r0 + r) * ld + k0 + k4);
    int off = r * 64 + ((kg ^ (r & 7)) << 3) + kr;
    ushort4 h, l;
    h.x = f2bf(v.x); l.x = f2bf(v.x - bfhi(h.x));
    h.y = f2bf(v.y); l.y = f2bf(v.y - bfhi(h.y));
    h.z = f2bf(v.z); l.z = f2bf(v.z - bfhi(h.z));
    h.w = f2bf(v.w); l.w = f2bf(v.w - bfhi(h.w));
    *(ushort4*)(dst + off) = h;
    *(ushort4*)(dst + 8192 + off) = l;
  }
}

// ---------- COL-stage (transpose): LDS[c][k] = W[k0+k][c0+c] (hi/lo) ----------
__device__ __forceinline__ void stage_colT(const float* __restrict__ W, int ld, int c0,
                                           int k0, unsigned short* dst) {
  int t = threadIdx.x;
#pragma unroll
  for (int ee = 0; ee < 8; ++ee) {
    int flat = ee * 512 + t;
    int c2 = flat >> 7, p = flat & 127;
    const float* src = W + (size_t)(k0 + 2 * c2) * ld + c0 + p;
    float xa = src[0], xb = src[ld];
    int c = 2 * c2;
    int off = p * 64 + ((((c >> 3)) ^ (p & 7)) << 3) + (c & 7);
    unsigned short ha = f2bf(xa), hb = f2bf(xb);
    ushort2 hv; hv.x = ha; hv.y = hb;
    ushort2 lv; lv.x = f2bf(xa - bfhi(ha)); lv.y = f2bf(xb - bfhi(hb));
    *(ushort2*)(dst + off) = hv;
    *(ushort2*)(dst + 8192 + off) = lv;
  }
}

// ---------- final core: A = At bf16 via gload16; B = X fp32 transpose-staged w/ prefetch ----------
__device__ __forceinline__ void final_core(const unsigned short* __restrict__ aH,
                                           const unsigned short* __restrict__ aL,
                                           const float* __restrict__ Xn, int i0, int j0,
                                           unsigned short* sm, f32x4 acc[4][2]) {
  int t = threadIdx.x, lane = t & 63, wid = t >> 6;
  const unsigned short* ap = (wid & 4) ? aL : aH;
  unsigned short* ldsA = sm + ((wid & 4) ? 8192 : 0);
  int rsub = lane >> 3;
  int gc = (lane & 7) ^ rsub;
  int gq = wid & 3;
#pragma unroll
  for (int m = 0; m < 4; ++m)
#pragma unroll
    for (int q = 0; q < 2; ++q) acc[m][q] = (f32x4){0.f, 0.f, 0.f, 0.f};
  float xa[8], xb[8];
#pragma unroll
  for (int s2 = 0; s2 < 4; ++s2) {
    int g = gq * 4 + s2;
    gload16(ap + (size_t)(i0 + g * 8 + rsub) * CD + gc * 8, ldsA + g * 512);
  }
#pragma unroll
  for (int ee = 0; ee < 8; ++ee) {
    int flat = ee * 512 + t;
    int c2 = flat >> 7, p = flat & 127;
    const float* src = Xn + (size_t)(2 * c2) * HW + j0 + p;
    xa[ee] = src[0];
    xb[ee] = src[HW];
  }
#pragma unroll
  for (int s = 0; s < 4; ++s) {
#pragma unroll
    for (int ee = 0; ee < 8; ++ee) {
      int flat = ee * 512 + t;
      int c2 = flat >> 7, p = flat & 127;
      int c = 2 * c2;
      int off = p * 64 + ((((c >> 3)) ^ (p & 7)) << 3) + (c & 7);
      unsigned short ha = f2bf(xa[ee]), hb = f2bf(xb[ee]);
      ushort2 hv; hv.x = ha; hv.y = hb;
      ushort2 lv; lv.x = f2bf(xa[ee] - bfhi(ha)); lv.y = f2bf(xb[ee] - bfhi(hb));
      *(ushort2*)(sm + 16384 + off) = hv;
      *(ushort2*)(sm + 24576 + off) = lv;
    }
    float xa2[8], xb2[8];
    if (s < 3) {
#pragma unroll
      for (int ee = 0; ee < 8; ++ee) {
        int flat = ee * 512 + t;
        int c2 = flat >> 7, p = flat & 127;
        const float* src = Xn + (size_t)((s + 1) * 64 + 2 * c2) * HW + j0 + p;
        xa2[ee] = src[0];
        xb2[ee] = src[HW];
      }
    }
    __syncthreads();
    mfma_body<16384>(sm, acc);
    __syncthreads();
    if (s < 3) {
#pragma unroll
      for (int s2 = 0; s2 < 4; ++s2) {
        int g = gq * 4 + s2;
        gload16(ap + (size_t)(i0 + g * 8 + rsub) * CD + (s + 1) * 64 + gc * 8,
                ldsA + g * 512);
      }
#pragma unroll
      for (int ee = 0; ee < 8; ++ee) { xa[ee] = xa2[ee]; xb[ee] = xb2[ee]; }
    }
  }
}

// ---------- coalesced fp32 epilogue ----------
__device__ __forceinline__ void epi_store(f32x4 acc[4][2], float* smf, float* dst,
                                          int ld, const float* cvrow) {
  int t = threadIdx.x, lane = t & 63, wid = t >> 6;
  int wr = wid >> 2, wc = wid & 3;
#pragma unroll
  for (int m = 0; m < 4; ++m) {
    int rbase = wr * 64 + m * 16 + ((lane >> 4) << 2);
#pragma unroll
    for (int q = 0; q < 2; ++q) {
      int col = wc * 32 + q * 16 + (lane & 15);
#pragma unroll
      for (int e = 0; e < 4; ++e) {
        int row = rbase + e;
        smf[row * 128 + (col ^ ((row & 4) << 2))] = acc[m][q][e];
      }
    }
  }
  __syncthreads();
#pragma unroll
  for (int it = 0; it < 8; ++it) {
    int row = it * 16 + wid * 2 + (lane >> 5);
    int col = (lane & 31) * 4;
    float4 v = *(const float4*)&smf[row * 128 + (col ^ ((row & 4) << 2))];
    if (cvrow) {
      float cb = cvrow[row];
      v.x += cb; v.y += cb; v.z += cb; v.w += cb;
    }
    *(float4*)(dst + (size_t)row * ld + col) = v;
  }
}

// ---------- kB: gram (192) + EF on-the-fly (8) + small vectors (13) ----------
__global__ __launch_bounds__(512) void kB(
    const float* __restrict__ X, float* __restrict__ Gp, float* __restrict__ psum2,
    const float* __restrict__ w0, const float* __restrict__ w1,
    const float* __restrict__ w2, const float* __restrict__ w3,
    const float* __restrict__ b0, const float* __restrict__ b1,
    const float* __restrict__ b2, unsigned short* __restrict__ Eh,
    unsigned short* __restrict__ El, float* __restrict__ Et,
    unsigned short* __restrict__ Fth, unsigned short* __restrict__ Ftl,
    float* __restrict__ Ff, float* __restrict__ vp, float* __restrict__ bpv,
    float* __restrict__ dlt, float* __restrict__ scal1,
    unsigned int* __restrict__ barctr) {
  __shared__ __align__(16) unsigned short sm[32768];
  int x = blockIdx.x, t = threadIdx.x;
  if (x < 192) {
    int tile = x % 3;  // 0: (0,0) diag, 1: (0,128), 2: (128,128) diag
    int z = x / 3;
    int n = z >> 4, ks = z & 15;
    const float* Xn = X + (size_t)n * CD * HW;
    f32x4 acc[4][2];
    if (tile == 1) {
      gram_core<false>(Xn, 0, 128, ks * 256, sm, acc, nullptr);
      epi_store(acc, (float*)sm, Gp + ((size_t)ks * NB + n) * CC + 128, CD, nullptr);
    } else {
      int i0 = (tile == 2) ? 128 : 0;
      float* psRow = psum2 + ((size_t)n * 16 + ks) * 256 + i0;
      gram_core<true>(Xn, i0, i0, ks * 256, sm, acc, psRow);
      epi_store(acc, (float*)sm,
                Gp + ((size_t)ks * NB + n) * CC + (size_t)i0 * CD + i0, CD, nullptr);
    }
  } else if (x < 200) {
    int e = x - 192;
    int zc = e >> 2, q = e & 3;
    int i0 = (q >> 1) * 128, j0 = (q & 1) * 128;
    f32x4 acc[4][2];
#pragma unroll
    for (int m = 0; m < 4; ++m)
#pragma unroll
      for (int qq = 0; qq < 2; ++qq) acc[m][qq] = (f32x4){0.f, 0.f, 0.f, 0.f};
    for (int s = 0; s < 4; ++s) {
      int k0 = s * 64;
      if (zc == 0) stage_rowA(w3, CD, i0, k0, sm);
      else stage_colT(w2, CD, i0, k0, sm);
      stage_colT(zc ? w1 : w0, CD, j0, k0, sm + 16384);
      __syncthreads();
      mfma_body<16384>(sm, acc);
      __syncthreads();
    }
    unsigned short* oh = zc ? Fth : Eh;
    unsigned short* ol = zc ? Ftl : El;
    float* tf = zc ? Ff : Et;
    int lane = t & 63, wid = t >> 6, wr = wid >> 2, wc = wid & 3;
#pragma unroll
    for (int m = 0; m < 4; ++m) {
      int row = i0 + wr * 64 + m * 16 + ((lane >> 4) << 2);
#pragma unroll
      for (int q2 = 0; q2 < 2; ++q2) {
        int col = j0 + wc * 32 + q2 * 16 + (lane & 15);
#pragma unroll
        for (int e2 = 0; e2 < 4; ++e2) {
          float v = acc[m][q2][e2];
          unsigned short hh = f2bf(v), ll = f2bf(v - bfhi(hh));
          oh[(size_t)(row + e2) * CD + col] = hh;
          ol[(size_t)(row + e2) * CD + col] = ll;
          tf[(size_t)col * CD + row + e2] = v;
        }
      }
    }
  } else {
    int task = x - 200;
    if (task == 0 && t == 0) { barctr[0] = 0u; barctr[1] = 0u; }
    if (task < 8) {
      float* vin = (float*)sm;
      int seg = task & 3;
      const float* Wm = (task < 4) ? w1 : w2;
      const float* v = (task < 4) ? b2 : b1;
      float* dst = (task < 4) ? (vp + seg * CD) : (bpv + seg * CD);
      if (t < 64) vin[t] = v[seg * 64 + t];
      __syncthreads();
      if (t < 256) {
        float a = 0.f;
#pragma unroll 16
        for (int kk = 0; kk < 64; ++kk)
          a += Wm[(size_t)(seg * 64 + kk) * CD + t] * vin[kk];
        dst[t] = a;
      }
    } else if (task < 12) {
      int lane = t & 63, wv = t >> 6;
      float4 bvv = *(const float4*)(b0 + lane * 4);
#pragma unroll
      for (int i = 0; i < 8; ++i) {
        int o = (task - 8) * 64 + wv * 8 + i;
        float4 v = *(const float4*)(w3 + (size_t)o * CD + lane * 4);
        float a = v.x * bvv.x + v.y * bvv.y + v.z * bvv.z + v.w * bvv.w;
        a += __shfl_xor(a, 1);  a += __shfl_xor(a, 2);  a += __shfl_xor(a, 4);
        a += __shfl_xor(a, 8);  a += __shfl_xor(a, 16); a += __shfl_xor(a, 32);
        if (lane == 0) dlt[o] = a;
      }
    } else if (task == 12) {
      float* red = (float*)sm;
      if (t < 256) red[t] = b1[t] * b2[t];
      __syncthreads();
      for (int off = 128; off > 0; off >>= 1) {
        if (t < off) red[t] += red[t + off];
        __syncthreads();
      }
      if (t == 0) scal1[0] = red[0];
    }
  }
}

// ---------- kDC: reduce+sag | barrier | Rm+cv | barrier | Atm  (116 blocks) ----------
__global__ __launch_bounds__(512) void kDC(
    const float* __restrict__ Gp, float* __restrict__ G,
    unsigned short* __restrict__ Gh, unsigned short* __restrict__ Gl,
    const float* __restrict__ psum2, const float* __restrict__ vp,
    const float* __restrict__ Ff, const float* __restrict__ Et,
    float* __restrict__ alp, float* __restrict__ gam, float* __restrict__ scal0,
    const unsigned short* __restrict__ Eh, const unsigned short* __restrict__ El,
    unsigned short* __restrict__ Rh, unsigned short* __restrict__ Rl,
    const float* __restrict__ dlt, const float* __restrict__ scal1,
    const float* __restrict__ b3, float* __restrict__ cv,
    const unsigned short* __restrict__ Fth, const unsigned short* __restrict__ Ftl,
    unsigned short* __restrict__ Athi, unsigned short* __restrict__ Atlo,
    const float* __restrict__ bpv, unsigned int* __restrict__ barctr) {
  __shared__ __align__(16) unsigned short sm[32768];
  int b = blockIdx.x, t = threadIdx.x;
  // phase 1
  if (b < 96) {
#pragma unroll
    for (int s = 0; s < 4; ++s) {
      int f = b * 2048 + s * 512 + t;
      int b2 = f >> 8, tt = f & 255;
      int quad = b2 >> 8, r = b2 & 255, n = r >> 6;
      int idx = (r & 63) * 256 + tt;
      int i = (idx >> 7) + ((quad == 2) ? 128 : 0);
      int j = (idx & 127) + ((quad >= 1) ? 128 : 0);
      float a = 0.f;
#pragma unroll
      for (int ks = 0; ks < KSG; ++ks)
        a += Gp[((size_t)ks * NB + n) * CC + (size_t)i * CD + j];
      size_t o = (size_t)n * CC + (size_t)i * CD + j;
      unsigned short hh = f2bf(a), ll = f2bf(a - bfhi(hh));
      G[o] = a; Gh[o] = hh; Gl[o] = ll;
      if (quad == 1) {
        size_t o2 = (size_t)n * CC + (size_t)j * CD + i;
        G[o2] = a; Gh[o2] = hh; Gl[o2] = ll;
      }
    }
  } else if (b < 100) {
    int n = b - 96;
    float* ss = (float*)sm;
    float* red = ss + 256;
    float a = 0.f;
    if (t < 256) {
#pragma unroll
      for (int ks = 0; ks < 16; ++ks) a += psum2[((size_t)n * 16 + ks) * 256 + t];
      ss[t] = a;
      red[t] = a * (vp[t] + vp[CD + t] + vp[2 * CD + t] + vp[3 * CD + t]);
    }
    __syncthreads();
    for (int off = 128; off > 0; off >>= 1) {
      if (t < off) red[t] += red[t + off];
      __syncthreads();
    }
    if (t == 0) scal0[n] = red[0];
    if (t < 256) {
      float al = 0.f, ga = 0.f;
#pragma unroll 16
      for (int k = 0; k < CD; ++k) {
        float sk = ss[k];
        al += Ff[(size_t)k * CD + t] * sk;
        ga += Et[(size_t)k * CD + t] * sk;
      }
      alp[n * CD + t] = al;
      gam[n * CD + t] = ga;
    }
  }
  // barrier 1
  __syncthreads();
  if (t == 0) {
    __threadfence();
    atomicAdd(&barctr[0], 1u);
    if (b >= 96) {
      while (__hip_atomic_load(&barctr[0], __ATOMIC_ACQUIRE, __HIP_MEMORY_SCOPE_AGENT) <
             116u) {}
    }
    __threadfence();
  }
  __syncthreads();
  // phase 2
  if (b >= 100) {
    int bb = b - 100;
    int n = bb >> 2, i0 = ((bb >> 1) & 1) * 128, j0 = (bb & 1) * 128;
    f32x4 acc[4][2];
    mfma_nt_core(Eh, El, Gh + (size_t)n * CC, Gl + (size_t)n * CC, i0, j0, sm, acc);
    int lane = t & 63, wid = t >> 6, wr = wid >> 2, wc = wid & 3;
#pragma unroll
    for (int m = 0; m < 4; ++m) {
      int row = i0 + wr * 64 + m * 16 + ((lane >> 4) << 2);
#pragma unroll
      for (int q = 0; q < 2; ++q) {
        int col = j0 + wc * 32 + q * 16 + (lane & 15);
#pragma unroll
        for (int e = 0; e < 4; ++e) {
          float v = acc[m][q][e];
          unsigned short hh = f2bf(v), ll = f2bf(v - bfhi(hh));
          Rh[(size_t)n * CC + (size_t)(row + e) * CD + col] = hh;
          Rl[(size_t)n * CC + (size_t)(row + e) * CD + col] = ll;
        }
      }
    }
  } else if (b >= 96) {
    int n = b - 96;
    float* vsh = (float*)sm;
    float* g1 = vsh + CD;
    if (t < CD) vsh[t] = vp[t] + vp[CD + t] + vp[2 * CD + t] + vp[3 * CD + t];
    __syncthreads();
    if (t < CD) {
      const float* Gn = G + (size_t)n * CC;
      float a = 0.f;
#pragma unroll 8
      for (int k = 0; k < CD; ++k) a += Gn[(size_t)k * CD + t] * vsh[k];
      g1[t] = a;
    }
    __syncthreads();
    if (t < CD) {
      float c2 = 0.f;
#pragma unroll 8
      for (int k = 0; k < CD; ++k) c2 += Et[(size_t)k * CD + t] * g1[k];
      cv[n * CD + t] = (c2 + scal0[n] * dlt[t] +
                        scal1[0] * (gam[n * CD + t] + (float)HW * dlt[t])) *
                           (1.0f / HW) +
                       b3[t];
    }
  }
  // barrier 2
  __syncthreads();
  if (t == 0) {
    __threadfence();
    atomicAdd(&barctr[1], 1u);
    if (b < 16) {
      while (__hip_atomic_load(&barctr[1], __ATOMIC_ACQUIRE, __HIP_MEMORY_SCOPE_AGENT) <
             116u) {}
    }
    __threadfence();
  }
  __syncthreads();
  // phase 3
  if (b < 16) {
    int n = b >> 2, i0 = ((b >> 1) & 1) * 128, j0 = (b & 1) * 128;
    f32x4 acc[4][2];
    mfma_nt_core(Rh + (size_t)n * CC, Rl + (size_t)n * CC, Fth, Ftl, i0, j0, sm, acc);
    int lane = t & 63, wid = t >> 6, wr = wid >> 2, wc = wid & 3;
#pragma unroll
    for (int m = 0; m < 4; ++m) {
      int row = i0 + wr * 64 + m * 16 + ((lane >> 4) << 2);
#pragma unroll
      for (int q = 0; q < 2; ++q) {
        int col = j0 + wc * 32 + q * 16 + (lane & 15);
        float bj = bpv[col] + bpv[CD + col] + bpv[2 * CD + col] + bpv[3 * CD + col];
        float aj = alp[n * CD + col];
#pragma unroll
        for (int e = 0; e < 4; ++e) {
          float di = dlt[row + e], gi = gam[n * CD + row + e];
          float v = (acc[m][q][e] + di * aj + gi * bj) * (1.0f / HW) + di * bj;
          unsigned short hh = f2bf(v), ll = f2bf(v - bfhi(hh));
          Athi[(size_t)n * CC + (size_t)(row + e) * CD + col] = hh;
          Atlo[(size_t)n * CC + (size_t)(row + e) * CD + col] = ll;
        }
      }
    }
  }
}

// ---------- kF: out = At x X (B transposed+split on the fly, prefetched) + cv ----------
__global__ __launch_bounds__(512) void kF(const unsigned short* __restrict__ Athi,
                                          const unsigned short* __restrict__ Atlo,
                                          const float* __restrict__ X,
                                          const float* __restrict__ cv,
                                          float* __restrict__ out) {
  int n = blockIdx.z;
  int i0 = blockIdx.x * 128, j0 = blockIdx.y * 128;
  __shared__ __align__(16) unsigned short sm[32768];
  f32x4 acc[4][2];
  final_core(Athi + (size_t)n * CC, Atlo + (size_t)n * CC, X + (size_t)n * CD * HW, i0,
             j0, sm, acc);
  epi_store(acc, (float*)sm, out + (size_t)n * CD * HW + (size_t)i0 * HW + j0, HW,
            cv + n * CD + i0);
}

extern "C" void kernel_launch(void* const* d_in, const int* in_sizes, int n_in,
                              void* d_out, int out_size, void* d_ws, size_t ws_size,
                              hipStream_t stream) {
  const float* X = (const float*)d_in[0];
  const float* w0 = (const float*)d_in[1];
  const float* b0 = (const float*)d_in[2];
  const float* w1 = (const float*)d_in[3];
  const float* b1 = (const float*)d_in[4];
  const float* w2 = (const float*)d_in[5];
  const float* b2 = (const float*)d_in[6];
  const float* w3 = (const float*)d_in[7];
  const float* b3 = (const float*)d_in[8];
  float* out = (float*)d_out;
  float* ws = (float*)d_ws;

  float* cv    = ws;
  float* alp   = ws + 1024;
  float* gam   = ws + 2048;
  float* dlt   = ws + 3072;
  float* vp    = ws + 4096;
  float* bpv   = ws + 5120;
  float* scal0 = ws + 6144;
  float* scal1 = ws + 6176;
  unsigned int* barctr = (unsigned int*)(ws + 6208);
  float* psum2 = ws + 8192;                    // NB*16*256 = 16384
  float* Et    = psum2 + 16384;
  float* Ff    = Et + CC;
  float* G     = Ff + CC;                      // NB*CC
  float* Gp    = G + (size_t)NB * CC;          // KSG*NB*CC
  unsigned short* Eh   = (unsigned short*)(Gp + (size_t)KSG * NB * CC);
  unsigned short* El   = Eh + CC;
  unsigned short* Fth  = El + CC;
  unsigned short* Ftl  = Fth + CC;
  unsigned short* Gh   = Ftl + CC;
  unsigned short* Gl   = Gh + (size_t)NB * CC;
  unsigned short* Rh   = Gl + (size_t)NB * CC;
  unsigned short* Rl   = Rh + (size_t)NB * CC;
  unsigned short* Athi = Rl + (size_t)NB * CC;
  unsigned short* Atlo = Athi + (size_t)NB * CC;

  kB<<<dim3(213), 512, 0, stream>>>(X, Gp, psum2, w0, w1, w2, w3, b0, b1, b2, Eh, El,
                                    Et, Fth, Ftl, Ff, vp, bpv, dlt, scal1, barctr);
  kDC<<<dim3(116), 512, 0, stream>>>(Gp, G, Gh, Gl, psum2, vp, Ff, Et, alp, gam, scal0,
                                     Eh, El, Rh, Rl, dlt, scal1, b3, cv, Fth, Ftl, Athi,
                                     Atlo, bpv, barctr);
  kF<<<dim3(2, 32, NB), 512, 0, stream>>>(Athi, Atlo, X, cv, out);
}

// Round 10
// 73.345 us; speedup vs baseline: 2.3718x; 1.3185x over previous
//
#include <hip/hip_runtime.h>

#define NB 4
#define CD 256
#define HW 4096
#define KSG 16
#define CC (CD * CD)

typedef __attribute__((ext_vector_type(8))) short bf16x8;
typedef __attribute__((ext_vector_type(4))) float f32x4;

__device__ inline unsigned short f2bf(float x) {
  unsigned int u = __float_as_uint(x);
  unsigned int r = (u + 0x7FFFu + ((u >> 16) & 1u)) >> 16;
  return (unsigned short)r;
}
__device__ inline float bfhi(unsigned short h) {
  return __uint_as_float(((unsigned int)h) << 16);
}
__device__ __forceinline__ void gload16(const unsigned short* g, unsigned short* l) {
  __builtin_amdgcn_global_load_lds((const __attribute__((address_space(1))) void*)g,
                                   (__attribute__((address_space(3))) void*)l, 16, 0, 0);
}

// ---------- MFMA body: A at sm[0]/sm[8192], B at sm[BOFF]/sm[BOFF+8192] ----------
template <int BOFF>
__device__ __forceinline__ void mfma_body(const unsigned short* sm, f32x4 acc[4][2]) {
  int t = threadIdx.x, lane = t & 63, wid = t >> 6;
  int wr = wid >> 2, wc = wid & 3;
  int lrow = lane & 15, lkb = lane >> 4;
#pragma unroll
  for (int ks2 = 0; ks2 < 2; ++ks2) {
    bf16x8 ah[4], al[4], bh[2], bl[2];
#pragma unroll
    for (int m = 0; m < 4; ++m) {
      int r = wr * 64 + m * 16 + lrow;
      int sw = ((ks2 * 4 + lkb) ^ (r & 7)) * 8;
      ah[m] = *(const bf16x8*)(sm + r * 64 + sw);
      al[m] = *(const bf16x8*)(sm + 8192 + r * 64 + sw);
    }
#pragma unroll
    for (int q = 0; q < 2; ++q) {
      int r = wc * 32 + q * 16 + lrow;
      int sw = ((ks2 * 4 + lkb) ^ (r & 7)) * 8;
      bh[q] = *(const bf16x8*)(sm + BOFF + r * 64 + sw);
      bl[q] = *(const bf16x8*)(sm + BOFF + 8192 + r * 64 + sw);
    }
#pragma unroll
    for (int m = 0; m < 4; ++m)
#pragma unroll
      for (int q = 0; q < 2; ++q) {
        acc[m][q] = __builtin_amdgcn_mfma_f32_16x16x32_bf16(ah[m], bh[q], acc[m][q], 0, 0, 0);
        acc[m][q] = __builtin_amdgcn_mfma_f32_16x16x32_bf16(ah[m], bl[q], acc[m][q], 0, 0, 0);
        acc[m][q] = __builtin_amdgcn_mfma_f32_16x16x32_bf16(al[m], bh[q], acc[m][q], 0, 0, 0);
      }
  }
}

// ---------- bf16-operand NT core (gload16 staging) ----------
__device__ __forceinline__ void mfma_nt_core(
    const unsigned short* __restrict__ pH, const unsigned short* __restrict__ pL,
    const unsigned short* __restrict__ qH, const unsigned short* __restrict__ qL,
    int i0, int j0, unsigned short* sm, f32x4 acc[4][2]) {
  int t = threadIdx.x;
  int lane = t & 63, wid = t >> 6;
  int tsel = wid >> 1;
  int gbase = (wid & 1) * 8;
  const unsigned short* bp2 = (tsel == 0) ? pH : (tsel == 1) ? pL : (tsel == 2) ? qH : qL;
  int tb = (tsel < 2) ? i0 : j0;
  int rsub = lane >> 3;
  int gc = (lane & 7) ^ rsub;
  unsigned short* ldsT = sm + tsel * 8192;
#pragma unroll
  for (int m = 0; m < 4; ++m)
#pragma unroll
    for (int q = 0; q < 2; ++q) acc[m][q] = (f32x4){0.f, 0.f, 0.f, 0.f};
  for (int k0 = 0; k0 < 256; k0 += 64) {
#pragma unroll
    for (int s = 0; s < 8; ++s) {
      int g = gbase + s;
      gload16(bp2 + (size_t)(tb + g * 8 + rsub) * CD + k0 + gc * 8, ldsT + g * 512);
    }
    __syncthreads();
    mfma_body<16384>(sm, acc);
    __syncthreads();
  }
}

// ---------- gram core: operands from X fp32, reg-prefetch; DIAG stages A only ----------
template <bool DIAG>
__device__ __forceinline__ void gram_core(const float* __restrict__ Xn, int i0, int j0,
                                          int kBegin, unsigned short* sm,
                                          f32x4 acc[4][2], float* __restrict__ psumRow) {
  int t = threadIdx.x;
  int r16 = t >> 4, k4 = (t & 15) * 4;
  int kg = k4 >> 3, kr = k4 & 7;
#pragma unroll
  for (int m = 0; m < 4; ++m)
#pragma unroll
    for (int q = 0; q < 2; ++q) acc[m][q] = (f32x4){0.f, 0.f, 0.f, 0.f};
  float ps[4] = {0.f, 0.f, 0.f, 0.f};
  float4 av[4], bv[4];
#pragma unroll
  for (int j = 0; j < 4; ++j) {
    av[j] = *(const float4*)(Xn + (size_t)(i0 + j * 32 + r16) * HW + kBegin + k4);
    if (!DIAG)
      bv[j] = *(const float4*)(Xn + (size_t)(j0 + j * 32 + r16) * HW + kBegin + k4);
  }
#pragma unroll
  for (int s = 0; s < 4; ++s) {
    float4 av2[4], bv2[4];
    if (s < 3) {
#pragma unroll
      for (int j = 0; j < 4; ++j) {
        av2[j] = *(const float4*)(Xn + (size_t)(i0 + j * 32 + r16) * HW + kBegin +
                                  (s + 1) * 64 + k4);
        if (!DIAG)
          bv2[j] = *(const float4*)(Xn + (size_t)(j0 + j * 32 + r16) * HW + kBegin +
                                    (s + 1) * 64 + k4);
      }
    }
#pragma unroll
    for (int j = 0; j < 4; ++j) {
      int r = j * 32 + r16;
      int off = r * 64 + ((kg ^ (r & 7)) << 3) + kr;
      ushort4 h, l;
      h.x = f2bf(av[j].x); l.x = f2bf(av[j].x - bfhi(h.x));
      h.y = f2bf(av[j].y); l.y = f2bf(av[j].y - bfhi(h.y));
      h.z = f2bf(av[j].z); l.z = f2bf(av[j].z - bfhi(h.z));
      h.w = f2bf(av[j].w); l.w = f2bf(av[j].w - bfhi(h.w));
      *(ushort4*)(sm + off) = h;
      *(ushort4*)(sm + 8192 + off) = l;
      ps[j] += av[j].x + av[j].y + av[j].z + av[j].w;
      if (!DIAG) {
        h.x = f2bf(bv[j].x); l.x = f2bf(bv[j].x - bfhi(h.x));
        h.y = f2bf(bv[j].y); l.y = f2bf(bv[j].y - bfhi(h.y));
        h.z = f2bf(bv[j].z); l.z = f2bf(bv[j].z - bfhi(h.z));
        h.w = f2bf(bv[j].w); l.w = f2bf(bv[j].w - bfhi(h.w));
        *(ushort4*)(sm + 16384 + off) = h;
        *(ushort4*)(sm + 24576 + off) = l;
      }
    }
    __syncthreads();
    mfma_body<DIAG ? 0 : 16384>(sm, acc);
    __syncthreads();
    if (s < 3) {
#pragma unroll
      for (int j = 0; j < 4; ++j) {
        av[j] = av2[j];
        if (!DIAG) bv[j] = bv2[j];
      }
    }
  }
  if (psumRow) {
#pragma unroll
    for (int j = 0; j < 4; ++j) {
      float v = ps[j];
      v += __shfl_xor(v, 1); v += __shfl_xor(v, 2);
      v += __shfl_xor(v, 4); v += __shfl_xor(v, 8);
      if ((t & 15) == 0) psumRow[j * 32 + r16] = v;
    }
  }
}

// ---------- ROW-stage: LDS[r][k] = W[r0+r][k0+k] (hi/lo) ----------
__device__ __forceinline__ void stage_rowA(const float* __restrict__ W, int ld, int r0,
                                           int k0, unsigned short* dst) {
  int t = threadIdx.x;
  int r16 = t >> 4, k4 = (t & 15) * 4;
  int kg = k4 >> 3, kr = k4 & 7;
#pragma unroll
  for (int j = 0; j < 4; ++j) {
    int r = j * 32 + r16;
    float4 v = *(const float4*)(W + (size_t)(r0 + r) * ld + k0 + k4);
    int off = r * 64 + ((kg ^ (r & 7)) << 3) + kr;
    ushort4 h, l;
    h.x = f2bf(v.x); l.x = f2bf(v.x - bfhi(h.x));
    h.y = f2bf(v.y); l.y = f2bf(v.y - bfhi(h.y));
    h.z = f2bf(v.z); l.z = f2bf(v.z - bfhi(h.z));
    h.w = f2bf(v.w); l.w = f2bf(v.w - bfhi(h.w));
    *(ushort4*)(dst + off) = h;
    *(ushort4*)(dst + 8192 + off) = l;
  }
}

// ---------- COL-stage (transpose): LDS[c][k] = W[k0+k][c0+c] (hi/lo) ----------
__device__ __forceinline__ void stage_colT(const float* __restrict__ W, int ld, int c0,
                                           int k0, unsigned short* dst) {
  int t = threadIdx.x;
#pragma unroll
  for (int ee = 0; ee < 8; ++ee) {
    int flat = ee * 512 + t;
    int c2 = flat >> 7, p = flat & 127;
    const float* src = W + (size_t)(k0 + 2 * c2) * ld + c0 + p;
    float xa = src[0], xb = src[ld];
    int c = 2 * c2;
    int off = p * 64 + ((((c >> 3)) ^ (p & 7)) << 3) + (c & 7);
    unsigned short ha = f2bf(xa), hb = f2bf(xb);
    ushort2 hv; hv.x = ha; hv.y = hb;
    ushort2 lv; lv.x = f2bf(xa - bfhi(ha)); lv.y = f2bf(xb - bfhi(hb));
    *(ushort2*)(dst + off) = hv;
    *(ushort2*)(dst + 8192 + off) = lv;
  }
}

// ---------- final core: A = At bf16 via gload16; B = X fp32 transpose-staged w/ prefetch ----------
__device__ __forceinline__ void final_core(const unsigned short* __restrict__ aH,
                                           const unsigned short* __restrict__ aL,
                                           const float* __restrict__ Xn, int i0, int j0,
                                           unsigned short* sm, f32x4 acc[4][2]) {
  int t = threadIdx.x, lane = t & 63, wid = t >> 6;
  const unsigned short* ap = (wid & 4) ? aL : aH;
  unsigned short* ldsA = sm + ((wid & 4) ? 8192 : 0);
  int rsub = lane >> 3;
  int gc = (lane & 7) ^ rsub;
  int gq = wid & 3;
#pragma unroll
  for (int m = 0; m < 4; ++m)
#pragma unroll
    for (int q = 0; q < 2; ++q) acc[m][q] = (f32x4){0.f, 0.f, 0.f, 0.f};
  float xa[8], xb[8];
#pragma unroll
  for (int s2 = 0; s2 < 4; ++s2) {
    int g = gq * 4 + s2;
    gload16(ap + (size_t)(i0 + g * 8 + rsub) * CD + gc * 8, ldsA + g * 512);
  }
#pragma unroll
  for (int ee = 0; ee < 8; ++ee) {
    int flat = ee * 512 + t;
    int c2 = flat >> 7, p = flat & 127;
    const float* src = Xn + (size_t)(2 * c2) * HW + j0 + p;
    xa[ee] = src[0];
    xb[ee] = src[HW];
  }
#pragma unroll
  for (int s = 0; s < 4; ++s) {
#pragma unroll
    for (int ee = 0; ee < 8; ++ee) {
      int flat = ee * 512 + t;
      int c2 = flat >> 7, p = flat & 127;
      int c = 2 * c2;
      int off = p * 64 + ((((c >> 3)) ^ (p & 7)) << 3) + (c & 7);
      unsigned short ha = f2bf(xa[ee]), hb = f2bf(xb[ee]);
      ushort2 hv; hv.x = ha; hv.y = hb;
      ushort2 lv; lv.x = f2bf(xa[ee] - bfhi(ha)); lv.y = f2bf(xb[ee] - bfhi(hb));
      *(ushort2*)(sm + 16384 + off) = hv;
      *(ushort2*)(sm + 24576 + off) = lv;
    }
    float xa2[8], xb2[8];
    if (s < 3) {
#pragma unroll
      for (int ee = 0; ee < 8; ++ee) {
        int flat = ee * 512 + t;
        int c2 = flat >> 7, p = flat & 127;
        const float* src = Xn + (size_t)((s + 1) * 64 + 2 * c2) * HW + j0 + p;
        xa2[ee] = src[0];
        xb2[ee] = src[HW];
      }
    }
    __syncthreads();
    mfma_body<16384>(sm, acc);
    __syncthreads();
    if (s < 3) {
#pragma unroll
      for (int s2 = 0; s2 < 4; ++s2) {
        int g = gq * 4 + s2;
        gload16(ap + (size_t)(i0 + g * 8 + rsub) * CD + (s + 1) * 64 + gc * 8,
                ldsA + g * 512);
      }
#pragma unroll
      for (int ee = 0; ee < 8; ++ee) { xa[ee] = xa2[ee]; xb[ee] = xb2[ee]; }
    }
  }
}

// ---------- coalesced fp32 epilogue ----------
__device__ __forceinline__ void epi_store(f32x4 acc[4][2], float* smf, float* dst,
                                          int ld, const float* cvrow) {
  int t = threadIdx.x, lane = t & 63, wid = t >> 6;
  int wr = wid >> 2, wc = wid & 3;
#pragma unroll
  for (int m = 0; m < 4; ++m) {
    int rbase = wr * 64 + m * 16 + ((lane >> 4) << 2);
#pragma unroll
    for (int q = 0; q < 2; ++q) {
      int col = wc * 32 + q * 16 + (lane & 15);
#pragma unroll
      for (int e = 0; e < 4; ++e) {
        int row = rbase + e;
        smf[row * 128 + (col ^ ((row & 4) << 2))] = acc[m][q][e];
      }
    }
  }
  __syncthreads();
#pragma unroll
  for (int it = 0; it < 8; ++it) {
    int row = it * 16 + wid * 2 + (lane >> 5);
    int col = (lane & 31) * 4;
    float4 v = *(const float4*)&smf[row * 128 + (col ^ ((row & 4) << 2))];
    if (cvrow) {
      float cb = cvrow[row];
      v.x += cb; v.y += cb; v.z += cb; v.w += cb;
    }
    *(float4*)(dst + (size_t)row * ld + col) = v;
  }
}

// ---------- kB: gram (192) + EF on-the-fly (8) + small vectors (13) ----------
__global__ __launch_bounds__(512) void kB(
    const float* __restrict__ X, float* __restrict__ Gp, float* __restrict__ psum2,
    const float* __restrict__ w0, const float* __restrict__ w1,
    const float* __restrict__ w2, const float* __restrict__ w3,
    const float* __restrict__ b0, const float* __restrict__ b1,
    const float* __restrict__ b2, unsigned short* __restrict__ Eh,
    unsigned short* __restrict__ El, float* __restrict__ Et,
    unsigned short* __restrict__ Fth, unsigned short* __restrict__ Ftl,
    float* __restrict__ Ff, float* __restrict__ vp, float* __restrict__ bpv,
    float* __restrict__ dlt, float* __restrict__ scal1) {
  __shared__ __align__(16) unsigned short sm[32768];
  int x = blockIdx.x, t = threadIdx.x;
  if (x < 192) {
    int tile = x % 3;  // 0: (0,0) diag, 1: (0,128), 2: (128,128) diag
    int z = x / 3;
    int n = z >> 4, ks = z & 15;
    const float* Xn = X + (size_t)n * CD * HW;
    f32x4 acc[4][2];
    if (tile == 1) {
      gram_core<false>(Xn, 0, 128, ks * 256, sm, acc, nullptr);
      epi_store(acc, (float*)sm, Gp + ((size_t)ks * NB + n) * CC + 128, CD, nullptr);
    } else {
      int i0 = (tile == 2) ? 128 : 0;
      float* psRow = psum2 + ((size_t)n * 16 + ks) * 256 + i0;
      gram_core<true>(Xn, i0, i0, ks * 256, sm, acc, psRow);
      epi_store(acc, (float*)sm,
                Gp + ((size_t)ks * NB + n) * CC + (size_t)i0 * CD + i0, CD, nullptr);
    }
  } else if (x < 200) {
    int e = x - 192;
    int zc = e >> 2, q = e & 3;
    int i0 = (q >> 1) * 128, j0 = (q & 1) * 128;
    f32x4 acc[4][2];
#pragma unroll
    for (int m = 0; m < 4; ++m)
#pragma unroll
      for (int qq = 0; qq < 2; ++qq) acc[m][qq] = (f32x4){0.f, 0.f, 0.f, 0.f};
    for (int s = 0; s < 4; ++s) {
      int k0 = s * 64;
      if (zc == 0) stage_rowA(w3, CD, i0, k0, sm);
      else stage_colT(w2, CD, i0, k0, sm);
      stage_colT(zc ? w1 : w0, CD, j0, k0, sm + 16384);
      __syncthreads();
      mfma_body<16384>(sm, acc);
      __syncthreads();
    }
    unsigned short* oh = zc ? Fth : Eh;
    unsigned short* ol = zc ? Ftl : El;
    float* tf = zc ? Ff : Et;
    int lane = t & 63, wid = t >> 6, wr = wid >> 2, wc = wid & 3;
#pragma unroll
    for (int m = 0; m < 4; ++m) {
      int row = i0 + wr * 64 + m * 16 + ((lane >> 4) << 2);
#pragma unroll
      for (int q2 = 0; q2 < 2; ++q2) {
        int col = j0 + wc * 32 + q2 * 16 + (lane & 15);
#pragma unroll
        for (int e2 = 0; e2 < 4; ++e2) {
          float v = acc[m][q2][e2];
          unsigned short hh = f2bf(v), ll = f2bf(v - bfhi(hh));
          oh[(size_t)(row + e2) * CD + col] = hh;
          ol[(size_t)(row + e2) * CD + col] = ll;
          tf[(size_t)col * CD + row + e2] = v;
        }
      }
    }
  } else {
    int task = x - 200;
    if (task < 8) {
      float* vin = (float*)sm;
      int seg = task & 3;
      const float* Wm = (task < 4) ? w1 : w2;
      const float* v = (task < 4) ? b2 : b1;
      float* dst = (task < 4) ? (vp + seg * CD) : (bpv + seg * CD);
      if (t < 64) vin[t] = v[seg * 64 + t];
      __syncthreads();
      if (t < 256) {
        float a = 0.f;
#pragma unroll 16
        for (int kk = 0; kk < 64; ++kk)
          a += Wm[(size_t)(seg * 64 + kk) * CD + t] * vin[kk];
        dst[t] = a;
      }
    } else if (task < 12) {
      int lane = t & 63, wv = t >> 6;
      float4 bvv = *(const float4*)(b0 + lane * 4);
#pragma unroll
      for (int i = 0; i < 8; ++i) {
        int o = (task - 8) * 64 + wv * 8 + i;
        float4 v = *(const float4*)(w3 + (size_t)o * CD + lane * 4);
        float a = v.x * bvv.x + v.y * bvv.y + v.z * bvv.z + v.w * bvv.w;
        a += __shfl_xor(a, 1);  a += __shfl_xor(a, 2);  a += __shfl_xor(a, 4);
        a += __shfl_xor(a, 8);  a += __shfl_xor(a, 16); a += __shfl_xor(a, 32);
        if (lane == 0) dlt[o] = a;
      }
    } else if (task == 12) {
      float* red = (float*)sm;
      if (t < 256) red[t] = b1[t] * b2[t];
      __syncthreads();
      for (int off = 128; off > 0; off >>= 1) {
        if (t < off) red[t] += red[t + off];
        __syncthreads();
      }
      if (t == 0) scal1[0] = red[0];
    }
  }
}

// ---------- kC: gram reduce (+mirror, +bf16 hi/lo) + sag (100 blocks) ----------
__global__ __launch_bounds__(512) void kC(
    const float* __restrict__ Gp, float* __restrict__ G,
    unsigned short* __restrict__ Gh, unsigned short* __restrict__ Gl,
    const float* __restrict__ psum2, const float* __restrict__ vp,
    const float* __restrict__ Ff, const float* __restrict__ Et,
    float* __restrict__ alp, float* __restrict__ gam, float* __restrict__ scal0) {
  __shared__ float smf[512];
  int b = blockIdx.x, t = threadIdx.x;
  if (b < 96) {
#pragma unroll
    for (int s = 0; s < 4; ++s) {
      int f = b * 2048 + s * 512 + t;
      int b2 = f >> 8, tt = f & 255;
      int quad = b2 >> 8, r = b2 & 255, n = r >> 6;
      int idx = (r & 63) * 256 + tt;
      int i = (idx >> 7) + ((quad == 2) ? 128 : 0);
      int j = (idx & 127) + ((quad >= 1) ? 128 : 0);
      float a = 0.f;
#pragma unroll
      for (int ks = 0; ks < KSG; ++ks)
        a += Gp[((size_t)ks * NB + n) * CC + (size_t)i * CD + j];
      size_t o = (size_t)n * CC + (size_t)i * CD + j;
      unsigned short hh = f2bf(a), ll = f2bf(a - bfhi(hh));
      G[o] = a; Gh[o] = hh; Gl[o] = ll;
      if (quad == 1) {
        size_t o2 = (size_t)n * CC + (size_t)j * CD + i;
        G[o2] = a; Gh[o2] = hh; Gl[o2] = ll;
      }
    }
  } else {
    int n = b - 96;
    float* ss = smf;
    float* red = ss + 256;
    float a = 0.f;
    if (t < 256) {
#pragma unroll
      for (int ks = 0; ks < 16; ++ks) a += psum2[((size_t)n * 16 + ks) * 256 + t];
      ss[t] = a;
      red[t] = a * (vp[t] + vp[CD + t] + vp[2 * CD + t] + vp[3 * CD + t]);
    }
    __syncthreads();
    for (int off = 128; off > 0; off >>= 1) {
      if (t < off) red[t] += red[t + off];
      __syncthreads();
    }
    if (t == 0) scal0[n] = red[0];
    if (t < 256) {
      float al = 0.f, ga = 0.f;
#pragma unroll 16
      for (int k = 0; k < CD; ++k) {
        float sk = ss[k];
        al += Ff[(size_t)k * CD + t] * sk;
        ga += Et[(size_t)k * CD + t] * sk;
      }
      alp[n * CD + t] = al;
      gam[n * CD + t] = ga;
    }
  }
}

// ---------- kD1: Rm (16 blocks) + cv (4 blocks) ----------
__global__ __launch_bounds__(512) void kD1(
    const unsigned short* __restrict__ Eh, const unsigned short* __restrict__ El,
    const unsigned short* __restrict__ Gh, const unsigned short* __restrict__ Gl,
    unsigned short* __restrict__ Rh, unsigned short* __restrict__ Rl,
    const float* __restrict__ G, const float* __restrict__ Et,
    const float* __restrict__ vp, const float* __restrict__ dlt,
    const float* __restrict__ gam, const float* __restrict__ scal0,
    const float* __restrict__ scal1, const float* __restrict__ b3,
    float* __restrict__ cv) {
  __shared__ __align__(16) unsigned short sm[32768];
  int b = blockIdx.x, t = threadIdx.x;
  if (b < 16) {
    int n = b >> 2, i0 = ((b >> 1) & 1) * 128, j0 = (b & 1) * 128;
    f32x4 acc[4][2];
    mfma_nt_core(Eh, El, Gh + (size_t)n * CC, Gl + (size_t)n * CC, i0, j0, sm, acc);
    int lane = t & 63, wid = t >> 6, wr = wid >> 2, wc = wid & 3;
#pragma unroll
    for (int m = 0; m < 4; ++m) {
      int row = i0 + wr * 64 + m * 16 + ((lane >> 4) << 2);
#pragma unroll
      for (int q = 0; q < 2; ++q) {
        int col = j0 + wc * 32 + q * 16 + (lane & 15);
#pragma unroll
        for (int e = 0; e < 4; ++e) {
          float v = acc[m][q][e];
          unsigned short hh = f2bf(v), ll = f2bf(v - bfhi(hh));
          Rh[(size_t)n * CC + (size_t)(row + e) * CD + col] = hh;
          Rl[(size_t)n * CC + (size_t)(row + e) * CD + col] = ll;
        }
      }
    }
  } else {
    int n = b - 16;
    float* vsh = (float*)sm;
    float* g1 = vsh + CD;
    if (t < CD) vsh[t] = vp[t] + vp[CD + t] + vp[2 * CD + t] + vp[3 * CD + t];
    __syncthreads();
    if (t < CD) {
      const float* Gn = G + (size_t)n * CC;
      float a = 0.f;
#pragma unroll 8
      for (int k = 0; k < CD; ++k) a += Gn[(size_t)k * CD + t] * vsh[k];
      g1[t] = a;
    }
    __syncthreads();
    if (t < CD) {
      float c2 = 0.f;
#pragma unroll 8
      for (int k = 0; k < CD; ++k) c2 += Et[(size_t)k * CD + t] * g1[k];
      cv[n * CD + t] = (c2 + scal0[n] * dlt[t] +
                        scal1[0] * (gam[n * CD + t] + (float)HW * dlt[t])) *
                           (1.0f / HW) +
                       b3[t];
    }
  }
}

// ---------- kD2: Atm (16 blocks) ----------
__global__ __launch_bounds__(512) void kD2(
    const unsigned short* __restrict__ Rh, const unsigned short* __restrict__ Rl,
    const unsigned short* __restrict__ Fth, const unsigned short* __restrict__ Ftl,
    unsigned short* __restrict__ Athi, unsigned short* __restrict__ Atlo,
    const float* __restrict__ dlt, const float* __restrict__ alp,
    const float* __restrict__ gam, const float* __restrict__ bpv) {
  __shared__ __align__(16) unsigned short sm[32768];
  int b = blockIdx.x, t = threadIdx.x;
  int n = b >> 2, i0 = ((b >> 1) & 1) * 128, j0 = (b & 1) * 128;
  f32x4 acc[4][2];
  mfma_nt_core(Rh + (size_t)n * CC, Rl + (size_t)n * CC, Fth, Ftl, i0, j0, sm, acc);
  int lane = t & 63, wid = t >> 6, wr = wid >> 2, wc = wid & 3;
#pragma unroll
  for (int m = 0; m < 4; ++m) {
    int row = i0 + wr * 64 + m * 16 + ((lane >> 4) << 2);
#pragma unroll
    for (int q = 0; q < 2; ++q) {
      int col = j0 + wc * 32 + q * 16 + (lane & 15);
      float bj = bpv[col] + bpv[CD + col] + bpv[2 * CD + col] + bpv[3 * CD + col];
      float aj = alp[n * CD + col];
#pragma unroll
      for (int e = 0; e < 4; ++e) {
        float di = dlt[row + e], gi = gam[n * CD + row + e];
        float v = (acc[m][q][e] + di * aj + gi * bj) * (1.0f / HW) + di * bj;
        unsigned short hh = f2bf(v), ll = f2bf(v - bfhi(hh));
        Athi[(size_t)n * CC + (size_t)(row + e) * CD + col] = hh;
        Atlo[(size_t)n * CC + (size_t)(row + e) * CD + col] = ll;
      }
    }
  }
}

// ---------- kF: out = At x X (B transposed+split on the fly, prefetched) + cv ----------
__global__ __launch_bounds__(512) void kF(const unsigned short* __restrict__ Athi,
                                          const unsigned short* __restrict__ Atlo,
                                          const float* __restrict__ X,
                                          const float* __restrict__ cv,
                                          float* __restrict__ out) {
  int n = blockIdx.z;
  int i0 = blockIdx.x * 128, j0 = blockIdx.y * 128;
  __shared__ __align__(16) unsigned short sm[32768];
  f32x4 acc[4][2];
  final_core(Athi + (size_t)n * CC, Atlo + (size_t)n * CC, X + (size_t)n * CD * HW, i0,
             j0, sm, acc);
  epi_store(acc, (float*)sm, out + (size_t)n * CD * HW + (size_t)i0 * HW + j0, HW,
            cv + n * CD + i0);
}

extern "C" void kernel_launch(void* const* d_in, const int* in_sizes, int n_in,
                              void* d_out, int out_size, void* d_ws, size_t ws_size,
                              hipStream_t stream) {
  const float* X = (const float*)d_in[0];
  const float* w0 = (const float*)d_in[1];
  const float* b0 = (const float*)d_in[2];
  const float* w1 = (const float*)d_in[3];
  const float* b1 = (const float*)d_in[4];
  const float* w2 = (const float*)d_in[5];
  const float* b2 = (const float*)d_in[6];
  const float* w3 = (const float*)d_in[7];
  const float* b3 = (const float*)d_in[8];
  float* out = (float*)d_out;
  float* ws = (float*)d_ws;

  float* cv    = ws;
  float* alp   = ws + 1024;
  float* gam   = ws + 2048;
  float* dlt   = ws + 3072;
  float* vp    = ws + 4096;
  float* bpv   = ws + 5120;
  float* scal0 = ws + 6144;
  float* scal1 = ws + 6176;
  float* psum2 = ws + 8192;                    // NB*16*256 = 16384
  float* Et    = psum2 + 16384;
  float* Ff    = Et + CC;
  float* G     = Ff + CC;                      // NB*CC
  float* Gp    = G + (size_t)NB * CC;          // KSG*NB*CC
  unsigned short* Eh   = (unsigned short*)(Gp + (size_t)KSG * NB * CC);
  unsigned short* El   = Eh + CC;
  unsigned short* Fth  = El + CC;
  unsigned short* Ftl  = Fth + CC;
  unsigned short* Gh   = Ftl + CC;
  unsigned short* Gl   = Gh + (size_t)NB * CC;
  unsigned short* Rh   = Gl + (size_t)NB * CC;
  unsigned short* Rl   = Rh + (size_t)NB * CC;
  unsigned short* Athi = Rl + (size_t)NB * CC;
  unsigned short* Atlo = Athi + (size_t)NB * CC;

  kB<<<dim3(213), 512, 0, stream>>>(X, Gp, psum2, w0, w1, w2, w3, b0, b1, b2, Eh, El,
                                    Et, Fth, Ftl, Ff, vp, bpv, dlt, scal1);
  kC<<<dim3(100), 512, 0, stream>>>(Gp, G, Gh, Gl, psum2, vp, Ff, Et, alp, gam, scal0);
  kD1<<<dim3(20), 512, 0, stream>>>(Eh, El, Gh, Gl, Rh, Rl, G, Et, vp, dlt, gam, scal0,
                                    scal1, b3, cv);
  kD2<<<dim3(16), 512, 0, stream>>>(Rh, Rl, Fth, Ftl, Athi, Atlo, dlt, alp, gam, bpv);
  kF<<<dim3(2, 32, NB), 512, 0, stream>>>(Athi, Atlo, X, cv, out);
}